// Round 1
// baseline (2255.823 us; speedup 1.0000x reference)
//
#include <hip/hip_runtime.h>
#include <hip/hip_bf16.h>

// ---------------- sizes ----------------
#define LSEQ 2048
#define DMODEL 768
#define DINNER 1536
#define DSTATE 16
#define DTRANK 48
#define XDBL_W (DTRANK + 2*DSTATE)   // 80

// ---------------- generic tiled fp32 GEMM: C[m,n] = sum_k A[m*lda+k]*B[n*ldb+k] ----------------
// EPI: 0 = none, 1 = +bias then softplus
template<int EPI>
__global__ __launch_bounds__(256) void gemm_tn(
    const float* __restrict__ A, int lda,
    const float* __restrict__ B, int ldb,
    float* __restrict__ C, int ldc,
    int M, int N, int K,
    const float* __restrict__ bias)
{
    __shared__ float As[16][64 + 4];
    __shared__ float Bs[16][64 + 4];
    const int tid = threadIdx.x;
    const int m0 = blockIdx.x * 64;
    const int n0 = blockIdx.y * 64;
    const int tx = tid & 15;    // n sub-tile
    const int ty = tid >> 4;    // m sub-tile
    const int lr = tid >> 4;    // load row (16 rows/pass)
    const int lc = tid & 15;    // load k
    float acc[4][4] = {};

    for (int k0 = 0; k0 < K; k0 += 16) {
        const int k = k0 + lc;
#pragma unroll
        for (int i = 0; i < 4; ++i) {
            int m = m0 + lr + i * 16;
            float v = 0.f;
            if (m < M) v = A[(size_t)m * lda + k];
            As[lc][lr + i * 16] = v;
        }
#pragma unroll
        for (int i = 0; i < 4; ++i) {
            int n = n0 + lr + i * 16;
            float v = 0.f;
            if (n < N) v = B[(size_t)n * ldb + k];
            Bs[lc][lr + i * 16] = v;
        }
        __syncthreads();
#pragma unroll
        for (int kk = 0; kk < 16; ++kk) {
            float a[4], b[4];
#pragma unroll
            for (int i = 0; i < 4; ++i) a[i] = As[kk][ty * 4 + i];
#pragma unroll
            for (int j = 0; j < 4; ++j) b[j] = Bs[kk][tx * 4 + j];
#pragma unroll
            for (int i = 0; i < 4; ++i)
#pragma unroll
                for (int j = 0; j < 4; ++j)
                    acc[i][j] = fmaf(a[i], b[j], acc[i][j]);
        }
        __syncthreads();
    }

#pragma unroll
    for (int i = 0; i < 4; ++i) {
        int m = m0 + ty * 4 + i;
        if (m >= M) continue;
#pragma unroll
        for (int j = 0; j < 4; ++j) {
            int n = n0 + tx * 4 + j;
            if (n >= N) continue;
            float v = acc[i][j];
            if (EPI == 1) {
                v += bias[n];
                // jax.nn.softplus = max(x,0) + log1p(exp(-|x|))
                v = fmaxf(v, 0.f) + log1pf(expf(-fabsf(v)));
            }
            C[(size_t)m * ldc + n] = v;
        }
    }
}

// ---------------- depthwise causal conv1d (width 4) + SiLU ----------------
__global__ __launch_bounds__(256) void conv_silu_kernel(
    const float* __restrict__ xz,      // (L, 3072); xh = cols [0,1536)
    const float* __restrict__ conv_w,  // (1536, 4)
    const float* __restrict__ conv_b,  // (1536,)
    float* __restrict__ u)             // (L, 1536)
{
    int idx = blockIdx.x * blockDim.x + threadIdx.x;
    if (idx >= LSEQ * DINNER) return;
    int d = idx % DINNER;
    int t = idx / DINNER;
    float w[4];
#pragma unroll
    for (int j = 0; j < 4; ++j) w[j] = conv_w[d * 4 + j];
    float acc = conv_b[d];
#pragma unroll
    for (int j = 0; j < 4; ++j) {
        int s = t - 3 + j;
        if (s >= 0) acc = fmaf(xz[(size_t)s * (2 * DINNER) + d], w[j], acc);
    }
    float sig = 1.f / (1.f + expf(-acc));
    u[idx] = acc * sig;
}

// ---------------- selective scan (faithful cumprod/cumsum-with-eps math) ----------------
// block: 256 threads = 16 d-channels x 16 states; grid: 1536/16 = 96 blocks
__global__ __launch_bounds__(256) void scan_kernel(
    const float* __restrict__ xz,     // z at col 1536+d, ld 3072
    const float* __restrict__ u,      // (L, 1536)
    const float* __restrict__ x_dbl,  // (L, 80): B at 48+n, C at 64+n
    const float* __restrict__ dtm,    // (L, 1536)
    const float* __restrict__ A_log,  // (1536, 16)
    const float* __restrict__ Dvec,   // (1536,)
    float* __restrict__ y)            // (L, 1536) gated output
{
    const int tid = threadIdx.x;
    const int n  = tid & 15;
    const int dl = tid >> 4;
    const int d  = blockIdx.x * 16 + dl;
    const float Acoef = -expf(A_log[d * DSTATE + n]);
    const float Dd = Dvec[d];
    const float eps = 1.1920928955078125e-07f;  // FLT_EPSILON
    float p = 1.f, g = 0.f;
    for (int t = 0; t < LSEQ; ++t) {
        float dtv = dtm[(size_t)t * DINNER + d];
        float uv  = u[(size_t)t * DINNER + d];
        float Bv  = x_dbl[(size_t)t * XDBL_W + DTRANK + n];
        float Cv  = x_dbl[(size_t)t * XDBL_W + DTRANK + DSTATE + n];
        float dA  = expf(dtv * Acoef);
        p = p * dA;                               // fp32 cumprod (underflow = reference behavior)
        float dBu = (dtv * Bv) * uv;
        g += dBu / fmaxf(p, eps);                 // IEEE div (no fast-math)
        float h = g * p;
        float part = h * Cv;
        part += __shfl_xor(part, 1, 16);
        part += __shfl_xor(part, 2, 16);
        part += __shfl_xor(part, 4, 16);
        part += __shfl_xor(part, 8, 16);
        if (n == 0) {
            float zv = xz[(size_t)t * (2 * DINNER) + DINNER + d];
            float sig = 1.f / (1.f + expf(-zv));
            y[(size_t)t * DINNER + d] = (part + Dd * uv) * (zv * sig);
        }
    }
}

// ---------------- launch ----------------
extern "C" void kernel_launch(void* const* d_in, const int* in_sizes, int n_in,
                              void* d_out, int out_size, void* d_ws, size_t ws_size,
                              hipStream_t stream) {
    const float* x          = (const float*)d_in[0];
    const float* in_proj_w  = (const float*)d_in[1];
    const float* conv_w     = (const float*)d_in[2];
    const float* conv_b     = (const float*)d_in[3];
    const float* x_proj_w   = (const float*)d_in[4];
    const float* dt_proj_w  = (const float*)d_in[5];
    const float* dt_proj_b  = (const float*)d_in[6];
    const float* A_log      = (const float*)d_in[7];
    const float* Dvec       = (const float*)d_in[8];
    const float* out_proj_w = (const float*)d_in[9];
    float* out = (float*)d_out;

    float* xz   = (float*)d_ws;                 // 2048*3072
    float* u    = xz   + (size_t)LSEQ * 2 * DINNER;
    float* xdbl = u    + (size_t)LSEQ * DINNER; // 2048*80
    float* dtb  = xdbl + (size_t)LSEQ * XDBL_W; // 2048*1536
    float* y    = dtb  + (size_t)LSEQ * DINNER; // 2048*1536

    dim3 blk(256);

    // 1. xz = x @ in_proj_w.T        (2048x768 * 768->3072)
    gemm_tn<0><<<dim3(LSEQ / 64, (2 * DINNER) / 64), blk, 0, stream>>>(
        x, DMODEL, in_proj_w, DMODEL, xz, 2 * DINNER, LSEQ, 2 * DINNER, DMODEL, nullptr);

    // 2. u = silu(depthwise_conv(xh) + b)
    conv_silu_kernel<<<(LSEQ * DINNER + 255) / 256, 256, 0, stream>>>(xz, conv_w, conv_b, u);

    // 3. x_dbl = u @ x_proj_w.T      (2048x1536 * 1536->80)
    gemm_tn<0><<<dim3(LSEQ / 64, (XDBL_W + 63) / 64), blk, 0, stream>>>(
        u, DINNER, x_proj_w, DINNER, xdbl, XDBL_W, LSEQ, XDBL_W, DINNER, nullptr);

    // 4. dt = softplus(x_dbl[:, :48] @ dt_proj_w.T + dt_proj_b)   (2048x48 * 48->1536)
    gemm_tn<1><<<dim3(LSEQ / 64, DINNER / 64), blk, 0, stream>>>(
        xdbl, XDBL_W, dt_proj_w, DTRANK, dtb, DINNER, LSEQ, DINNER, DTRANK, dt_proj_b);

    // 5. selective scan + D*u + gate by silu(z)
    scan_kernel<<<DINNER / 16, 256, 0, stream>>>(xz, u, xdbl, dtb, A_log, Dvec, y);

    // 6. out = y @ out_proj_w.T      (2048x1536 * 1536->768)
    gemm_tn<0><<<dim3(LSEQ / 64, DMODEL / 64), blk, 0, stream>>>(
        y, DINNER, out_proj_w, DINNER, out, DMODEL, LSEQ, DMODEL, DINNER, nullptr);
}

// Round 2
// 708.384 us; speedup vs baseline: 3.1845x; 3.1845x over previous
//
#include <hip/hip_runtime.h>
#include <hip/hip_bf16.h>

// ---------------- sizes ----------------
#define LSEQ 2048
#define DMODEL 768
#define DINNER 1536
#define DSTATE 16
#define DTRANK 48
#define XDBL_W (DTRANK + 2*DSTATE)   // 80
#define CHUNK 64
#define NCHUNK (LSEQ / CHUNK)        // 32
#define NDN (DINNER * DSTATE)        // 24576
#define FEPS 1.1920928955078125e-07f

// ---------------- generic tiled fp32 GEMM: C[m,n] = sum_k A[m*lda+k]*B[n*ldb+k] ----------------
// EPI: 0 = none, 1 = +bias then softplus
template<int EPI>
__global__ __launch_bounds__(256) void gemm_tn(
    const float* __restrict__ A, int lda,
    const float* __restrict__ B, int ldb,
    float* __restrict__ C, int ldc,
    int M, int N, int K,
    const float* __restrict__ bias)
{
    __shared__ float As[16][64 + 4];
    __shared__ float Bs[16][64 + 4];
    const int tid = threadIdx.x;
    const int m0 = blockIdx.x * 64;
    const int n0 = blockIdx.y * 64;
    const int tx = tid & 15;    // n sub-tile
    const int ty = tid >> 4;    // m sub-tile
    const int lr = tid >> 4;    // load row (16 rows/pass)
    const int lc = tid & 15;    // load k
    float acc[4][4] = {};

    for (int k0 = 0; k0 < K; k0 += 16) {
        const int k = k0 + lc;
#pragma unroll
        for (int i = 0; i < 4; ++i) {
            int m = m0 + lr + i * 16;
            float v = 0.f;
            if (m < M) v = A[(size_t)m * lda + k];
            As[lc][lr + i * 16] = v;
        }
#pragma unroll
        for (int i = 0; i < 4; ++i) {
            int n = n0 + lr + i * 16;
            float v = 0.f;
            if (n < N) v = B[(size_t)n * ldb + k];
            Bs[lc][lr + i * 16] = v;
        }
        __syncthreads();
#pragma unroll
        for (int kk = 0; kk < 16; ++kk) {
            float a[4], b[4];
#pragma unroll
            for (int i = 0; i < 4; ++i) a[i] = As[kk][ty * 4 + i];
#pragma unroll
            for (int j = 0; j < 4; ++j) b[j] = Bs[kk][tx * 4 + j];
#pragma unroll
            for (int i = 0; i < 4; ++i)
#pragma unroll
                for (int j = 0; j < 4; ++j)
                    acc[i][j] = fmaf(a[i], b[j], acc[i][j]);
        }
        __syncthreads();
    }

#pragma unroll
    for (int i = 0; i < 4; ++i) {
        int m = m0 + ty * 4 + i;
        if (m >= M) continue;
#pragma unroll
        for (int j = 0; j < 4; ++j) {
            int n = n0 + tx * 4 + j;
            if (n >= N) continue;
            float v = acc[i][j];
            if (EPI == 1) {
                v += bias[n];
                // jax.nn.softplus = max(x,0) + log1p(exp(-|x|))
                v = fmaxf(v, 0.f) + log1pf(expf(-fabsf(v)));
            }
            C[(size_t)m * ldc + n] = v;
        }
    }
}

// ---------------- depthwise causal conv1d (width 4) + SiLU ----------------
__global__ __launch_bounds__(256) void conv_silu_kernel(
    const float* __restrict__ xz,      // (L, 3072); xh = cols [0,1536)
    const float* __restrict__ conv_w,  // (1536, 4)
    const float* __restrict__ conv_b,  // (1536,)
    float* __restrict__ u)             // (L, 1536)
{
    int idx = blockIdx.x * blockDim.x + threadIdx.x;
    if (idx >= LSEQ * DINNER) return;
    int d = idx % DINNER;
    int t = idx / DINNER;
    float w[4];
#pragma unroll
    for (int j = 0; j < 4; ++j) w[j] = conv_w[d * 4 + j];
    float acc = conv_b[d];
#pragma unroll
    for (int j = 0; j < 4; ++j) {
        int s = t - 3 + j;
        if (s >= 0) acc = fmaf(xz[(size_t)s * (2 * DINNER) + d], w[j], acc);
    }
    float sig = 1.f / (1.f + expf(-acc));
    u[idx] = acc * sig;
}

// ================= chunked faithful scan =================
// grid: (96 d-groups, NCHUNK chunks); block 256 = 16 d x 16 n; tid = dl*16+n

// Phase 1: per-chunk product of dA (sequential within chunk, faithful rounding)
__global__ __launch_bounds__(256) void scan_chunkprod(
    const float* __restrict__ dtm,    // (L, 1536)
    const float* __restrict__ A_log,  // (1536, 16)
    float* __restrict__ P)            // (NCHUNK, 24576)
{
    __shared__ float sdt[CHUNK][16];
    const int tid = threadIdx.x;
    const int d0 = blockIdx.x * 16;
    const int t0 = blockIdx.y * CHUNK;
    const int r = tid >> 4, c = tid & 15;
#pragma unroll
    for (int i = 0; i < CHUNK / 16; ++i) {
        int t = r + i * 16;
        sdt[t][c] = dtm[(size_t)(t0 + t) * DINNER + d0 + c];
    }
    __syncthreads();
    const int n = tid & 15, dl = tid >> 4;
    const float Acoef = -expf(A_log[(d0 + dl) * DSTATE + n]);
    float p = 1.f;
    for (int t = 0; t < CHUNK; ++t)
        p *= expf(sdt[t][dl] * Acoef);
    P[(size_t)blockIdx.y * NDN + d0 * DSTATE + tid] = p;
}

// Phase 2/3b: in-place exclusive scan over chunks (left-to-right). PROD=1: product, else sum.
template<int PROD>
__global__ __launch_bounds__(256) void scan_exclusive(float* __restrict__ buf)
{
    const int dn = blockIdx.x * 256 + threadIdx.x;
    float run = PROD ? 1.f : 0.f;
    for (int cidx = 0; cidx < NCHUNK; ++cidx) {
        float v = buf[(size_t)cidx * NDN + dn];
        buf[(size_t)cidx * NDN + dn] = run;
        run = PROD ? run * v : run + v;
    }
}

// Phase 3a: per-chunk sum of dBu/max(p,eps), with p seeded by prefix product
__global__ __launch_bounds__(256) void scan_chunksum(
    const float* __restrict__ dtm,
    const float* __restrict__ u,
    const float* __restrict__ xdbl,   // (L, 80): B at col 48+n
    const float* __restrict__ A_log,
    const float* __restrict__ Ppre,   // exclusive prefix products
    float* __restrict__ S)
{
    __shared__ float sdt[CHUNK][16], su[CHUNK][16], sB[CHUNK][16];
    const int tid = threadIdx.x;
    const int d0 = blockIdx.x * 16;
    const int t0 = blockIdx.y * CHUNK;
    const int r = tid >> 4, c = tid & 15;
#pragma unroll
    for (int i = 0; i < CHUNK / 16; ++i) {
        int t = r + i * 16;
        size_t row = (size_t)(t0 + t);
        sdt[t][c] = dtm[row * DINNER + d0 + c];
        su[t][c]  = u[row * DINNER + d0 + c];
        sB[t][c]  = xdbl[row * XDBL_W + DTRANK + c];
    }
    __syncthreads();
    const int n = tid & 15, dl = tid >> 4;
    const float Acoef = -expf(A_log[(d0 + dl) * DSTATE + n]);
    float p = Ppre[(size_t)blockIdx.y * NDN + d0 * DSTATE + tid];
    float s = 0.f;
    for (int t = 0; t < CHUNK; ++t) {
        float dtv = sdt[t][dl];
        float dA = expf(dtv * Acoef);
        p *= dA;
        float w = (dtv * sB[t][n]) * su[t][dl] / fmaxf(p, FEPS);
        s += w;
    }
    S[(size_t)blockIdx.y * NDN + d0 * DSTATE + tid] = s;
}

// Phase 3c: final pass — h = g*p, reduce over n, add D*u, gate with silu(z),
// write y into the dead xh slots of xz (stride 3072).
__global__ __launch_bounds__(256) void scan_final(
    const float* __restrict__ dtm,
    const float* __restrict__ u,
    const float* __restrict__ xdbl,
    const float* __restrict__ A_log,
    const float* __restrict__ Dvec,
    const float* __restrict__ Ppre,
    const float* __restrict__ Gpre,
    float* __restrict__ xz)           // z read (cols 1536+), y written (cols 0..1535)
{
    __shared__ float sdt[CHUNK][16], su[CHUNK][16], sB[CHUNK][16], sC[CHUNK][16], sz[CHUNK][16];
    const int tid = threadIdx.x;
    const int d0 = blockIdx.x * 16;
    const int t0 = blockIdx.y * CHUNK;
    const int r = tid >> 4, c = tid & 15;
#pragma unroll
    for (int i = 0; i < CHUNK / 16; ++i) {
        int t = r + i * 16;
        size_t row = (size_t)(t0 + t);
        sdt[t][c] = dtm[row * DINNER + d0 + c];
        su[t][c]  = u[row * DINNER + d0 + c];
        sB[t][c]  = xdbl[row * XDBL_W + DTRANK + c];
        sC[t][c]  = xdbl[row * XDBL_W + DTRANK + DSTATE + c];
        sz[t][c]  = xz[row * (size_t)(2 * DINNER) + DINNER + d0 + c];
    }
    __syncthreads();
    const int n = tid & 15, dl = tid >> 4;
    const int d = d0 + dl;
    const float Acoef = -expf(A_log[d * DSTATE + n]);
    const float Dd = Dvec[d];
    float p = Ppre[(size_t)blockIdx.y * NDN + d0 * DSTATE + tid];
    float g = Gpre[(size_t)blockIdx.y * NDN + d0 * DSTATE + tid];
    for (int t = 0; t < CHUNK; ++t) {
        float dtv = sdt[t][dl];
        float dA = expf(dtv * Acoef);
        p *= dA;
        float w = (dtv * sB[t][n]) * su[t][dl] / fmaxf(p, FEPS);
        g += w;
        float part = (g * p) * sC[t][n];
        part += __shfl_xor(part, 1, 16);
        part += __shfl_xor(part, 2, 16);
        part += __shfl_xor(part, 4, 16);
        part += __shfl_xor(part, 8, 16);
        if (n == 0) {
            float zv = sz[t][dl];
            float sig = 1.f / (1.f + expf(-zv));
            xz[(size_t)(t0 + t) * (2 * DINNER) + d] = (part + Dd * su[t][dl]) * (zv * sig);
        }
    }
}

// ---------------- launch ----------------
extern "C" void kernel_launch(void* const* d_in, const int* in_sizes, int n_in,
                              void* d_out, int out_size, void* d_ws, size_t ws_size,
                              hipStream_t stream) {
    const float* x          = (const float*)d_in[0];
    const float* in_proj_w  = (const float*)d_in[1];
    const float* conv_w     = (const float*)d_in[2];
    const float* conv_b     = (const float*)d_in[3];
    const float* x_proj_w   = (const float*)d_in[4];
    const float* dt_proj_w  = (const float*)d_in[5];
    const float* dt_proj_b  = (const float*)d_in[6];
    const float* A_log      = (const float*)d_in[7];
    const float* Dvec       = (const float*)d_in[8];
    const float* out_proj_w = (const float*)d_in[9];
    float* out = (float*)d_out;

    float* xz   = (float*)d_ws;                 // 2048*3072 (y overlaid in xh slots later)
    float* u    = xz   + (size_t)LSEQ * 2 * DINNER;
    float* xdbl = u    + (size_t)LSEQ * DINNER; // 2048*80
    float* dtb  = xdbl + (size_t)LSEQ * XDBL_W; // 2048*1536
    float* P    = dtb  + (size_t)LSEQ * DINNER; // NCHUNK*24576
    float* S    = P    + (size_t)NCHUNK * NDN;  // NCHUNK*24576

    dim3 blk(256);

    // 1. xz = x @ in_proj_w.T        (2048x768 -> 3072)
    gemm_tn<0><<<dim3(LSEQ / 64, (2 * DINNER) / 64), blk, 0, stream>>>(
        x, DMODEL, in_proj_w, DMODEL, xz, 2 * DINNER, LSEQ, 2 * DINNER, DMODEL, nullptr);

    // 2. u = silu(depthwise_conv(xh) + b)
    conv_silu_kernel<<<(LSEQ * DINNER + 255) / 256, 256, 0, stream>>>(xz, conv_w, conv_b, u);

    // 3. x_dbl = u @ x_proj_w.T      (2048x1536 -> 80)
    gemm_tn<0><<<dim3(LSEQ / 64, (XDBL_W + 63) / 64), blk, 0, stream>>>(
        u, DINNER, x_proj_w, DINNER, xdbl, XDBL_W, LSEQ, XDBL_W, DINNER, nullptr);

    // 4. dt = softplus(x_dbl[:, :48] @ dt_proj_w.T + dt_proj_b)   (2048x48 -> 1536)
    gemm_tn<1><<<dim3(LSEQ / 64, DINNER / 64), blk, 0, stream>>>(
        xdbl, XDBL_W, dt_proj_w, DTRANK, dtb, DINNER, LSEQ, DINNER, DTRANK, dt_proj_b);

    // 5. chunked faithful selective scan
    scan_chunkprod<<<dim3(DINNER / 16, NCHUNK), blk, 0, stream>>>(dtb, A_log, P);
    scan_exclusive<1><<<NDN / 256, blk, 0, stream>>>(P);
    scan_chunksum<<<dim3(DINNER / 16, NCHUNK), blk, 0, stream>>>(dtb, u, xdbl, A_log, P, S);
    scan_exclusive<0><<<NDN / 256, blk, 0, stream>>>(S);
    scan_final<<<dim3(DINNER / 16, NCHUNK), blk, 0, stream>>>(dtb, u, xdbl, A_log, Dvec, P, S, xz);

    // 6. out = y @ out_proj_w.T      (y lives in xz with ld 3072)
    gemm_tn<0><<<dim3(LSEQ / 64, DMODEL / 64), blk, 0, stream>>>(
        xz, 2 * DINNER, out_proj_w, DINNER, out, DMODEL, LSEQ, DMODEL, DINNER, nullptr);
}

// Round 3
// 345.335 us; speedup vs baseline: 6.5323x; 2.0513x over previous
//
#include <hip/hip_runtime.h>
#include <hip/hip_bf16.h>

// ---------------- sizes ----------------
#define LSEQ 2048
#define DMODEL 768
#define DINNER 1536
#define DSTATE 16
#define DTRANK 48
#define XDBL_W (DTRANK + 2*DSTATE)   // 80
#define CHUNK 64
#define NCHUNK (LSEQ / CHUNK)        // 32
#define NDN (DINNER * DSTATE)        // 24576
#define FEPS 1.1920928955078125e-07f
#define SPLITK 8

typedef short bf16x8 __attribute__((ext_vector_type(8)));
typedef float f32x4 __attribute__((ext_vector_type(4)));
typedef unsigned short u16;

__device__ __forceinline__ u16 f2bf_rn(float f) {
    unsigned u = __float_as_uint(f);
    unsigned r = u + 0x7FFFu + ((u >> 16) & 1u);
    return (u16)(r >> 16);
}
__device__ __forceinline__ float bf2f(u16 h) {
    return __uint_as_float(((unsigned)h) << 16);
}

// ---------------- fp32 -> bf16 hi/lo split conversion ----------------
__global__ __launch_bounds__(256) void cvt_split(
    const float* __restrict__ src, u16* __restrict__ hi, u16* __restrict__ lo, int n)
{
    int i = (blockIdx.x * 256 + threadIdx.x) * 4;
    if (i >= n) return;
    float4 v = *(const float4*)&src[i];
    u16 h0 = f2bf_rn(v.x), h1 = f2bf_rn(v.y), h2 = f2bf_rn(v.z), h3 = f2bf_rn(v.w);
    u16 l0 = f2bf_rn(v.x - bf2f(h0));
    u16 l1 = f2bf_rn(v.y - bf2f(h1));
    u16 l2 = f2bf_rn(v.z - bf2f(h2));
    u16 l3 = f2bf_rn(v.w - bf2f(h3));
    ushort4 hv = make_ushort4(h0, h1, h2, h3);
    ushort4 lv = make_ushort4(l0, l1, l2, l3);
    *(ushort4*)&hi[i] = hv;
    *(ushort4*)&lo[i] = lv;
}

// ---------------- split-bf16 MFMA GEMM: C[m,n] = sum_k A[m][k]*B[n][k] ----------------
// 128x128 tile, 4 waves (each 64x64), BK=32. A,B as bf16 hi/lo planes, ld = K.
__global__ __launch_bounds__(256) void mfma_gemm_tn(
    const u16* __restrict__ Ahi, const u16* __restrict__ Alo,
    const u16* __restrict__ Bhi, const u16* __restrict__ Blo,
    float* __restrict__ C, int ldc, int K)
{
    __shared__ u16 lds[4 * 4096];   // planes: Ahi, Alo, Bhi, Blo (128x32 each, 8KB)
    const int tid = threadIdx.x;
    const int wid = tid >> 6;
    const int lane = tid & 63;
    const int m0 = blockIdx.x * 128;
    const int n0 = blockIdx.y * 128;

    // staging: wave wid stages plane wid; 8 issues of 1KB; linear LDS dest,
    // pre-swizzled global source (chunk' = chunk ^ ((row>>1)&3))
    const int st_subrow = lane >> 2;   // 0..15
    const int st_cphys = lane & 3;
    const u16* myplane = (wid == 0) ? Ahi : (wid == 1) ? Alo : (wid == 2) ? Bhi : Blo;
    const int rowbase = (wid < 2) ? m0 : n0;

    f32x4 acc[4][4] = {};
    const int wm = (wid >> 1) * 64;
    const int wn = (wid & 1) * 64;
    const int fr = lane & 15;
    const int fc = lane >> 4;

    for (int k0 = 0; k0 < K; k0 += 32) {
#pragma unroll
        for (int j = 0; j < 8; ++j) {
            int row = j * 16 + st_subrow;                       // 0..127
            int clog = st_cphys ^ ((row >> 1) & 3);
            const u16* g = myplane + (size_t)(rowbase + row) * K + k0 + clog * 8;
            u16* l = &lds[wid * 4096 + j * 512];
            __builtin_amdgcn_global_load_lds(
                (const __attribute__((address_space(1))) unsigned int*)g,
                (__attribute__((address_space(3))) unsigned int*)l, 16, 0, 0);
        }
        __syncthreads();   // drains vmcnt (global_load_lds) + lgkm

        bf16x8 ah[4], al[4], bh[4], bl[4];
        const bf16x8* L = (const bf16x8*)lds;
#pragma unroll
        for (int mi = 0; mi < 4; ++mi) {
            int r = wm + mi * 16 + fr;
            int idx = r * 4 + (fc ^ ((r >> 1) & 3));
            ah[mi] = L[idx];
            al[mi] = L[512 + idx];
        }
#pragma unroll
        for (int nj = 0; nj < 4; ++nj) {
            int r = wn + nj * 16 + fr;
            int idx = r * 4 + (fc ^ ((r >> 1) & 3));
            bh[nj] = L[1024 + idx];
            bl[nj] = L[1536 + idx];
        }
#pragma unroll
        for (int mi = 0; mi < 4; ++mi)
#pragma unroll
            for (int nj = 0; nj < 4; ++nj) {
                acc[mi][nj] = __builtin_amdgcn_mfma_f32_16x16x32_bf16(ah[mi], bh[nj], acc[mi][nj], 0, 0, 0);
                acc[mi][nj] = __builtin_amdgcn_mfma_f32_16x16x32_bf16(ah[mi], bl[nj], acc[mi][nj], 0, 0, 0);
                acc[mi][nj] = __builtin_amdgcn_mfma_f32_16x16x32_bf16(al[mi], bh[nj], acc[mi][nj], 0, 0, 0);
            }
        __syncthreads();   // protect LDS before next stage
    }

#pragma unroll
    for (int mi = 0; mi < 4; ++mi) {
        int row_b = m0 + wm + mi * 16 + (lane >> 4) * 4;
#pragma unroll
        for (int nj = 0; nj < 4; ++nj) {
            int col = n0 + wn + nj * 16 + (lane & 15);
#pragma unroll
            for (int r = 0; r < 4; ++r)
                C[(size_t)(row_b + r) * ldc + col] = acc[mi][nj][r];
        }
    }
}

// ---------------- fp32 tiled GEMM (kept for dt_proj): C[m,n]=sum_k A[m][k]*B[n][k] ----------------
template<int EPI>
__global__ __launch_bounds__(256) void gemm_tn(
    const float* __restrict__ A, int lda,
    const float* __restrict__ B, int ldb,
    float* __restrict__ C, int ldc,
    int M, int N, int K,
    const float* __restrict__ bias)
{
    __shared__ float As[16][64 + 4];
    __shared__ float Bs[16][64 + 4];
    const int tid = threadIdx.x;
    const int m0 = blockIdx.x * 64;
    const int n0 = blockIdx.y * 64;
    const int tx = tid & 15;
    const int ty = tid >> 4;
    const int lr = tid >> 4;
    const int lc = tid & 15;
    float acc[4][4] = {};

    for (int k0 = 0; k0 < K; k0 += 16) {
        const int k = k0 + lc;
#pragma unroll
        for (int i = 0; i < 4; ++i) {
            int m = m0 + lr + i * 16;
            As[lc][lr + i * 16] = (m < M) ? A[(size_t)m * lda + k] : 0.f;
        }
#pragma unroll
        for (int i = 0; i < 4; ++i) {
            int n = n0 + lr + i * 16;
            Bs[lc][lr + i * 16] = (n < N) ? B[(size_t)n * ldb + k] : 0.f;
        }
        __syncthreads();
#pragma unroll
        for (int kk = 0; kk < 16; ++kk) {
            float a[4], b[4];
#pragma unroll
            for (int i = 0; i < 4; ++i) a[i] = As[kk][ty * 4 + i];
#pragma unroll
            for (int j = 0; j < 4; ++j) b[j] = Bs[kk][tx * 4 + j];
#pragma unroll
            for (int i = 0; i < 4; ++i)
#pragma unroll
                for (int j = 0; j < 4; ++j)
                    acc[i][j] = fmaf(a[i], b[j], acc[i][j]);
        }
        __syncthreads();
    }

#pragma unroll
    for (int i = 0; i < 4; ++i) {
        int m = m0 + ty * 4 + i;
        if (m >= M) continue;
#pragma unroll
        for (int j = 0; j < 4; ++j) {
            int n = n0 + tx * 4 + j;
            if (n >= N) continue;
            float v = acc[i][j];
            if (EPI == 1) {
                v += bias[n];
                v = fmaxf(v, 0.f) + log1pf(expf(-fabsf(v)));
            }
            C[(size_t)m * ldc + n] = v;
        }
    }
}

// ---------------- fp32 split-K GEMM for x_proj (deterministic two-pass) ----------------
__global__ __launch_bounds__(256) void gemm_tn_splitk(
    const float* __restrict__ A, int lda,
    const float* __restrict__ B, int ldb,
    float* __restrict__ Cpart, int ldc,
    int M, int N, int Kchunk)
{
    __shared__ float As[16][64 + 4];
    __shared__ float Bs[16][64 + 4];
    const int tid = threadIdx.x;
    const int m0 = blockIdx.x * 64;
    const int n0 = blockIdx.y * 64;
    const int kb = blockIdx.z * Kchunk;
    const int tx = tid & 15;
    const int ty = tid >> 4;
    const int lr = tid >> 4;
    const int lc = tid & 15;
    float acc[4][4] = {};

    for (int k0 = kb; k0 < kb + Kchunk; k0 += 16) {
        const int k = k0 + lc;
#pragma unroll
        for (int i = 0; i < 4; ++i) {
            int m = m0 + lr + i * 16;
            As[lc][lr + i * 16] = (m < M) ? A[(size_t)m * lda + k] : 0.f;
        }
#pragma unroll
        for (int i = 0; i < 4; ++i) {
            int n = n0 + lr + i * 16;
            Bs[lc][lr + i * 16] = (n < N) ? B[(size_t)n * ldb + k] : 0.f;
        }
        __syncthreads();
#pragma unroll
        for (int kk = 0; kk < 16; ++kk) {
            float a[4], b[4];
#pragma unroll
            for (int i = 0; i < 4; ++i) a[i] = As[kk][ty * 4 + i];
#pragma unroll
            for (int j = 0; j < 4; ++j) b[j] = Bs[kk][tx * 4 + j];
#pragma unroll
            for (int i = 0; i < 4; ++i)
#pragma unroll
                for (int j = 0; j < 4; ++j)
                    acc[i][j] = fmaf(a[i], b[j], acc[i][j]);
        }
        __syncthreads();
    }

    float* Cs = Cpart + (size_t)blockIdx.z * M * ldc;
#pragma unroll
    for (int i = 0; i < 4; ++i) {
        int m = m0 + ty * 4 + i;
        if (m >= M) continue;
#pragma unroll
        for (int j = 0; j < 4; ++j) {
            int n = n0 + tx * 4 + j;
            if (n >= N) continue;
            Cs[(size_t)m * ldc + n] = acc[i][j];
        }
    }
}

__global__ __launch_bounds__(256) void splitk_reduce(
    const float* __restrict__ Ppart, float* __restrict__ out, int n)
{
    int i = blockIdx.x * 256 + threadIdx.x;
    if (i >= n) return;
    float s = 0.f;
#pragma unroll
    for (int z = 0; z < SPLITK; ++z) s += Ppart[(size_t)z * n + i];
    out[i] = s;
}

// ---------------- depthwise causal conv1d (width 4) + SiLU ----------------
__global__ __launch_bounds__(256) void conv_silu_kernel(
    const float* __restrict__ xz,
    const float* __restrict__ conv_w,
    const float* __restrict__ conv_b,
    float* __restrict__ u)
{
    int idx = blockIdx.x * blockDim.x + threadIdx.x;
    if (idx >= LSEQ * DINNER) return;
    int d = idx % DINNER;
    int t = idx / DINNER;
    float w[4];
#pragma unroll
    for (int j = 0; j < 4; ++j) w[j] = conv_w[d * 4 + j];
    float acc = conv_b[d];
#pragma unroll
    for (int j = 0; j < 4; ++j) {
        int s = t - 3 + j;
        if (s >= 0) acc = fmaf(xz[(size_t)s * (2 * DINNER) + d], w[j], acc);
    }
    float sig = 1.f / (1.f + expf(-acc));
    u[idx] = acc * sig;
}

// ================= chunked faithful scan =================
__global__ __launch_bounds__(256) void scan_chunkprod(
    const float* __restrict__ dtm,
    const float* __restrict__ A_log,
    float* __restrict__ P)
{
    __shared__ float sdt[CHUNK][16];
    const int tid = threadIdx.x;
    const int d0 = blockIdx.x * 16;
    const int t0 = blockIdx.y * CHUNK;
    const int r = tid >> 4, c = tid & 15;
#pragma unroll
    for (int i = 0; i < CHUNK / 16; ++i) {
        int t = r + i * 16;
        sdt[t][c] = dtm[(size_t)(t0 + t) * DINNER + d0 + c];
    }
    __syncthreads();
    const int n = tid & 15, dl = tid >> 4;
    const float Acoef = -expf(A_log[(d0 + dl) * DSTATE + n]);
    float p = 1.f;
    for (int t = 0; t < CHUNK; ++t)
        p *= expf(sdt[t][dl] * Acoef);
    P[(size_t)blockIdx.y * NDN + d0 * DSTATE + tid] = p;
}

template<int PROD>
__global__ __launch_bounds__(256) void scan_exclusive(float* __restrict__ buf)
{
    const int dn = blockIdx.x * 256 + threadIdx.x;
    float run = PROD ? 1.f : 0.f;
    for (int cidx = 0; cidx < NCHUNK; ++cidx) {
        float v = buf[(size_t)cidx * NDN + dn];
        buf[(size_t)cidx * NDN + dn] = run;
        run = PROD ? run * v : run + v;
    }
}

__global__ __launch_bounds__(256) void scan_chunksum(
    const float* __restrict__ dtm,
    const float* __restrict__ u,
    const float* __restrict__ xdbl,
    const float* __restrict__ A_log,
    const float* __restrict__ Ppre,
    float* __restrict__ S)
{
    __shared__ float sdt[CHUNK][16], su[CHUNK][16], sB[CHUNK][16];
    const int tid = threadIdx.x;
    const int d0 = blockIdx.x * 16;
    const int t0 = blockIdx.y * CHUNK;
    const int r = tid >> 4, c = tid & 15;
#pragma unroll
    for (int i = 0; i < CHUNK / 16; ++i) {
        int t = r + i * 16;
        size_t row = (size_t)(t0 + t);
        sdt[t][c] = dtm[row * DINNER + d0 + c];
        su[t][c]  = u[row * DINNER + d0 + c];
        sB[t][c]  = xdbl[row * XDBL_W + DTRANK + c];
    }
    __syncthreads();
    const int n = tid & 15, dl = tid >> 4;
    const float Acoef = -expf(A_log[(d0 + dl) * DSTATE + n]);
    float p = Ppre[(size_t)blockIdx.y * NDN + d0 * DSTATE + tid];
    float s = 0.f;
    for (int t = 0; t < CHUNK; ++t) {
        float dtv = sdt[t][dl];
        float dA = expf(dtv * Acoef);
        p *= dA;
        float w = (dtv * sB[t][n]) * su[t][dl] / fmaxf(p, FEPS);
        s += w;
    }
    S[(size_t)blockIdx.y * NDN + d0 * DSTATE + tid] = s;
}

// final pass: h=g*p, reduce over n, +D*u, gate silu(z); emit y as bf16 hi/lo planes
__global__ __launch_bounds__(256) void scan_final(
    const float* __restrict__ dtm,
    const float* __restrict__ u,
    const float* __restrict__ xdbl,
    const float* __restrict__ A_log,
    const float* __restrict__ Dvec,
    const float* __restrict__ Ppre,
    const float* __restrict__ Gpre,
    const float* __restrict__ xz,      // z read (cols 1536+)
    u16* __restrict__ yhi, u16* __restrict__ ylo)
{
    __shared__ float sdt[CHUNK][16], su[CHUNK][16], sB[CHUNK][16], sC[CHUNK][16], sz[CHUNK][16];
    const int tid = threadIdx.x;
    const int d0 = blockIdx.x * 16;
    const int t0 = blockIdx.y * CHUNK;
    const int r = tid >> 4, c = tid & 15;
#pragma unroll
    for (int i = 0; i < CHUNK / 16; ++i) {
        int t = r + i * 16;
        size_t row = (size_t)(t0 + t);
        sdt[t][c] = dtm[row * DINNER + d0 + c];
        su[t][c]  = u[row * DINNER + d0 + c];
        sB[t][c]  = xdbl[row * XDBL_W + DTRANK + c];
        sC[t][c]  = xdbl[row * XDBL_W + DTRANK + DSTATE + c];
        sz[t][c]  = xz[row * (size_t)(2 * DINNER) + DINNER + d0 + c];
    }
    __syncthreads();
    const int n = tid & 15, dl = tid >> 4;
    const int d = d0 + dl;
    const float Acoef = -expf(A_log[d * DSTATE + n]);
    const float Dd = Dvec[d];
    float p = Ppre[(size_t)blockIdx.y * NDN + d0 * DSTATE + tid];
    float g = Gpre[(size_t)blockIdx.y * NDN + d0 * DSTATE + tid];
    for (int t = 0; t < CHUNK; ++t) {
        float dtv = sdt[t][dl];
        float dA = expf(dtv * Acoef);
        p *= dA;
        float w = (dtv * sB[t][n]) * su[t][dl] / fmaxf(p, FEPS);
        g += w;
        float part = (g * p) * sC[t][n];
        part += __shfl_xor(part, 1, 16);
        part += __shfl_xor(part, 2, 16);
        part += __shfl_xor(part, 4, 16);
        part += __shfl_xor(part, 8, 16);
        if (n == 0) {
            float zv = sz[t][dl];
            float sig = 1.f / (1.f + expf(-zv));
            float yv = (part + Dd * su[t][dl]) * (zv * sig);
            u16 h = f2bf_rn(yv);
            u16 l = f2bf_rn(yv - bf2f(h));
            yhi[(size_t)(t0 + t) * DINNER + d] = h;
            ylo[(size_t)(t0 + t) * DINNER + d] = l;
        }
    }
}

// ---------------- launch ----------------
extern "C" void kernel_launch(void* const* d_in, const int* in_sizes, int n_in,
                              void* d_out, int out_size, void* d_ws, size_t ws_size,
                              hipStream_t stream) {
    const float* x          = (const float*)d_in[0];
    const float* in_proj_w  = (const float*)d_in[1];
    const float* conv_w     = (const float*)d_in[2];
    const float* conv_b     = (const float*)d_in[3];
    const float* x_proj_w   = (const float*)d_in[4];
    const float* dt_proj_w  = (const float*)d_in[5];
    const float* dt_proj_b  = (const float*)d_in[6];
    const float* A_log      = (const float*)d_in[7];
    const float* Dvec       = (const float*)d_in[8];
    const float* out_proj_w = (const float*)d_in[9];
    float* out = (float*)d_out;

    char* w = (char*)d_ws;
    auto alloc = [&](size_t bytes) { char* p = w; w += (bytes + 255) & ~(size_t)255; return p; };

    float* xz    = (float*)alloc((size_t)LSEQ * 2 * DINNER * 4);
    float* u     = (float*)alloc((size_t)LSEQ * DINNER * 4);
    float* xdbl  = (float*)alloc((size_t)LSEQ * XDBL_W * 4);
    float* dtb   = (float*)alloc((size_t)LSEQ * DINNER * 4);
    float* P     = (float*)alloc((size_t)NCHUNK * NDN * 4);
    float* S     = (float*)alloc((size_t)NCHUNK * NDN * 4);
    float* Ppart = (float*)alloc((size_t)SPLITK * LSEQ * XDBL_W * 4);
    u16* xhi  = (u16*)alloc((size_t)LSEQ * DMODEL * 2);
    u16* xlo  = (u16*)alloc((size_t)LSEQ * DMODEL * 2);
    u16* wihi = (u16*)alloc((size_t)2 * DINNER * DMODEL * 2);
    u16* wilo = (u16*)alloc((size_t)2 * DINNER * DMODEL * 2);
    u16* owhi = (u16*)alloc((size_t)DMODEL * DINNER * 2);
    u16* owlo = (u16*)alloc((size_t)DMODEL * DINNER * 2);
    u16* yhi  = (u16*)alloc((size_t)LSEQ * DINNER * 2);
    u16* ylo  = (u16*)alloc((size_t)LSEQ * DINNER * 2);

    dim3 blk(256);

    // 0. conversions to bf16 hi/lo
    cvt_split<<<(LSEQ * DMODEL) / 1024, blk, 0, stream>>>(x, xhi, xlo, LSEQ * DMODEL);
    cvt_split<<<(2 * DINNER * DMODEL) / 1024, blk, 0, stream>>>(in_proj_w, wihi, wilo, 2 * DINNER * DMODEL);
    cvt_split<<<(DMODEL * DINNER) / 1024, blk, 0, stream>>>(out_proj_w, owhi, owlo, DMODEL * DINNER);

    // 1. xz = x @ in_proj_w.T   (M=2048, N=3072, K=768) via split-bf16 MFMA
    mfma_gemm_tn<<<dim3(LSEQ / 128, (2 * DINNER) / 128), blk, 0, stream>>>(
        xhi, xlo, wihi, wilo, xz, 2 * DINNER, DMODEL);

    // 2. u = silu(depthwise_conv(xh) + b)
    conv_silu_kernel<<<(LSEQ * DINNER + 255) / 256, blk, 0, stream>>>(xz, conv_w, conv_b, u);

    // 3. x_dbl = u @ x_proj_w.T (M=2048, N=80, K=1536) split-K fp32, deterministic reduce
    gemm_tn_splitk<<<dim3(LSEQ / 64, (XDBL_W + 63) / 64, SPLITK), blk, 0, stream>>>(
        u, DINNER, x_proj_w, DINNER, Ppart, XDBL_W, LSEQ, XDBL_W, DINNER / SPLITK);
    splitk_reduce<<<(LSEQ * XDBL_W + 255) / 256, blk, 0, stream>>>(Ppart, xdbl, LSEQ * XDBL_W);

    // 4. dt = softplus(x_dbl[:, :48] @ dt_proj_w.T + dt_proj_b)
    gemm_tn<1><<<dim3(LSEQ / 64, DINNER / 64), blk, 0, stream>>>(
        xdbl, XDBL_W, dt_proj_w, DTRANK, dtb, DINNER, LSEQ, DINNER, DTRANK, dt_proj_b);

    // 5. chunked faithful selective scan (y emitted as bf16 hi/lo)
    scan_chunkprod<<<dim3(DINNER / 16, NCHUNK), blk, 0, stream>>>(dtb, A_log, P);
    scan_exclusive<1><<<NDN / 256, blk, 0, stream>>>(P);
    scan_chunksum<<<dim3(DINNER / 16, NCHUNK), blk, 0, stream>>>(dtb, u, xdbl, A_log, P, S);
    scan_exclusive<0><<<NDN / 256, blk, 0, stream>>>(S);
    scan_final<<<dim3(DINNER / 16, NCHUNK), blk, 0, stream>>>(
        dtb, u, xdbl, A_log, Dvec, P, S, xz, yhi, ylo);

    // 6. out = y @ out_proj_w.T (M=2048, N=768, K=1536) via split-bf16 MFMA
    mfma_gemm_tn<<<dim3(LSEQ / 128, DMODEL / 128), blk, 0, stream>>>(
        yhi, ylo, owhi, owlo, out, DMODEL, DINNER);
}

// Round 6
// 311.681 us; speedup vs baseline: 7.2376x; 1.1080x over previous
//
#include <hip/hip_runtime.h>
#include <hip/hip_bf16.h>

// ---------------- sizes ----------------
#define LSEQ 2048
#define DMODEL 768
#define DINNER 1536
#define DSTATE 16
#define DTRANK 48
#define XDBL_W (DTRANK + 2*DSTATE)   // 80
#define CHUNK 64
#define NCHUNK (LSEQ / CHUNK)        // 32
#define NDN (DINNER * DSTATE)        // 24576
#define FEPS 1.1920928955078125e-07f
#define SPLITK 8

typedef short bf16x8 __attribute__((ext_vector_type(8)));
typedef float f32x4 __attribute__((ext_vector_type(4)));
typedef unsigned short u16;

__device__ __forceinline__ u16 f2bf_rn(float f) {
    unsigned u = __float_as_uint(f);
    unsigned r = u + 0x7FFFu + ((u >> 16) & 1u);
    return (u16)(r >> 16);
}
__device__ __forceinline__ float bf2f(u16 h) {
    return __uint_as_float(((unsigned)h) << 16);
}

// ---------------- fp32 -> bf16 hi/lo split conversion ----------------
__global__ __launch_bounds__(256) void cvt_split(
    const float* __restrict__ src, u16* __restrict__ hi, u16* __restrict__ lo, int n)
{
    int i = (blockIdx.x * 256 + threadIdx.x) * 4;
    if (i >= n) return;
    float4 v = *(const float4*)&src[i];
    u16 h0 = f2bf_rn(v.x), h1 = f2bf_rn(v.y), h2 = f2bf_rn(v.z), h3 = f2bf_rn(v.w);
    u16 l0 = f2bf_rn(v.x - bf2f(h0));
    u16 l1 = f2bf_rn(v.y - bf2f(h1));
    u16 l2 = f2bf_rn(v.z - bf2f(h2));
    u16 l3 = f2bf_rn(v.w - bf2f(h3));
    ushort4 hv = make_ushort4(h0, h1, h2, h3);
    ushort4 lv = make_ushort4(l0, l1, l2, l3);
    *(ushort4*)&hi[i] = hv;
    *(ushort4*)&lo[i] = lv;
}

// ---------------- split-bf16 MFMA GEMM: C[m,n] = sum_k A[m][k]*B[n][k] ----------------
// 128x128 tile, 4 waves (each 64x64), BK=32. A,B as bf16 hi/lo planes, ld = K.
__global__ __launch_bounds__(256) void mfma_gemm_tn(
    const u16* __restrict__ Ahi, const u16* __restrict__ Alo,
    const u16* __restrict__ Bhi, const u16* __restrict__ Blo,
    float* __restrict__ C, int ldc, int K)
{
    __shared__ u16 lds[4 * 4096];   // planes: Ahi, Alo, Bhi, Blo (128x32 each, 8KB)
    const int tid = threadIdx.x;
    const int wid = tid >> 6;
    const int lane = tid & 63;
    const int m0 = blockIdx.x * 128;
    const int n0 = blockIdx.y * 128;

    const int st_subrow = lane >> 2;   // 0..15
    const int st_cphys = lane & 3;
    const u16* myplane = (wid == 0) ? Ahi : (wid == 1) ? Alo : (wid == 2) ? Bhi : Blo;
    const int rowbase = (wid < 2) ? m0 : n0;

    f32x4 acc[4][4] = {};
    const int wm = (wid >> 1) * 64;
    const int wn = (wid & 1) * 64;
    const int fr = lane & 15;
    const int fc = lane >> 4;

    for (int k0 = 0; k0 < K; k0 += 32) {
#pragma unroll
        for (int j = 0; j < 8; ++j) {
            int row = j * 16 + st_subrow;                       // 0..127
            int clog = st_cphys ^ ((row >> 1) & 3);
            const u16* g = myplane + (size_t)(rowbase + row) * K + k0 + clog * 8;
            u16* l = &lds[wid * 4096 + j * 512];
            __builtin_amdgcn_global_load_lds(
                (const __attribute__((address_space(1))) unsigned int*)g,
                (__attribute__((address_space(3))) unsigned int*)l, 16, 0, 0);
        }
        __syncthreads();

        bf16x8 ah[4], al[4], bh[4], bl[4];
        const bf16x8* L = (const bf16x8*)lds;
#pragma unroll
        for (int mi = 0; mi < 4; ++mi) {
            int r = wm + mi * 16 + fr;
            int idx = r * 4 + (fc ^ ((r >> 1) & 3));
            ah[mi] = L[idx];
            al[mi] = L[512 + idx];
        }
#pragma unroll
        for (int nj = 0; nj < 4; ++nj) {
            int r = wn + nj * 16 + fr;
            int idx = r * 4 + (fc ^ ((r >> 1) & 3));
            bh[nj] = L[1024 + idx];
            bl[nj] = L[1536 + idx];
        }
#pragma unroll
        for (int mi = 0; mi < 4; ++mi)
#pragma unroll
            for (int nj = 0; nj < 4; ++nj) {
                acc[mi][nj] = __builtin_amdgcn_mfma_f32_16x16x32_bf16(ah[mi], bh[nj], acc[mi][nj], 0, 0, 0);
                acc[mi][nj] = __builtin_amdgcn_mfma_f32_16x16x32_bf16(ah[mi], bl[nj], acc[mi][nj], 0, 0, 0);
                acc[mi][nj] = __builtin_amdgcn_mfma_f32_16x16x32_bf16(al[mi], bh[nj], acc[mi][nj], 0, 0, 0);
            }
        __syncthreads();
    }

#pragma unroll
    for (int mi = 0; mi < 4; ++mi) {
        int row_b = m0 + wm + mi * 16 + (lane >> 4) * 4;
#pragma unroll
        for (int nj = 0; nj < 4; ++nj) {
            int col = n0 + wn + nj * 16 + (lane & 15);
#pragma unroll
            for (int r = 0; r < 4; ++r)
                C[(size_t)(row_b + r) * ldc + col] = acc[mi][nj][r];
        }
    }
}

// ---------------- fp32 tiled GEMM (kept for dt_proj): C[m,n]=sum_k A[m][k]*B[n][k] ----------------
template<int EPI>
__global__ __launch_bounds__(256) void gemm_tn(
    const float* __restrict__ A, int lda,
    const float* __restrict__ B, int ldb,
    float* __restrict__ C, int ldc,
    int M, int N, int K,
    const float* __restrict__ bias)
{
    __shared__ float As[16][64 + 4];
    __shared__ float Bs[16][64 + 4];
    const int tid = threadIdx.x;
    const int m0 = blockIdx.x * 64;
    const int n0 = blockIdx.y * 64;
    const int tx = tid & 15;
    const int ty = tid >> 4;
    const int lr = tid >> 4;
    const int lc = tid & 15;
    float acc[4][4] = {};

    for (int k0 = 0; k0 < K; k0 += 16) {
        const int k = k0 + lc;
#pragma unroll
        for (int i = 0; i < 4; ++i) {
            int m = m0 + lr + i * 16;
            As[lc][lr + i * 16] = (m < M) ? A[(size_t)m * lda + k] : 0.f;
        }
#pragma unroll
        for (int i = 0; i < 4; ++i) {
            int n = n0 + lr + i * 16;
            Bs[lc][lr + i * 16] = (n < N) ? B[(size_t)n * ldb + k] : 0.f;
        }
        __syncthreads();
#pragma unroll
        for (int kk = 0; kk < 16; ++kk) {
            float a[4], b[4];
#pragma unroll
            for (int i = 0; i < 4; ++i) a[i] = As[kk][ty * 4 + i];
#pragma unroll
            for (int j = 0; j < 4; ++j) b[j] = Bs[kk][tx * 4 + j];
#pragma unroll
            for (int i = 0; i < 4; ++i)
#pragma unroll
                for (int j = 0; j < 4; ++j)
                    acc[i][j] = fmaf(a[i], b[j], acc[i][j]);
        }
        __syncthreads();
    }

#pragma unroll
    for (int i = 0; i < 4; ++i) {
        int m = m0 + ty * 4 + i;
        if (m >= M) continue;
#pragma unroll
        for (int j = 0; j < 4; ++j) {
            int n = n0 + tx * 4 + j;
            if (n >= N) continue;
            float v = acc[i][j];
            if (EPI == 1) {
                v += bias[n];
                v = fmaxf(v, 0.f) + log1pf(expf(-fabsf(v)));
            }
            C[(size_t)m * ldc + n] = v;
        }
    }
}

// ---------------- fp32 split-K GEMM for x_proj (deterministic two-pass) ----------------
__global__ __launch_bounds__(256) void gemm_tn_splitk(
    const float* __restrict__ A, int lda,
    const float* __restrict__ B, int ldb,
    float* __restrict__ Cpart, int ldc,
    int M, int N, int Kchunk)
{
    __shared__ float As[16][64 + 4];
    __shared__ float Bs[16][64 + 4];
    const int tid = threadIdx.x;
    const int m0 = blockIdx.x * 64;
    const int n0 = blockIdx.y * 64;
    const int kb = blockIdx.z * Kchunk;
    const int tx = tid & 15;
    const int ty = tid >> 4;
    const int lr = tid >> 4;
    const int lc = tid & 15;
    float acc[4][4] = {};

    for (int k0 = kb; k0 < kb + Kchunk; k0 += 16) {
        const int k = k0 + lc;
#pragma unroll
        for (int i = 0; i < 4; ++i) {
            int m = m0 + lr + i * 16;
            As[lc][lr + i * 16] = (m < M) ? A[(size_t)m * lda + k] : 0.f;
        }
#pragma unroll
        for (int i = 0; i < 4; ++i) {
            int n = n0 + lr + i * 16;
            Bs[lc][lr + i * 16] = (n < N) ? B[(size_t)n * ldb + k] : 0.f;
        }
        __syncthreads();
#pragma unroll
        for (int kk = 0; kk < 16; ++kk) {
            float a[4], b[4];
#pragma unroll
            for (int i = 0; i < 4; ++i) a[i] = As[kk][ty * 4 + i];
#pragma unroll
            for (int j = 0; j < 4; ++j) b[j] = Bs[kk][tx * 4 + j];
#pragma unroll
            for (int i = 0; i < 4; ++i)
#pragma unroll
                for (int j = 0; j < 4; ++j)
                    acc[i][j] = fmaf(a[i], b[j], acc[i][j]);
        }
        __syncthreads();
    }

    float* Cs = Cpart + (size_t)blockIdx.z * M * ldc;
#pragma unroll
    for (int i = 0; i < 4; ++i) {
        int m = m0 + ty * 4 + i;
        if (m >= M) continue;
#pragma unroll
        for (int j = 0; j < 4; ++j) {
            int n = n0 + tx * 4 + j;
            if (n >= N) continue;
            Cs[(size_t)m * ldc + n] = acc[i][j];
        }
    }
}

__global__ __launch_bounds__(256) void splitk_reduce(
    const float* __restrict__ Ppart, float* __restrict__ out, int n)
{
    int i = blockIdx.x * 256 + threadIdx.x;
    if (i >= n) return;
    float s = 0.f;
#pragma unroll
    for (int z = 0; z < SPLITK; ++z) s += Ppart[(size_t)z * n + i];
    out[i] = s;
}

// ---------------- depthwise causal conv1d (width 4) + SiLU ----------------
__global__ __launch_bounds__(256) void conv_silu_kernel(
    const float* __restrict__ xz,
    const float* __restrict__ conv_w,
    const float* __restrict__ conv_b,
    float* __restrict__ u)
{
    int idx = blockIdx.x * blockDim.x + threadIdx.x;
    if (idx >= LSEQ * DINNER) return;
    int d = idx % DINNER;
    int t = idx / DINNER;
    float w[4];
#pragma unroll
    for (int j = 0; j < 4; ++j) w[j] = conv_w[d * 4 + j];
    float acc = conv_b[d];
#pragma unroll
    for (int j = 0; j < 4; ++j) {
        int s = t - 3 + j;
        if (s >= 0) acc = fmaf(xz[(size_t)s * (2 * DINNER) + d], w[j], acc);
    }
    float sig = 1.f / (1.f + expf(-acc));
    u[idx] = acc * sig;
}

// ================= chunked faithful scan =================
// Phase 1: per-chunk product of dA via exp(Acoef * sum(dt)) — single fast exp.
// (product of exps == exp of sum up to ~1e-7 rel; enters y only via decay-suppressed
// ratios p_t/p_s, so deviation << current 6e-5 absmax floor.)
__global__ __launch_bounds__(256) void scan_chunkprod(
    const float* __restrict__ dtm,
    const float* __restrict__ A_log,
    float* __restrict__ P)
{
    __shared__ float sdt[CHUNK][16];
    const int tid = threadIdx.x;
    const int d0 = blockIdx.x * 16;
    const int t0 = blockIdx.y * CHUNK;
    const int r = tid >> 4, c = tid & 15;
#pragma unroll
    for (int i = 0; i < CHUNK / 16; ++i) {
        int t = r + i * 16;
        sdt[t][c] = dtm[(size_t)(t0 + t) * DINNER + d0 + c];
    }
    __syncthreads();
    const int n = tid & 15, dl = tid >> 4;
    const float Acoef = -expf(A_log[(d0 + dl) * DSTATE + n]);
    float s = 0.f;
    for (int t = 0; t < CHUNK; ++t)
        s += sdt[t][dl];
    P[(size_t)blockIdx.y * NDN + d0 * DSTATE + tid] = __expf(Acoef * s);
}

template<int PROD>
__global__ __launch_bounds__(256) void scan_exclusive(float* __restrict__ buf)
{
    const int dn = blockIdx.x * 256 + threadIdx.x;
    float run = PROD ? 1.f : 0.f;
    for (int cidx = 0; cidx < NCHUNK; ++cidx) {
        float v = buf[(size_t)cidx * NDN + dn];
        buf[(size_t)cidx * NDN + dn] = run;
        run = PROD ? run * v : run + v;
    }
}

__global__ __launch_bounds__(256) void scan_chunksum(
    const float* __restrict__ dtm,
    const float* __restrict__ u,
    const float* __restrict__ xdbl,
    const float* __restrict__ A_log,
    const float* __restrict__ Ppre,
    float* __restrict__ S)
{
    __shared__ float sdt[CHUNK][16], su[CHUNK][16], sB[CHUNK][16];
    const int tid = threadIdx.x;
    const int d0 = blockIdx.x * 16;
    const int t0 = blockIdx.y * CHUNK;
    const int r = tid >> 4, c = tid & 15;
#pragma unroll
    for (int i = 0; i < CHUNK / 16; ++i) {
        int t = r + i * 16;
        size_t row = (size_t)(t0 + t);
        sdt[t][c] = dtm[row * DINNER + d0 + c];
        su[t][c]  = u[row * DINNER + d0 + c];
        sB[t][c]  = xdbl[row * XDBL_W + DTRANK + c];
    }
    __syncthreads();
    const int n = tid & 15, dl = tid >> 4;
    const float Acoef = -expf(A_log[(d0 + dl) * DSTATE + n]);
    float p = Ppre[(size_t)blockIdx.y * NDN + d0 * DSTATE + tid];
    float s = 0.f;
    for (int t = 0; t < CHUNK; ++t) {
        float dtv = sdt[t][dl];
        float dA = __expf(dtv * Acoef);                 // native v_exp
        p *= dA;
        float w = __fdividef((dtv * sB[t][n]) * su[t][dl], fmaxf(p, FEPS));  // rcp-based
        s += w;
    }
    S[(size_t)blockIdx.y * NDN + d0 * DSTATE + tid] = s;
}

// final pass: h=g*p, reduce over n, +D*u, gate silu(z); emit y as bf16 hi/lo planes
__global__ __launch_bounds__(256) void scan_final(
    const float* __restrict__ dtm,
    const float* __restrict__ u,
    const float* __restrict__ xdbl,
    const float* __restrict__ A_log,
    const float* __restrict__ Dvec,
    const float* __restrict__ Ppre,
    const float* __restrict__ Gpre,
    const float* __restrict__ xz,      // z read (cols 1536+)
    u16* __restrict__ yhi, u16* __restrict__ ylo)
{
    __shared__ float sdt[CHUNK][16], su[CHUNK][16], sB[CHUNK][16], sC[CHUNK][16], sz[CHUNK][16];
    const int tid = threadIdx.x;
    const int d0 = blockIdx.x * 16;
    const int t0 = blockIdx.y * CHUNK;
    const int r = tid >> 4, c = tid & 15;
#pragma unroll
    for (int i = 0; i < CHUNK / 16; ++i) {
        int t = r + i * 16;
        size_t row = (size_t)(t0 + t);
        sdt[t][c] = dtm[row * DINNER + d0 + c];
        su[t][c]  = u[row * DINNER + d0 + c];
        sB[t][c]  = xdbl[row * XDBL_W + DTRANK + c];
        sC[t][c]  = xdbl[row * XDBL_W + DTRANK + DSTATE + c];
        sz[t][c]  = xz[row * (size_t)(2 * DINNER) + DINNER + d0 + c];
    }
    __syncthreads();
    const int n = tid & 15, dl = tid >> 4;
    const int d = d0 + dl;
    const float Acoef = -expf(A_log[d * DSTATE + n]);
    const float Dd = Dvec[d];
    float p = Ppre[(size_t)blockIdx.y * NDN + d0 * DSTATE + tid];
    float g = Gpre[(size_t)blockIdx.y * NDN + d0 * DSTATE + tid];
    for (int t = 0; t < CHUNK; ++t) {
        float dtv = sdt[t][dl];
        float dA = __expf(dtv * Acoef);                 // native v_exp (matches chunksum)
        p *= dA;
        float w = __fdividef((dtv * sB[t][n]) * su[t][dl], fmaxf(p, FEPS));
        g += w;
        float part = (g * p) * sC[t][n];
        part += __shfl_xor(part, 1, 16);
        part += __shfl_xor(part, 2, 16);
        part += __shfl_xor(part, 4, 16);
        part += __shfl_xor(part, 8, 16);
        if (n == 0) {
            float zv = sz[t][dl];
            float sig = 1.f / (1.f + expf(-zv));
            float yv = (part + Dd * su[t][dl]) * (zv * sig);
            u16 h = f2bf_rn(yv);
            u16 l = f2bf_rn(yv - bf2f(h));
            yhi[(size_t)(t0 + t) * DINNER + d] = h;
            ylo[(size_t)(t0 + t) * DINNER + d] = l;
        }
    }
}

// ---------------- launch ----------------
extern "C" void kernel_launch(void* const* d_in, const int* in_sizes, int n_in,
                              void* d_out, int out_size, void* d_ws, size_t ws_size,
                              hipStream_t stream) {
    const float* x          = (const float*)d_in[0];
    const float* in_proj_w  = (const float*)d_in[1];
    const float* conv_w     = (const float*)d_in[2];
    const float* conv_b     = (const float*)d_in[3];
    const float* x_proj_w   = (const float*)d_in[4];
    const float* dt_proj_w  = (const float*)d_in[5];
    const float* dt_proj_b  = (const float*)d_in[6];
    const float* A_log      = (const float*)d_in[7];
    const float* Dvec       = (const float*)d_in[8];
    const float* out_proj_w = (const float*)d_in[9];
    float* out = (float*)d_out;

    char* w = (char*)d_ws;
    auto alloc = [&](size_t bytes) { char* p = w; w += (bytes + 255) & ~(size_t)255; return p; };

    float* xz    = (float*)alloc((size_t)LSEQ * 2 * DINNER * 4);
    float* u     = (float*)alloc((size_t)LSEQ * DINNER * 4);
    float* xdbl  = (float*)alloc((size_t)LSEQ * XDBL_W * 4);
    float* dtb   = (float*)alloc((size_t)LSEQ * DINNER * 4);
    float* P     = (float*)alloc((size_t)NCHUNK * NDN * 4);
    float* S     = (float*)alloc((size_t)NCHUNK * NDN * 4);
    float* Ppart = (float*)alloc((size_t)SPLITK * LSEQ * XDBL_W * 4);
    u16* xhi  = (u16*)alloc((size_t)LSEQ * DMODEL * 2);
    u16* xlo  = (u16*)alloc((size_t)LSEQ * DMODEL * 2);
    u16* wihi = (u16*)alloc((size_t)2 * DINNER * DMODEL * 2);
    u16* wilo = (u16*)alloc((size_t)2 * DINNER * DMODEL * 2);
    u16* owhi = (u16*)alloc((size_t)DMODEL * DINNER * 2);
    u16* owlo = (u16*)alloc((size_t)DMODEL * DINNER * 2);
    u16* yhi  = (u16*)alloc((size_t)LSEQ * DINNER * 2);
    u16* ylo  = (u16*)alloc((size_t)LSEQ * DINNER * 2);

    dim3 blk(256);

    // 0. conversions to bf16 hi/lo
    cvt_split<<<(LSEQ * DMODEL) / 1024, blk, 0, stream>>>(x, xhi, xlo, LSEQ * DMODEL);
    cvt_split<<<(2 * DINNER * DMODEL) / 1024, blk, 0, stream>>>(in_proj_w, wihi, wilo, 2 * DINNER * DMODEL);
    cvt_split<<<(DMODEL * DINNER) / 1024, blk, 0, stream>>>(out_proj_w, owhi, owlo, DMODEL * DINNER);

    // 1. xz = x @ in_proj_w.T   (M=2048, N=3072, K=768) via split-bf16 MFMA
    mfma_gemm_tn<<<dim3(LSEQ / 128, (2 * DINNER) / 128), blk, 0, stream>>>(
        xhi, xlo, wihi, wilo, xz, 2 * DINNER, DMODEL);

    // 2. u = silu(depthwise_conv(xh) + b)
    conv_silu_kernel<<<(LSEQ * DINNER + 255) / 256, blk, 0, stream>>>(xz, conv_w, conv_b, u);

    // 3. x_dbl = u @ x_proj_w.T (M=2048, N=80, K=1536) split-K fp32, deterministic reduce
    gemm_tn_splitk<<<dim3(LSEQ / 64, (XDBL_W + 63) / 64, SPLITK), blk, 0, stream>>>(
        u, DINNER, x_proj_w, DINNER, Ppart, XDBL_W, LSEQ, XDBL_W, DINNER / SPLITK);
    splitk_reduce<<<(LSEQ * XDBL_W + 255) / 256, blk, 0, stream>>>(Ppart, xdbl, LSEQ * XDBL_W);

    // 4. dt = softplus(x_dbl[:, :48] @ dt_proj_w.T + dt_proj_b)
    gemm_tn<1><<<dim3(LSEQ / 64, DINNER / 64), blk, 0, stream>>>(
        xdbl, XDBL_W, dt_proj_w, DTRANK, dtb, DINNER, LSEQ, DINNER, DTRANK, dt_proj_b);

    // 5. chunked faithful selective scan (y emitted as bf16 hi/lo)
    scan_chunkprod<<<dim3(DINNER / 16, NCHUNK), blk, 0, stream>>>(dtb, A_log, P);
    scan_exclusive<1><<<NDN / 256, blk, 0, stream>>>(P);
    scan_chunksum<<<dim3(DINNER / 16, NCHUNK), blk, 0, stream>>>(dtb, u, xdbl, A_log, P, S);
    scan_exclusive<0><<<NDN / 256, blk, 0, stream>>>(S);
    scan_final<<<dim3(DINNER / 16, NCHUNK), blk, 0, stream>>>(
        dtb, u, xdbl, A_log, Dvec, P, S, xz, yhi, ylo);

    // 6. out = y @ out_proj_w.T (M=2048, N=768, K=1536) via split-bf16 MFMA
    mfma_gemm_tn<<<dim3(LSEQ / 128, DMODEL / 128), blk, 0, stream>>>(
        yhi, ylo, owhi, owlo, out, DMODEL, DINNER);
}

// Round 7
// 284.851 us; speedup vs baseline: 7.9193x; 1.0942x over previous
//
#include <hip/hip_runtime.h>
#include <hip/hip_bf16.h>

// ---------------- sizes ----------------
#define LSEQ 2048
#define DMODEL 768
#define DINNER 1536
#define DSTATE 16
#define DTRANK 48
#define XDBL_W (DTRANK + 2*DSTATE)   // 80
#define CHUNK 64
#define NCHUNK (LSEQ / CHUNK)        // 32
#define NDN (DINNER * DSTATE)        // 24576
#define FEPS 1.1920928955078125e-07f
#define SPLITK 8
#define LDST 68                      // padded LDS row stride (floats): 16B-aligned, 2-way max

typedef short bf16x8 __attribute__((ext_vector_type(8)));
typedef float f32x4 __attribute__((ext_vector_type(4)));
typedef unsigned short u16;

__device__ __forceinline__ u16 f2bf_rn(float f) {
    unsigned u = __float_as_uint(f);
    unsigned r = u + 0x7FFFu + ((u >> 16) & 1u);
    return (u16)(r >> 16);
}
__device__ __forceinline__ float bf2f(u16 h) {
    return __uint_as_float(((unsigned)h) << 16);
}

// ---------------- fp32 -> bf16 hi/lo split conversion ----------------
__global__ __launch_bounds__(256) void cvt_split(
    const float* __restrict__ src, u16* __restrict__ hi, u16* __restrict__ lo, int n)
{
    int i = (blockIdx.x * 256 + threadIdx.x) * 4;
    if (i >= n) return;
    float4 v = *(const float4*)&src[i];
    u16 h0 = f2bf_rn(v.x), h1 = f2bf_rn(v.y), h2 = f2bf_rn(v.z), h3 = f2bf_rn(v.w);
    u16 l0 = f2bf_rn(v.x - bf2f(h0));
    u16 l1 = f2bf_rn(v.y - bf2f(h1));
    u16 l2 = f2bf_rn(v.z - bf2f(h2));
    u16 l3 = f2bf_rn(v.w - bf2f(h3));
    ushort4 hv = make_ushort4(h0, h1, h2, h3);
    ushort4 lv = make_ushort4(l0, l1, l2, l3);
    *(ushort4*)&hi[i] = hv;
    *(ushort4*)&lo[i] = lv;
}

// ---------------- split-bf16 MFMA GEMM: C[m,n] = sum_k A[m][k]*B[n][k] ----------------
__global__ __launch_bounds__(256) void mfma_gemm_tn(
    const u16* __restrict__ Ahi, const u16* __restrict__ Alo,
    const u16* __restrict__ Bhi, const u16* __restrict__ Blo,
    float* __restrict__ C, int ldc, int K)
{
    __shared__ u16 lds[4 * 4096];   // planes: Ahi, Alo, Bhi, Blo (128x32 each, 8KB)
    const int tid = threadIdx.x;
    const int wid = tid >> 6;
    const int lane = tid & 63;
    const int m0 = blockIdx.x * 128;
    const int n0 = blockIdx.y * 128;

    const int st_subrow = lane >> 2;   // 0..15
    const int st_cphys = lane & 3;
    const u16* myplane = (wid == 0) ? Ahi : (wid == 1) ? Alo : (wid == 2) ? Bhi : Blo;
    const int rowbase = (wid < 2) ? m0 : n0;

    f32x4 acc[4][4] = {};
    const int wm = (wid >> 1) * 64;
    const int wn = (wid & 1) * 64;
    const int fr = lane & 15;
    const int fc = lane >> 4;

    for (int k0 = 0; k0 < K; k0 += 32) {
#pragma unroll
        for (int j = 0; j < 8; ++j) {
            int row = j * 16 + st_subrow;                       // 0..127
            int clog = st_cphys ^ ((row >> 1) & 3);
            const u16* g = myplane + (size_t)(rowbase + row) * K + k0 + clog * 8;
            u16* l = &lds[wid * 4096 + j * 512];
            __builtin_amdgcn_global_load_lds(
                (const __attribute__((address_space(1))) unsigned int*)g,
                (__attribute__((address_space(3))) unsigned int*)l, 16, 0, 0);
        }
        __syncthreads();

        bf16x8 ah[4], al[4], bh[4], bl[4];
        const bf16x8* L = (const bf16x8*)lds;
#pragma unroll
        for (int mi = 0; mi < 4; ++mi) {
            int r = wm + mi * 16 + fr;
            int idx = r * 4 + (fc ^ ((r >> 1) & 3));
            ah[mi] = L[idx];
            al[mi] = L[512 + idx];
        }
#pragma unroll
        for (int nj = 0; nj < 4; ++nj) {
            int r = wn + nj * 16 + fr;
            int idx = r * 4 + (fc ^ ((r >> 1) & 3));
            bh[nj] = L[1024 + idx];
            bl[nj] = L[1536 + idx];
        }
#pragma unroll
        for (int mi = 0; mi < 4; ++mi)
#pragma unroll
            for (int nj = 0; nj < 4; ++nj) {
                acc[mi][nj] = __builtin_amdgcn_mfma_f32_16x16x32_bf16(ah[mi], bh[nj], acc[mi][nj], 0, 0, 0);
                acc[mi][nj] = __builtin_amdgcn_mfma_f32_16x16x32_bf16(ah[mi], bl[nj], acc[mi][nj], 0, 0, 0);
                acc[mi][nj] = __builtin_amdgcn_mfma_f32_16x16x32_bf16(al[mi], bh[nj], acc[mi][nj], 0, 0, 0);
            }
        __syncthreads();
    }

#pragma unroll
    for (int mi = 0; mi < 4; ++mi) {
        int row_b = m0 + wm + mi * 16 + (lane >> 4) * 4;
#pragma unroll
        for (int nj = 0; nj < 4; ++nj) {
            int col = n0 + wn + nj * 16 + (lane & 15);
#pragma unroll
            for (int r = 0; r < 4; ++r)
                C[(size_t)(row_b + r) * ldc + col] = acc[mi][nj][r];
        }
    }
}

// ---------------- fp32 tiled GEMM (dt_proj): C[m,n]=sum_k A[m][k]*B[n][k] ----------------
template<int EPI>
__global__ __launch_bounds__(256) void gemm_tn(
    const float* __restrict__ A, int lda,
    const float* __restrict__ B, int ldb,
    float* __restrict__ C, int ldc,
    int M, int N, int K,
    const float* __restrict__ bias)
{
    __shared__ float As[16][64 + 4];
    __shared__ float Bs[16][64 + 4];
    const int tid = threadIdx.x;
    const int m0 = blockIdx.x * 64;
    const int n0 = blockIdx.y * 64;
    const int tx = tid & 15;
    const int ty = tid >> 4;
    const int lr = tid >> 4;
    const int lc = tid & 15;
    float acc[4][4] = {};

    for (int k0 = 0; k0 < K; k0 += 16) {
        const int k = k0 + lc;
#pragma unroll
        for (int i = 0; i < 4; ++i) {
            int m = m0 + lr + i * 16;
            As[lc][lr + i * 16] = (m < M) ? A[(size_t)m * lda + k] : 0.f;
        }
#pragma unroll
        for (int i = 0; i < 4; ++i) {
            int n = n0 + lr + i * 16;
            Bs[lc][lr + i * 16] = (n < N) ? B[(size_t)n * ldb + k] : 0.f;
        }
        __syncthreads();
#pragma unroll
        for (int kk = 0; kk < 16; ++kk) {
            float a[4], b[4];
#pragma unroll
            for (int i = 0; i < 4; ++i) a[i] = As[kk][ty * 4 + i];
#pragma unroll
            for (int j = 0; j < 4; ++j) b[j] = Bs[kk][tx * 4 + j];
#pragma unroll
            for (int i = 0; i < 4; ++i)
#pragma unroll
                for (int j = 0; j < 4; ++j)
                    acc[i][j] = fmaf(a[i], b[j], acc[i][j]);
        }
        __syncthreads();
    }

#pragma unroll
    for (int i = 0; i < 4; ++i) {
        int m = m0 + ty * 4 + i;
        if (m >= M) continue;
#pragma unroll
        for (int j = 0; j < 4; ++j) {
            int n = n0 + tx * 4 + j;
            if (n >= N) continue;
            float v = acc[i][j];
            if (EPI == 1) {
                v += bias[n];
                v = fmaxf(v, 0.f) + log1pf(expf(-fabsf(v)));
            }
            C[(size_t)m * ldc + n] = v;
        }
    }
}

// ---------------- fp32 split-K GEMM for x_proj (deterministic two-pass) ----------------
__global__ __launch_bounds__(256) void gemm_tn_splitk(
    const float* __restrict__ A, int lda,
    const float* __restrict__ B, int ldb,
    float* __restrict__ Cpart, int ldc,
    int M, int N, int Kchunk)
{
    __shared__ float As[16][64 + 4];
    __shared__ float Bs[16][64 + 4];
    const int tid = threadIdx.x;
    const int m0 = blockIdx.x * 64;
    const int n0 = blockIdx.y * 64;
    const int kb = blockIdx.z * Kchunk;
    const int tx = tid & 15;
    const int ty = tid >> 4;
    const int lr = tid >> 4;
    const int lc = tid & 15;
    float acc[4][4] = {};

    for (int k0 = kb; k0 < kb + Kchunk; k0 += 16) {
        const int k = k0 + lc;
#pragma unroll
        for (int i = 0; i < 4; ++i) {
            int m = m0 + lr + i * 16;
            As[lc][lr + i * 16] = (m < M) ? A[(size_t)m * lda + k] : 0.f;
        }
#pragma unroll
        for (int i = 0; i < 4; ++i) {
            int n = n0 + lr + i * 16;
            Bs[lc][lr + i * 16] = (n < N) ? B[(size_t)n * ldb + k] : 0.f;
        }
        __syncthreads();
#pragma unroll
        for (int kk = 0; kk < 16; ++kk) {
            float a[4], b[4];
#pragma unroll
            for (int i = 0; i < 4; ++i) a[i] = As[kk][ty * 4 + i];
#pragma unroll
            for (int j = 0; j < 4; ++j) b[j] = Bs[kk][tx * 4 + j];
#pragma unroll
            for (int i = 0; i < 4; ++i)
#pragma unroll
                for (int j = 0; j < 4; ++j)
                    acc[i][j] = fmaf(a[i], b[j], acc[i][j]);
        }
        __syncthreads();
    }

    float* Cs = Cpart + (size_t)blockIdx.z * M * ldc;
#pragma unroll
    for (int i = 0; i < 4; ++i) {
        int m = m0 + ty * 4 + i;
        if (m >= M) continue;
#pragma unroll
        for (int j = 0; j < 4; ++j) {
            int n = n0 + tx * 4 + j;
            if (n >= N) continue;
            Cs[(size_t)m * ldc + n] = acc[i][j];
        }
    }
}

__global__ __launch_bounds__(256) void splitk_reduce(
    const float* __restrict__ Ppart, float* __restrict__ out, int n)
{
    int i = blockIdx.x * 256 + threadIdx.x;
    if (i >= n) return;
    float s = 0.f;
#pragma unroll
    for (int z = 0; z < SPLITK; ++z) s += Ppart[(size_t)z * n + i];
    out[i] = s;
}

// ---------------- depthwise causal conv1d (width 4) + SiLU ----------------
__global__ __launch_bounds__(256) void conv_silu_kernel(
    const float* __restrict__ xz,
    const float* __restrict__ conv_w,
    const float* __restrict__ conv_b,
    float* __restrict__ u)
{
    int idx = blockIdx.x * blockDim.x + threadIdx.x;
    if (idx >= LSEQ * DINNER) return;
    int d = idx % DINNER;
    int t = idx / DINNER;
    float w[4];
#pragma unroll
    for (int j = 0; j < 4; ++j) w[j] = conv_w[d * 4 + j];
    float acc = conv_b[d];
#pragma unroll
    for (int j = 0; j < 4; ++j) {
        int s = t - 3 + j;
        if (s >= 0) acc = fmaf(xz[(size_t)s * (2 * DINNER) + d], w[j], acc);
    }
    float sig = 1.f / (1.f + __expf(-acc));
    u[idx] = acc * sig;
}

// ================= chunked faithful scan (transposed-LDS, lean loops) =================
// LDS layout: arr[16][LDST] — row = d-lane (or n-lane), col = t. LDST=68 floats keeps
// every [dl][4*tb] address 16B-aligned (68*4=272=17*16) and bank spread (68%32=4).

// Phase 1: per-chunk dA-product via exp(Acoef * sum(dt)).
__global__ __launch_bounds__(256) void scan_chunkprod(
    const float* __restrict__ dtm,
    const float* __restrict__ A_log,
    float* __restrict__ P)
{
    __shared__ float sdtT[16][LDST];
    const int tid = threadIdx.x;
    const int d0 = blockIdx.x * 16;
    const int t0 = blockIdx.y * CHUNK;
    const int r = tid >> 4, c = tid & 15;
#pragma unroll
    for (int i = 0; i < 4; ++i) {
        int t = r + i * 16;
        sdtT[c][t] = dtm[(size_t)(t0 + t) * DINNER + d0 + c];
    }
    __syncthreads();
    const int n = tid & 15, dl = tid >> 4;
    const float Acoef = -expf(A_log[(d0 + dl) * DSTATE + n]);
    float s = 0.f;
#pragma unroll
    for (int tb = 0; tb < 16; ++tb) {
        f32x4 q = *(const f32x4*)&sdtT[dl][tb * 4];
        s += q[0] + q[1] + q[2] + q[3];
    }
    P[(size_t)blockIdx.y * NDN + d0 * DSTATE + tid] = __expf(Acoef * s);
}

template<int PROD>
__global__ __launch_bounds__(256) void scan_exclusive(float* __restrict__ buf)
{
    const int dn = blockIdx.x * 256 + threadIdx.x;
    float run = PROD ? 1.f : 0.f;
#pragma unroll
    for (int cidx = 0; cidx < NCHUNK; ++cidx) {
        float v = buf[(size_t)cidx * NDN + dn];
        buf[(size_t)cidx * NDN + dn] = run;
        run = PROD ? run * v : run + v;
    }
}

// Phase 3a: per-chunk sum of dBu/max(p,eps), p seeded by prefix product
__global__ __launch_bounds__(256) void scan_chunksum(
    const float* __restrict__ dtm,
    const float* __restrict__ u,
    const float* __restrict__ xdbl,
    const float* __restrict__ A_log,
    const float* __restrict__ Ppre,
    float* __restrict__ S)
{
    __shared__ float sdtT[16][LDST], suT[16][LDST], sBT[16][LDST];
    const int tid = threadIdx.x;
    const int d0 = blockIdx.x * 16;
    const int t0 = blockIdx.y * CHUNK;
    const int r = tid >> 4, c = tid & 15;
#pragma unroll
    for (int i = 0; i < 4; ++i) {
        int t = r + i * 16;
        size_t row = (size_t)(t0 + t);
        sdtT[c][t] = dtm[row * DINNER + d0 + c];
        suT[c][t]  = u[row * DINNER + d0 + c];
        sBT[c][t]  = xdbl[row * XDBL_W + DTRANK + c];
    }
    __syncthreads();
    const int n = tid & 15, dl = tid >> 4;
    const float Acoef = -expf(A_log[(d0 + dl) * DSTATE + n]);
    float p = Ppre[(size_t)blockIdx.y * NDN + d0 * DSTATE + tid];
    float s = 0.f;
#pragma unroll
    for (int tb = 0; tb < 16; ++tb) {
        f32x4 dq = *(const f32x4*)&sdtT[dl][tb * 4];
        f32x4 uq = *(const f32x4*)&suT[dl][tb * 4];
        f32x4 bq = *(const f32x4*)&sBT[n][tb * 4];
#pragma unroll
        for (int j = 0; j < 4; ++j) {
            float dtv = dq[j];
            p *= __expf(dtv * Acoef);
            s += __fdividef((dtv * bq[j]) * uq[j], fmaxf(p, FEPS));
        }
    }
    S[(size_t)blockIdx.y * NDN + d0 * DSTATE + tid] = s;
}

// Phase 3c: recurrence + n-reduction only; store raw part into dead xh half of xz.
__global__ __launch_bounds__(256) void scan_final(
    const float* __restrict__ dtm,
    const float* __restrict__ u,
    const float* __restrict__ xdbl,
    const float* __restrict__ A_log,
    const float* __restrict__ Ppre,
    const float* __restrict__ Gpre,
    float* __restrict__ xz)           // part written to cols 0..1535
{
    __shared__ float sdtT[16][LDST], suT[16][LDST], sBT[16][LDST], sCT[16][LDST];
    const int tid = threadIdx.x;
    const int d0 = blockIdx.x * 16;
    const int t0 = blockIdx.y * CHUNK;
    const int r = tid >> 4, c = tid & 15;
#pragma unroll
    for (int i = 0; i < 4; ++i) {
        int t = r + i * 16;
        size_t row = (size_t)(t0 + t);
        sdtT[c][t] = dtm[row * DINNER + d0 + c];
        suT[c][t]  = u[row * DINNER + d0 + c];
        sBT[c][t]  = xdbl[row * XDBL_W + DTRANK + c];
        sCT[c][t]  = xdbl[row * XDBL_W + DTRANK + DSTATE + c];
    }
    __syncthreads();
    const int n = tid & 15, dl = tid >> 4;
    const int d = d0 + dl;
    const float Acoef = -expf(A_log[d * DSTATE + n]);
    float p = Ppre[(size_t)blockIdx.y * NDN + d0 * DSTATE + tid];
    float g = Gpre[(size_t)blockIdx.y * NDN + d0 * DSTATE + tid];
#pragma unroll
    for (int tb = 0; tb < 16; ++tb) {
        f32x4 dq = *(const f32x4*)&sdtT[dl][tb * 4];
        f32x4 uq = *(const f32x4*)&suT[dl][tb * 4];
        f32x4 bq = *(const f32x4*)&sBT[n][tb * 4];
        f32x4 cq = *(const f32x4*)&sCT[n][tb * 4];
#pragma unroll
        for (int j = 0; j < 4; ++j) {
            float dtv = dq[j];
            p *= __expf(dtv * Acoef);
            g += __fdividef((dtv * bq[j]) * uq[j], fmaxf(p, FEPS));
            float part = (g * p) * cq[j];
            part += __shfl_xor(part, 1, 16);
            part += __shfl_xor(part, 2, 16);
            part += __shfl_xor(part, 4, 16);
            part += __shfl_xor(part, 8, 16);
            if (n == 0)
                xz[(size_t)(t0 + tb * 4 + j) * (2 * DINNER) + d] = part;
        }
    }
}

// gate/output epilogue: y = (part + D*u) * silu(z), emitted as bf16 hi/lo planes.
__global__ __launch_bounds__(256) void gate_kernel(
    const float* __restrict__ xz,     // part at cols 0..1535, z at cols 1536..3071
    const float* __restrict__ u,
    const float* __restrict__ Dvec,
    u16* __restrict__ yhi, u16* __restrict__ ylo)
{
    int i4 = (blockIdx.x * 256 + threadIdx.x) * 4;
    if (i4 >= LSEQ * DINNER) return;
    int t = i4 / DINNER;
    int d = i4 - t * DINNER;
    size_t base = (size_t)t * (2 * DINNER) + d;
    float4 part = *(const float4*)&xz[base];
    float4 zv   = *(const float4*)&xz[base + DINNER];
    float4 uv   = *(const float4*)&u[i4];
    float4 Dd   = *(const float4*)&Dvec[d];
    ushort4 hv, lv;
    float pa[4] = {part.x, part.y, part.z, part.w};
    float za[4] = {zv.x, zv.y, zv.z, zv.w};
    float ua[4] = {uv.x, uv.y, uv.z, uv.w};
    float Da[4] = {Dd.x, Dd.y, Dd.z, Dd.w};
    u16 ha[4], la[4];
#pragma unroll
    for (int j = 0; j < 4; ++j) {
        float sig = 1.f / (1.f + __expf(-za[j]));
        float yv = (pa[j] + Da[j] * ua[j]) * (za[j] * sig);
        ha[j] = f2bf_rn(yv);
        la[j] = f2bf_rn(yv - bf2f(ha[j]));
    }
    hv = make_ushort4(ha[0], ha[1], ha[2], ha[3]);
    lv = make_ushort4(la[0], la[1], la[2], la[3]);
    *(ushort4*)&yhi[i4] = hv;
    *(ushort4*)&ylo[i4] = lv;
}

// ---------------- launch ----------------
extern "C" void kernel_launch(void* const* d_in, const int* in_sizes, int n_in,
                              void* d_out, int out_size, void* d_ws, size_t ws_size,
                              hipStream_t stream) {
    const float* x          = (const float*)d_in[0];
    const float* in_proj_w  = (const float*)d_in[1];
    const float* conv_w     = (const float*)d_in[2];
    const float* conv_b     = (const float*)d_in[3];
    const float* x_proj_w   = (const float*)d_in[4];
    const float* dt_proj_w  = (const float*)d_in[5];
    const float* dt_proj_b  = (const float*)d_in[6];
    const float* A_log      = (const float*)d_in[7];
    const float* Dvec       = (const float*)d_in[8];
    const float* out_proj_w = (const float*)d_in[9];
    float* out = (float*)d_out;

    char* w = (char*)d_ws;
    auto alloc = [&](size_t bytes) { char* p = w; w += (bytes + 255) & ~(size_t)255; return p; };

    float* xz    = (float*)alloc((size_t)LSEQ * 2 * DINNER * 4);
    float* u     = (float*)alloc((size_t)LSEQ * DINNER * 4);
    float* xdbl  = (float*)alloc((size_t)LSEQ * XDBL_W * 4);
    float* dtb   = (float*)alloc((size_t)LSEQ * DINNER * 4);
    float* P     = (float*)alloc((size_t)NCHUNK * NDN * 4);
    float* S     = (float*)alloc((size_t)NCHUNK * NDN * 4);
    float* Ppart = (float*)alloc((size_t)SPLITK * LSEQ * XDBL_W * 4);
    u16* xhi  = (u16*)alloc((size_t)LSEQ * DMODEL * 2);
    u16* xlo  = (u16*)alloc((size_t)LSEQ * DMODEL * 2);
    u16* wihi = (u16*)alloc((size_t)2 * DINNER * DMODEL * 2);
    u16* wilo = (u16*)alloc((size_t)2 * DINNER * DMODEL * 2);
    u16* owhi = (u16*)alloc((size_t)DMODEL * DINNER * 2);
    u16* owlo = (u16*)alloc((size_t)DMODEL * DINNER * 2);
    u16* yhi  = (u16*)alloc((size_t)LSEQ * DINNER * 2);
    u16* ylo  = (u16*)alloc((size_t)LSEQ * DINNER * 2);

    dim3 blk(256);

    // 0. conversions to bf16 hi/lo
    cvt_split<<<(LSEQ * DMODEL) / 1024, blk, 0, stream>>>(x, xhi, xlo, LSEQ * DMODEL);
    cvt_split<<<(2 * DINNER * DMODEL) / 1024, blk, 0, stream>>>(in_proj_w, wihi, wilo, 2 * DINNER * DMODEL);
    cvt_split<<<(DMODEL * DINNER) / 1024, blk, 0, stream>>>(out_proj_w, owhi, owlo, DMODEL * DINNER);

    // 1. xz = x @ in_proj_w.T   (M=2048, N=3072, K=768) via split-bf16 MFMA
    mfma_gemm_tn<<<dim3(LSEQ / 128, (2 * DINNER) / 128), blk, 0, stream>>>(
        xhi, xlo, wihi, wilo, xz, 2 * DINNER, DMODEL);

    // 2. u = silu(depthwise_conv(xh) + b)
    conv_silu_kernel<<<(LSEQ * DINNER + 255) / 256, blk, 0, stream>>>(xz, conv_w, conv_b, u);

    // 3. x_dbl = u @ x_proj_w.T (M=2048, N=80, K=1536) split-K fp32, deterministic reduce
    gemm_tn_splitk<<<dim3(LSEQ / 64, (XDBL_W + 63) / 64, SPLITK), blk, 0, stream>>>(
        u, DINNER, x_proj_w, DINNER, Ppart, XDBL_W, LSEQ, XDBL_W, DINNER / SPLITK);
    splitk_reduce<<<(LSEQ * XDBL_W + 255) / 256, blk, 0, stream>>>(Ppart, xdbl, LSEQ * XDBL_W);

    // 4. dt = softplus(x_dbl[:, :48] @ dt_proj_w.T + dt_proj_b)
    gemm_tn<1><<<dim3(LSEQ / 64, DINNER / 64), blk, 0, stream>>>(
        xdbl, XDBL_W, dt_proj_w, DTRANK, dtb, DINNER, LSEQ, DINNER, DTRANK, dt_proj_b);

    // 5. chunked faithful selective scan (lean loops); part -> xz cols 0..1535
    scan_chunkprod<<<dim3(DINNER / 16, NCHUNK), blk, 0, stream>>>(dtb, A_log, P);
    scan_exclusive<1><<<NDN / 256, blk, 0, stream>>>(P);
    scan_chunksum<<<dim3(DINNER / 16, NCHUNK), blk, 0, stream>>>(dtb, u, xdbl, A_log, P, S);
    scan_exclusive<0><<<NDN / 256, blk, 0, stream>>>(S);
    scan_final<<<dim3(DINNER / 16, NCHUNK), blk, 0, stream>>>(
        dtb, u, xdbl, A_log, P, S, xz);

    // 5b. gate epilogue: y = (part + D*u)*silu(z) -> bf16 hi/lo
    gate_kernel<<<(LSEQ * DINNER) / 1024, blk, 0, stream>>>(xz, u, Dvec, yhi, ylo);

    // 6. out = y @ out_proj_w.T (M=2048, N=768, K=1536) via split-bf16 MFMA
    mfma_gemm_tn<<<dim3(LSEQ / 128, DMODEL / 128), blk, 0, stream>>>(
        yhi, ylo, owhi, owlo, out, DMODEL, DINNER);
}

// Round 8
// 243.772 us; speedup vs baseline: 9.2538x; 1.1685x over previous
//
#include <hip/hip_runtime.h>
#include <hip/hip_bf16.h>

// ---------------- sizes ----------------
#define LSEQ 2048
#define DMODEL 768
#define DINNER 1536
#define DSTATE 16
#define DTRANK 48
#define XDBL_W (DTRANK + 2*DSTATE)   // 80
#define CHUNK 64
#define NCHUNK (LSEQ / CHUNK)        // 32
#define NDN (DINNER * DSTATE)        // 24576
#define FEPS 1.1920928955078125e-07f
#define SPLITK 8
#define OSPLIT 4                     // split-K factor for out_proj
#define LDST 68                      // padded LDS row stride (floats)

typedef short bf16x8 __attribute__((ext_vector_type(8)));
typedef float f32x4 __attribute__((ext_vector_type(4)));
typedef unsigned short u16;

__device__ __forceinline__ u16 f2bf_rn(float f) {
    unsigned u = __float_as_uint(f);
    unsigned r = u + 0x7FFFu + ((u >> 16) & 1u);
    return (u16)(r >> 16);
}
__device__ __forceinline__ float bf2f(u16 h) {
    return __uint_as_float(((unsigned)h) << 16);
}

// ---------------- fp32 -> bf16 hi/lo split conversion ----------------
__global__ __launch_bounds__(256) void cvt_split(
    const float* __restrict__ src, u16* __restrict__ hi, u16* __restrict__ lo, int n)
{
    int i = (blockIdx.x * 256 + threadIdx.x) * 4;
    if (i >= n) return;
    float4 v = *(const float4*)&src[i];
    u16 h0 = f2bf_rn(v.x), h1 = f2bf_rn(v.y), h2 = f2bf_rn(v.z), h3 = f2bf_rn(v.w);
    u16 l0 = f2bf_rn(v.x - bf2f(h0));
    u16 l1 = f2bf_rn(v.y - bf2f(h1));
    u16 l2 = f2bf_rn(v.z - bf2f(h2));
    u16 l3 = f2bf_rn(v.w - bf2f(h3));
    ushort4 hv = make_ushort4(h0, h1, h2, h3);
    ushort4 lv = make_ushort4(l0, l1, l2, l3);
    *(ushort4*)&hi[i] = hv;
    *(ushort4*)&lo[i] = lv;
}

// ---------------- split-bf16 MFMA GEMM, double-buffered ----------------
// C[m,n] = sum_{k in [z*Klen, (z+1)*Klen)} A[m][k]*B[n][k]; z = blockIdx.z.
// Partial z writes to C + z*LSEQ*ldc. 128x128 tile, 4 waves, BK=32.
__global__ __launch_bounds__(256) void mfma_gemm_tn(
    const u16* __restrict__ Ahi, const u16* __restrict__ Alo,
    const u16* __restrict__ Bhi, const u16* __restrict__ Blo,
    float* __restrict__ C, int ldc, int ldk, int Klen)
{
    __shared__ u16 lds[2 * 4 * 4096];   // 2 buffers x 4 planes x 8KB = 64KB
    const int tid = threadIdx.x;
    const int wid = tid >> 6;
    const int lane = tid & 63;
    const int m0 = blockIdx.x * 128;
    const int n0 = blockIdx.y * 128;
    const int Koff = blockIdx.z * Klen;

    const int st_subrow = lane >> 2;   // 0..15
    const int st_cphys = lane & 3;
    const u16* myplane = (wid == 0) ? Ahi : (wid == 1) ? Alo : (wid == 2) ? Bhi : Blo;
    const int rowbase = (wid < 2) ? m0 : n0;

    f32x4 acc[4][4] = {};
    const int wm = (wid >> 1) * 64;
    const int wn = (wid & 1) * 64;
    const int fr = lane & 15;
    const int fc = lane >> 4;
    const int nsteps = Klen / 32;

    // stage K-tile (absolute k0) into buffer buf
    auto stage = [&](int buf, int k0) {
#pragma unroll
        for (int j = 0; j < 8; ++j) {
            int row = j * 16 + st_subrow;                       // 0..127
            int clog = st_cphys ^ ((row >> 1) & 3);
            const u16* g = myplane + (size_t)(rowbase + row) * ldk + k0 + clog * 8;
            u16* l = &lds[buf * 16384 + wid * 4096 + j * 512];
            __builtin_amdgcn_global_load_lds(
                (const __attribute__((address_space(1))) unsigned int*)g,
                (__attribute__((address_space(3))) unsigned int*)l, 16, 0, 0);
        }
    };

    stage(0, Koff);
    int cur = 0;
    for (int t = 0; t < nsteps; ++t) {
        __syncthreads();   // drains buf[cur] loads; all waves done reading buf[cur^1]
        if (t + 1 < nsteps) stage(cur ^ 1, Koff + (t + 1) * 32);

        bf16x8 ah[4], al[4], bh[4], bl[4];
        const bf16x8* L = (const bf16x8*)&lds[cur * 16384];
#pragma unroll
        for (int mi = 0; mi < 4; ++mi) {
            int r = wm + mi * 16 + fr;
            int idx = r * 4 + (fc ^ ((r >> 1) & 3));
            ah[mi] = L[idx];
            al[mi] = L[512 + idx];
        }
#pragma unroll
        for (int nj = 0; nj < 4; ++nj) {
            int r = wn + nj * 16 + fr;
            int idx = r * 4 + (fc ^ ((r >> 1) & 3));
            bh[nj] = L[1024 + idx];
            bl[nj] = L[1536 + idx];
        }
#pragma unroll
        for (int mi = 0; mi < 4; ++mi)
#pragma unroll
            for (int nj = 0; nj < 4; ++nj) {
                acc[mi][nj] = __builtin_amdgcn_mfma_f32_16x16x32_bf16(ah[mi], bh[nj], acc[mi][nj], 0, 0, 0);
                acc[mi][nj] = __builtin_amdgcn_mfma_f32_16x16x32_bf16(ah[mi], bl[nj], acc[mi][nj], 0, 0, 0);
                acc[mi][nj] = __builtin_amdgcn_mfma_f32_16x16x32_bf16(al[mi], bh[nj], acc[mi][nj], 0, 0, 0);
            }
        cur ^= 1;
    }

    float* Cz = C + (size_t)blockIdx.z * LSEQ * ldc;
#pragma unroll
    for (int mi = 0; mi < 4; ++mi) {
        int row_b = m0 + wm + mi * 16 + (lane >> 4) * 4;
#pragma unroll
        for (int nj = 0; nj < 4; ++nj) {
            int col = n0 + wn + nj * 16 + (lane & 15);
#pragma unroll
            for (int r = 0; r < 4; ++r)
                Cz[(size_t)(row_b + r) * ldc + col] = acc[mi][nj][r];
        }
    }
}

// deterministic 4-way partial reduce for out_proj
__global__ __launch_bounds__(256) void reduce4(
    const float* __restrict__ Ppart, float* __restrict__ out, int n)
{
    int i = (blockIdx.x * 256 + threadIdx.x) * 4;
    if (i >= n) return;
    float4 a0 = *(const float4*)&Ppart[i];
    float4 a1 = *(const float4*)&Ppart[(size_t)n + i];
    float4 a2 = *(const float4*)&Ppart[(size_t)2 * n + i];
    float4 a3 = *(const float4*)&Ppart[(size_t)3 * n + i];
    float4 r;
    r.x = ((a0.x + a1.x) + a2.x) + a3.x;
    r.y = ((a0.y + a1.y) + a2.y) + a3.y;
    r.z = ((a0.z + a1.z) + a2.z) + a3.z;
    r.w = ((a0.w + a1.w) + a2.w) + a3.w;
    *(float4*)&out[i] = r;
}

// ---------------- fp32 tiled GEMM (dt_proj): C[m,n]=sum_k A[m][k]*B[n][k] ----------------
template<int EPI>
__global__ __launch_bounds__(256) void gemm_tn(
    const float* __restrict__ A, int lda,
    const float* __restrict__ B, int ldb,
    float* __restrict__ C, int ldc,
    int M, int N, int K,
    const float* __restrict__ bias)
{
    __shared__ float As[16][64 + 4];
    __shared__ float Bs[16][64 + 4];
    const int tid = threadIdx.x;
    const int m0 = blockIdx.x * 64;
    const int n0 = blockIdx.y * 64;
    const int tx = tid & 15;
    const int ty = tid >> 4;
    const int lr = tid >> 4;
    const int lc = tid & 15;
    float acc[4][4] = {};

    for (int k0 = 0; k0 < K; k0 += 16) {
        const int k = k0 + lc;
#pragma unroll
        for (int i = 0; i < 4; ++i) {
            int m = m0 + lr + i * 16;
            As[lc][lr + i * 16] = (m < M) ? A[(size_t)m * lda + k] : 0.f;
        }
#pragma unroll
        for (int i = 0; i < 4; ++i) {
            int n = n0 + lr + i * 16;
            Bs[lc][lr + i * 16] = (n < N) ? B[(size_t)n * ldb + k] : 0.f;
        }
        __syncthreads();
#pragma unroll
        for (int kk = 0; kk < 16; ++kk) {
            float a[4], b[4];
#pragma unroll
            for (int i = 0; i < 4; ++i) a[i] = As[kk][ty * 4 + i];
#pragma unroll
            for (int j = 0; j < 4; ++j) b[j] = Bs[kk][tx * 4 + j];
#pragma unroll
            for (int i = 0; i < 4; ++i)
#pragma unroll
                for (int j = 0; j < 4; ++j)
                    acc[i][j] = fmaf(a[i], b[j], acc[i][j]);
        }
        __syncthreads();
    }

#pragma unroll
    for (int i = 0; i < 4; ++i) {
        int m = m0 + ty * 4 + i;
        if (m >= M) continue;
#pragma unroll
        for (int j = 0; j < 4; ++j) {
            int n = n0 + tx * 4 + j;
            if (n >= N) continue;
            float v = acc[i][j];
            if (EPI == 1) {
                v += bias[n];
                v = fmaxf(v, 0.f) + log1pf(expf(-fabsf(v)));
            }
            C[(size_t)m * ldc + n] = v;
        }
    }
}

// ---------------- fp32 split-K GEMM for x_proj (deterministic two-pass) ----------------
__global__ __launch_bounds__(256) void gemm_tn_splitk(
    const float* __restrict__ A, int lda,
    const float* __restrict__ B, int ldb,
    float* __restrict__ Cpart, int ldc,
    int M, int N, int Kchunk)
{
    __shared__ float As[16][64 + 4];
    __shared__ float Bs[16][64 + 4];
    const int tid = threadIdx.x;
    const int m0 = blockIdx.x * 64;
    const int n0 = blockIdx.y * 64;
    const int kb = blockIdx.z * Kchunk;
    const int tx = tid & 15;
    const int ty = tid >> 4;
    const int lr = tid >> 4;
    const int lc = tid & 15;
    float acc[4][4] = {};

    for (int k0 = kb; k0 < kb + Kchunk; k0 += 16) {
        const int k = k0 + lc;
#pragma unroll
        for (int i = 0; i < 4; ++i) {
            int m = m0 + lr + i * 16;
            As[lc][lr + i * 16] = (m < M) ? A[(size_t)m * lda + k] : 0.f;
        }
#pragma unroll
        for (int i = 0; i < 4; ++i) {
            int n = n0 + lr + i * 16;
            Bs[lc][lr + i * 16] = (n < N) ? B[(size_t)n * ldb + k] : 0.f;
        }
        __syncthreads();
#pragma unroll
        for (int kk = 0; kk < 16; ++kk) {
            float a[4], b[4];
#pragma unroll
            for (int i = 0; i < 4; ++i) a[i] = As[kk][ty * 4 + i];
#pragma unroll
            for (int j = 0; j < 4; ++j) b[j] = Bs[kk][tx * 4 + j];
#pragma unroll
            for (int i = 0; i < 4; ++i)
#pragma unroll
                for (int j = 0; j < 4; ++j)
                    acc[i][j] = fmaf(a[i], b[j], acc[i][j]);
        }
        __syncthreads();
    }

    float* Cs = Cpart + (size_t)blockIdx.z * M * ldc;
#pragma unroll
    for (int i = 0; i < 4; ++i) {
        int m = m0 + ty * 4 + i;
        if (m >= M) continue;
#pragma unroll
        for (int j = 0; j < 4; ++j) {
            int n = n0 + tx * 4 + j;
            if (n >= N) continue;
            Cs[(size_t)m * ldc + n] = acc[i][j];
        }
    }
}

__global__ __launch_bounds__(256) void splitk_reduce(
    const float* __restrict__ Ppart, float* __restrict__ out, int n)
{
    int i = blockIdx.x * 256 + threadIdx.x;
    if (i >= n) return;
    float s = 0.f;
#pragma unroll
    for (int z = 0; z < SPLITK; ++z) s += Ppart[(size_t)z * n + i];
    out[i] = s;
}

// ---------------- depthwise causal conv1d (width 4) + SiLU ----------------
__global__ __launch_bounds__(256) void conv_silu_kernel(
    const float* __restrict__ xz,
    const float* __restrict__ conv_w,
    const float* __restrict__ conv_b,
    float* __restrict__ u)
{
    int idx = blockIdx.x * blockDim.x + threadIdx.x;
    if (idx >= LSEQ * DINNER) return;
    int d = idx % DINNER;
    int t = idx / DINNER;
    float w[4];
#pragma unroll
    for (int j = 0; j < 4; ++j) w[j] = conv_w[d * 4 + j];
    float acc = conv_b[d];
#pragma unroll
    for (int j = 0; j < 4; ++j) {
        int s = t - 3 + j;
        if (s >= 0) acc = fmaf(xz[(size_t)s * (2 * DINNER) + d], w[j], acc);
    }
    float sig = 1.f / (1.f + __expf(-acc));
    u[idx] = acc * sig;
}

// ================= chunked faithful scan (transposed-LDS, lean loops) =================
__global__ __launch_bounds__(256) void scan_chunkprod(
    const float* __restrict__ dtm,
    const float* __restrict__ A_log,
    float* __restrict__ P)
{
    __shared__ float sdtT[16][LDST];
    const int tid = threadIdx.x;
    const int d0 = blockIdx.x * 16;
    const int t0 = blockIdx.y * CHUNK;
    const int r = tid >> 4, c = tid & 15;
#pragma unroll
    for (int i = 0; i < 4; ++i) {
        int t = r + i * 16;
        sdtT[c][t] = dtm[(size_t)(t0 + t) * DINNER + d0 + c];
    }
    __syncthreads();
    const int n = tid & 15, dl = tid >> 4;
    const float Acoef = -expf(A_log[(d0 + dl) * DSTATE + n]);
    float s = 0.f;
#pragma unroll
    for (int tb = 0; tb < 16; ++tb) {
        f32x4 q = *(const f32x4*)&sdtT[dl][tb * 4];
        s += q[0] + q[1] + q[2] + q[3];
    }
    P[(size_t)blockIdx.y * NDN + d0 * DSTATE + tid] = __expf(Acoef * s);
}

template<int PROD>
__global__ __launch_bounds__(256) void scan_exclusive(float* __restrict__ buf)
{
    const int dn = blockIdx.x * 256 + threadIdx.x;
    float run = PROD ? 1.f : 0.f;
#pragma unroll
    for (int cidx = 0; cidx < NCHUNK; ++cidx) {
        float v = buf[(size_t)cidx * NDN + dn];
        buf[(size_t)cidx * NDN + dn] = run;
        run = PROD ? run * v : run + v;
    }
}

__global__ __launch_bounds__(256) void scan_chunksum(
    const float* __restrict__ dtm,
    const float* __restrict__ u,
    const float* __restrict__ xdbl,
    const float* __restrict__ A_log,
    const float* __restrict__ Ppre,
    float* __restrict__ S)
{
    __shared__ float sdtT[16][LDST], suT[16][LDST], sBT[16][LDST];
    const int tid = threadIdx.x;
    const int d0 = blockIdx.x * 16;
    const int t0 = blockIdx.y * CHUNK;
    const int r = tid >> 4, c = tid & 15;
#pragma unroll
    for (int i = 0; i < 4; ++i) {
        int t = r + i * 16;
        size_t row = (size_t)(t0 + t);
        sdtT[c][t] = dtm[row * DINNER + d0 + c];
        suT[c][t]  = u[row * DINNER + d0 + c];
        sBT[c][t]  = xdbl[row * XDBL_W + DTRANK + c];
    }
    __syncthreads();
    const int n = tid & 15, dl = tid >> 4;
    const float Acoef = -expf(A_log[(d0 + dl) * DSTATE + n]);
    float p = Ppre[(size_t)blockIdx.y * NDN + d0 * DSTATE + tid];
    float s = 0.f;
#pragma unroll
    for (int tb = 0; tb < 16; ++tb) {
        f32x4 dq = *(const f32x4*)&sdtT[dl][tb * 4];
        f32x4 uq = *(const f32x4*)&suT[dl][tb * 4];
        f32x4 bq = *(const f32x4*)&sBT[n][tb * 4];
#pragma unroll
        for (int j = 0; j < 4; ++j) {
            float dtv = dq[j];
            p *= __expf(dtv * Acoef);
            s += __fdividef((dtv * bq[j]) * uq[j], fmaxf(p, FEPS));
        }
    }
    S[(size_t)blockIdx.y * NDN + d0 * DSTATE + tid] = s;
}

__global__ __launch_bounds__(256) void scan_final(
    const float* __restrict__ dtm,
    const float* __restrict__ u,
    const float* __restrict__ xdbl,
    const float* __restrict__ A_log,
    const float* __restrict__ Ppre,
    const float* __restrict__ Gpre,
    float* __restrict__ xz)           // part written to cols 0..1535
{
    __shared__ float sdtT[16][LDST], suT[16][LDST], sBT[16][LDST], sCT[16][LDST];
    const int tid = threadIdx.x;
    const int d0 = blockIdx.x * 16;
    const int t0 = blockIdx.y * CHUNK;
    const int r = tid >> 4, c = tid & 15;
#pragma unroll
    for (int i = 0; i < 4; ++i) {
        int t = r + i * 16;
        size_t row = (size_t)(t0 + t);
        sdtT[c][t] = dtm[row * DINNER + d0 + c];
        suT[c][t]  = u[row * DINNER + d0 + c];
        sBT[c][t]  = xdbl[row * XDBL_W + DTRANK + c];
        sCT[c][t]  = xdbl[row * XDBL_W + DTRANK + DSTATE + c];
    }
    __syncthreads();
    const int n = tid & 15, dl = tid >> 4;
    const int d = d0 + dl;
    const float Acoef = -expf(A_log[d * DSTATE + n]);
    float p = Ppre[(size_t)blockIdx.y * NDN + d0 * DSTATE + tid];
    float g = Gpre[(size_t)blockIdx.y * NDN + d0 * DSTATE + tid];
#pragma unroll
    for (int tb = 0; tb < 16; ++tb) {
        f32x4 dq = *(const f32x4*)&sdtT[dl][tb * 4];
        f32x4 uq = *(const f32x4*)&suT[dl][tb * 4];
        f32x4 bq = *(const f32x4*)&sBT[n][tb * 4];
        f32x4 cq = *(const f32x4*)&sCT[n][tb * 4];
#pragma unroll
        for (int j = 0; j < 4; ++j) {
            float dtv = dq[j];
            p *= __expf(dtv * Acoef);
            g += __fdividef((dtv * bq[j]) * uq[j], fmaxf(p, FEPS));
            float part = (g * p) * cq[j];
            part += __shfl_xor(part, 1, 16);
            part += __shfl_xor(part, 2, 16);
            part += __shfl_xor(part, 4, 16);
            part += __shfl_xor(part, 8, 16);
            if (n == 0)
                xz[(size_t)(t0 + tb * 4 + j) * (2 * DINNER) + d] = part;
        }
    }
}

// gate/output epilogue: y = (part + D*u) * silu(z), emitted as bf16 hi/lo planes.
__global__ __launch_bounds__(256) void gate_kernel(
    const float* __restrict__ xz,     // part at cols 0..1535, z at cols 1536..3071
    const float* __restrict__ u,
    const float* __restrict__ Dvec,
    u16* __restrict__ yhi, u16* __restrict__ ylo)
{
    int i4 = (blockIdx.x * 256 + threadIdx.x) * 4;
    if (i4 >= LSEQ * DINNER) return;
    int t = i4 / DINNER;
    int d = i4 - t * DINNER;
    size_t base = (size_t)t * (2 * DINNER) + d;
    float4 part = *(const float4*)&xz[base];
    float4 zv   = *(const float4*)&xz[base + DINNER];
    float4 uv   = *(const float4*)&u[i4];
    float4 Dd   = *(const float4*)&Dvec[d];
    float pa[4] = {part.x, part.y, part.z, part.w};
    float za[4] = {zv.x, zv.y, zv.z, zv.w};
    float ua[4] = {uv.x, uv.y, uv.z, uv.w};
    float Da[4] = {Dd.x, Dd.y, Dd.z, Dd.w};
    u16 ha[4], la[4];
#pragma unroll
    for (int j = 0; j < 4; ++j) {
        float sig = 1.f / (1.f + __expf(-za[j]));
        float yv = (pa[j] + Da[j] * ua[j]) * (za[j] * sig);
        ha[j] = f2bf_rn(yv);
        la[j] = f2bf_rn(yv - bf2f(ha[j]));
    }
    *(ushort4*)&yhi[i4] = make_ushort4(ha[0], ha[1], ha[2], ha[3]);
    *(ushort4*)&ylo[i4] = make_ushort4(la[0], la[1], la[2], la[3]);
}

// ---------------- launch ----------------
extern "C" void kernel_launch(void* const* d_in, const int* in_sizes, int n_in,
                              void* d_out, int out_size, void* d_ws, size_t ws_size,
                              hipStream_t stream) {
    const float* x          = (const float*)d_in[0];
    const float* in_proj_w  = (const float*)d_in[1];
    const float* conv_w     = (const float*)d_in[2];
    const float* conv_b     = (const float*)d_in[3];
    const float* x_proj_w   = (const float*)d_in[4];
    const float* dt_proj_w  = (const float*)d_in[5];
    const float* dt_proj_b  = (const float*)d_in[6];
    const float* A_log      = (const float*)d_in[7];
    const float* Dvec       = (const float*)d_in[8];
    const float* out_proj_w = (const float*)d_in[9];
    float* out = (float*)d_out;

    char* w = (char*)d_ws;
    auto alloc = [&](size_t bytes) { char* p = w; w += (bytes + 255) & ~(size_t)255; return p; };

    float* xz    = (float*)alloc((size_t)LSEQ * 2 * DINNER * 4);
    float* u     = (float*)alloc((size_t)LSEQ * DINNER * 4);
    float* xdbl  = (float*)alloc((size_t)LSEQ * XDBL_W * 4);
    float* dtb   = (float*)alloc((size_t)LSEQ * DINNER * 4);
    float* P     = (float*)alloc((size_t)NCHUNK * NDN * 4);
    float* S     = (float*)alloc((size_t)NCHUNK * NDN * 4);
    float* Ppart = (float*)alloc((size_t)SPLITK * LSEQ * XDBL_W * 4);
    u16* xhi  = (u16*)alloc((size_t)LSEQ * DMODEL * 2);
    u16* xlo  = (u16*)alloc((size_t)LSEQ * DMODEL * 2);
    u16* wihi = (u16*)alloc((size_t)2 * DINNER * DMODEL * 2);
    u16* wilo = (u16*)alloc((size_t)2 * DINNER * DMODEL * 2);
    u16* owhi = (u16*)alloc((size_t)DMODEL * DINNER * 2);
    u16* owlo = (u16*)alloc((size_t)DMODEL * DINNER * 2);
    u16* yhi  = (u16*)alloc((size_t)LSEQ * DINNER * 2);
    u16* ylo  = (u16*)alloc((size_t)LSEQ * DINNER * 2);
    // out_proj partials (OSPLIT x 2048 x 768 fp32 = 25.2MB) aliased over the
    // u..S region (32MB), all dead after gate_kernel which precedes out_proj.
    float* opart = u;

    dim3 blk(256);

    // 0. conversions to bf16 hi/lo
    cvt_split<<<(LSEQ * DMODEL) / 1024, blk, 0, stream>>>(x, xhi, xlo, LSEQ * DMODEL);
    cvt_split<<<(2 * DINNER * DMODEL) / 1024, blk, 0, stream>>>(in_proj_w, wihi, wilo, 2 * DINNER * DMODEL);
    cvt_split<<<(DMODEL * DINNER) / 1024, blk, 0, stream>>>(out_proj_w, owhi, owlo, DMODEL * DINNER);

    // 1. xz = x @ in_proj_w.T   (M=2048, N=3072, K=768), dbuf MFMA
    mfma_gemm_tn<<<dim3(LSEQ / 128, (2 * DINNER) / 128, 1), blk, 0, stream>>>(
        xhi, xlo, wihi, wilo, xz, 2 * DINNER, DMODEL, DMODEL);

    // 2. u = silu(depthwise_conv(xh) + b)
    conv_silu_kernel<<<(LSEQ * DINNER + 255) / 256, blk, 0, stream>>>(xz, conv_w, conv_b, u);

    // 3. x_dbl = u @ x_proj_w.T (M=2048, N=80, K=1536) split-K fp32, deterministic reduce
    gemm_tn_splitk<<<dim3(LSEQ / 64, (XDBL_W + 63) / 64, SPLITK), blk, 0, stream>>>(
        u, DINNER, x_proj_w, DINNER, Ppart, XDBL_W, LSEQ, XDBL_W, DINNER / SPLITK);
    splitk_reduce<<<(LSEQ * XDBL_W + 255) / 256, blk, 0, stream>>>(Ppart, xdbl, LSEQ * XDBL_W);

    // 4. dt = softplus(x_dbl[:, :48] @ dt_proj_w.T + dt_proj_b)
    gemm_tn<1><<<dim3(LSEQ / 64, DINNER / 64), blk, 0, stream>>>(
        xdbl, XDBL_W, dt_proj_w, DTRANK, dtb, DINNER, LSEQ, DINNER, DTRANK, dt_proj_b);

    // 5. chunked faithful selective scan; part -> xz cols 0..1535
    scan_chunkprod<<<dim3(DINNER / 16, NCHUNK), blk, 0, stream>>>(dtb, A_log, P);
    scan_exclusive<1><<<NDN / 256, blk, 0, stream>>>(P);
    scan_chunksum<<<dim3(DINNER / 16, NCHUNK), blk, 0, stream>>>(dtb, u, xdbl, A_log, P, S);
    scan_exclusive<0><<<NDN / 256, blk, 0, stream>>>(S);
    scan_final<<<dim3(DINNER / 16, NCHUNK), blk, 0, stream>>>(
        dtb, u, xdbl, A_log, P, S, xz);

    // 5b. gate epilogue: y = (part + D*u)*silu(z) -> bf16 hi/lo
    gate_kernel<<<(LSEQ * DINNER) / 1024, blk, 0, stream>>>(xz, u, Dvec, yhi, ylo);

    // 6. out = y @ out_proj_w.T (M=2048, N=768, K=1536), split-K=4 + reduce
    //    (opart overwrites u/xdbl/dtb/P/S — all dead at this point)
    mfma_gemm_tn<<<dim3(LSEQ / 128, DMODEL / 128, OSPLIT), blk, 0, stream>>>(
        yhi, ylo, owhi, owlo, opart, DMODEL, DINNER, DINNER / OSPLIT);
    reduce4<<<(LSEQ * DMODEL) / 1024, blk, 0, stream>>>(opart, out, LSEQ * DMODEL);
}

// Round 9
// 238.172 us; speedup vs baseline: 9.4714x; 1.0235x over previous
//
#include <hip/hip_runtime.h>
#include <hip/hip_bf16.h>

// ---------------- sizes ----------------
#define LSEQ 2048
#define DMODEL 768
#define DINNER 1536
#define DSTATE 16
#define DTRANK 48
#define XDBL_W (DTRANK + 2*DSTATE)   // 80
#define CHUNK 64
#define NCHUNK (LSEQ / CHUNK)        // 32
#define NDN (DINNER * DSTATE)        // 24576
#define FEPS 1.1920928955078125e-07f
#define SPLITK 8
#define OSPLIT 4                     // split-K factor for out_proj
#define LDST 68                      // padded LDS row stride (floats)

typedef short bf16x8 __attribute__((ext_vector_type(8)));
typedef float f32x4 __attribute__((ext_vector_type(4)));
typedef unsigned short u16;

__device__ __forceinline__ u16 f2bf_rn(float f) {
    unsigned u = __float_as_uint(f);
    unsigned r = u + 0x7FFFu + ((u >> 16) & 1u);
    return (u16)(r >> 16);
}
__device__ __forceinline__ float bf2f(u16 h) {
    return __uint_as_float(((unsigned)h) << 16);
}

// quad_perm DPP lane exchange (full-rate VALU, no LDS pipe).
// 0xB1 = [1,0,3,2] (xor1 within quad); 0x4E = [2,3,0,1] (xor2 within quad).
template<int CTRL>
__device__ __forceinline__ float qperm(float x) {
    return __int_as_float(__builtin_amdgcn_update_dpp(
        0, __float_as_int(x), CTRL, 0xF, 0xF, true));
}

// ---------------- fp32 -> bf16 hi/lo split conversion ----------------
__global__ __launch_bounds__(256) void cvt_split(
    const float* __restrict__ src, u16* __restrict__ hi, u16* __restrict__ lo, int n)
{
    int i = (blockIdx.x * 256 + threadIdx.x) * 4;
    if (i >= n) return;
    float4 v = *(const float4*)&src[i];
    u16 h0 = f2bf_rn(v.x), h1 = f2bf_rn(v.y), h2 = f2bf_rn(v.z), h3 = f2bf_rn(v.w);
    u16 l0 = f2bf_rn(v.x - bf2f(h0));
    u16 l1 = f2bf_rn(v.y - bf2f(h1));
    u16 l2 = f2bf_rn(v.z - bf2f(h2));
    u16 l3 = f2bf_rn(v.w - bf2f(h3));
    *(ushort4*)&hi[i] = make_ushort4(h0, h1, h2, h3);
    *(ushort4*)&lo[i] = make_ushort4(l0, l1, l2, l3);
}

// ---------------- split-bf16 MFMA GEMM, double-buffered ----------------
__global__ __launch_bounds__(256) void mfma_gemm_tn(
    const u16* __restrict__ Ahi, const u16* __restrict__ Alo,
    const u16* __restrict__ Bhi, const u16* __restrict__ Blo,
    float* __restrict__ C, int ldc, int ldk, int Klen)
{
    __shared__ u16 lds[2 * 4 * 4096];   // 2 buffers x 4 planes x 8KB = 64KB
    const int tid = threadIdx.x;
    const int wid = tid >> 6;
    const int lane = tid & 63;
    const int m0 = blockIdx.x * 128;
    const int n0 = blockIdx.y * 128;
    const int Koff = blockIdx.z * Klen;

    const int st_subrow = lane >> 2;
    const int st_cphys = lane & 3;
    const u16* myplane = (wid == 0) ? Ahi : (wid == 1) ? Alo : (wid == 2) ? Bhi : Blo;
    const int rowbase = (wid < 2) ? m0 : n0;

    f32x4 acc[4][4] = {};
    const int wm = (wid >> 1) * 64;
    const int wn = (wid & 1) * 64;
    const int fr = lane & 15;
    const int fc = lane >> 4;
    const int nsteps = Klen / 32;

    auto stage = [&](int buf, int k0) {
#pragma unroll
        for (int j = 0; j < 8; ++j) {
            int row = j * 16 + st_subrow;
            int clog = st_cphys ^ ((row >> 1) & 3);
            const u16* g = myplane + (size_t)(rowbase + row) * ldk + k0 + clog * 8;
            u16* l = &lds[buf * 16384 + wid * 4096 + j * 512];
            __builtin_amdgcn_global_load_lds(
                (const __attribute__((address_space(1))) unsigned int*)g,
                (__attribute__((address_space(3))) unsigned int*)l, 16, 0, 0);
        }
    };

    stage(0, Koff);
    int cur = 0;
    for (int t = 0; t < nsteps; ++t) {
        __syncthreads();
        if (t + 1 < nsteps) stage(cur ^ 1, Koff + (t + 1) * 32);

        bf16x8 ah[4], al[4], bh[4], bl[4];
        const bf16x8* L = (const bf16x8*)&lds[cur * 16384];
#pragma unroll
        for (int mi = 0; mi < 4; ++mi) {
            int r = wm + mi * 16 + fr;
            int idx = r * 4 + (fc ^ ((r >> 1) & 3));
            ah[mi] = L[idx];
            al[mi] = L[512 + idx];
        }
#pragma unroll
        for (int nj = 0; nj < 4; ++nj) {
            int r = wn + nj * 16 + fr;
            int idx = r * 4 + (fc ^ ((r >> 1) & 3));
            bh[nj] = L[1024 + idx];
            bl[nj] = L[1536 + idx];
        }
#pragma unroll
        for (int mi = 0; mi < 4; ++mi)
#pragma unroll
            for (int nj = 0; nj < 4; ++nj) {
                acc[mi][nj] = __builtin_amdgcn_mfma_f32_16x16x32_bf16(ah[mi], bh[nj], acc[mi][nj], 0, 0, 0);
                acc[mi][nj] = __builtin_amdgcn_mfma_f32_16x16x32_bf16(ah[mi], bl[nj], acc[mi][nj], 0, 0, 0);
                acc[mi][nj] = __builtin_amdgcn_mfma_f32_16x16x32_bf16(al[mi], bh[nj], acc[mi][nj], 0, 0, 0);
            }
        cur ^= 1;
    }

    float* Cz = C + (size_t)blockIdx.z * LSEQ * ldc;
#pragma unroll
    for (int mi = 0; mi < 4; ++mi) {
        int row_b = m0 + wm + mi * 16 + (lane >> 4) * 4;
#pragma unroll
        for (int nj = 0; nj < 4; ++nj) {
            int col = n0 + wn + nj * 16 + (lane & 15);
#pragma unroll
            for (int r = 0; r < 4; ++r)
                Cz[(size_t)(row_b + r) * ldc + col] = acc[mi][nj][r];
        }
    }
}

// deterministic 4-way partial reduce for out_proj
__global__ __launch_bounds__(256) void reduce4(
    const float* __restrict__ Ppart, float* __restrict__ out, int n)
{
    int i = (blockIdx.x * 256 + threadIdx.x) * 4;
    if (i >= n) return;
    float4 a0 = *(const float4*)&Ppart[i];
    float4 a1 = *(const float4*)&Ppart[(size_t)n + i];
    float4 a2 = *(const float4*)&Ppart[(size_t)2 * n + i];
    float4 a3 = *(const float4*)&Ppart[(size_t)3 * n + i];
    float4 r;
    r.x = ((a0.x + a1.x) + a2.x) + a3.x;
    r.y = ((a0.y + a1.y) + a2.y) + a3.y;
    r.z = ((a0.z + a1.z) + a2.z) + a3.z;
    r.w = ((a0.w + a1.w) + a2.w) + a3.w;
    *(float4*)&out[i] = r;
}

// ---------------- fp32 tiled GEMM (dt_proj) ----------------
template<int EPI>
__global__ __launch_bounds__(256) void gemm_tn(
    const float* __restrict__ A, int lda,
    const float* __restrict__ B, int ldb,
    float* __restrict__ C, int ldc,
    int M, int N, int K,
    const float* __restrict__ bias)
{
    __shared__ float As[16][64 + 4];
    __shared__ float Bs[16][64 + 4];
    const int tid = threadIdx.x;
    const int m0 = blockIdx.x * 64;
    const int n0 = blockIdx.y * 64;
    const int tx = tid & 15;
    const int ty = tid >> 4;
    const int lr = tid >> 4;
    const int lc = tid & 15;
    float acc[4][4] = {};

    for (int k0 = 0; k0 < K; k0 += 16) {
        const int k = k0 + lc;
#pragma unroll
        for (int i = 0; i < 4; ++i) {
            int m = m0 + lr + i * 16;
            As[lc][lr + i * 16] = (m < M) ? A[(size_t)m * lda + k] : 0.f;
        }
#pragma unroll
        for (int i = 0; i < 4; ++i) {
            int n = n0 + lr + i * 16;
            Bs[lc][lr + i * 16] = (n < N) ? B[(size_t)n * ldb + k] : 0.f;
        }
        __syncthreads();
#pragma unroll
        for (int kk = 0; kk < 16; ++kk) {
            float a[4], b[4];
#pragma unroll
            for (int i = 0; i < 4; ++i) a[i] = As[kk][ty * 4 + i];
#pragma unroll
            for (int j = 0; j < 4; ++j) b[j] = Bs[kk][tx * 4 + j];
#pragma unroll
            for (int i = 0; i < 4; ++i)
#pragma unroll
                for (int j = 0; j < 4; ++j)
                    acc[i][j] = fmaf(a[i], b[j], acc[i][j]);
        }
        __syncthreads();
    }

#pragma unroll
    for (int i = 0; i < 4; ++i) {
        int m = m0 + ty * 4 + i;
        if (m >= M) continue;
#pragma unroll
        for (int j = 0; j < 4; ++j) {
            int n = n0 + tx * 4 + j;
            if (n >= N) continue;
            float v = acc[i][j];
            if (EPI == 1) {
                v += bias[n];
                v = fmaxf(v, 0.f) + log1pf(expf(-fabsf(v)));
            }
            C[(size_t)m * ldc + n] = v;
        }
    }
}

// ---------------- fp32 split-K GEMM for x_proj ----------------
__global__ __launch_bounds__(256) void gemm_tn_splitk(
    const float* __restrict__ A, int lda,
    const float* __restrict__ B, int ldb,
    float* __restrict__ Cpart, int ldc,
    int M, int N, int Kchunk)
{
    __shared__ float As[16][64 + 4];
    __shared__ float Bs[16][64 + 4];
    const int tid = threadIdx.x;
    const int m0 = blockIdx.x * 64;
    const int n0 = blockIdx.y * 64;
    const int kb = blockIdx.z * Kchunk;
    const int tx = tid & 15;
    const int ty = tid >> 4;
    const int lr = tid >> 4;
    const int lc = tid & 15;
    float acc[4][4] = {};

    for (int k0 = kb; k0 < kb + Kchunk; k0 += 16) {
        const int k = k0 + lc;
#pragma unroll
        for (int i = 0; i < 4; ++i) {
            int m = m0 + lr + i * 16;
            As[lc][lr + i * 16] = (m < M) ? A[(size_t)m * lda + k] : 0.f;
        }
#pragma unroll
        for (int i = 0; i < 4; ++i) {
            int n = n0 + lr + i * 16;
            Bs[lc][lr + i * 16] = (n < N) ? B[(size_t)n * ldb + k] : 0.f;
        }
        __syncthreads();
#pragma unroll
        for (int kk = 0; kk < 16; ++kk) {
            float a[4], b[4];
#pragma unroll
            for (int i = 0; i < 4; ++i) a[i] = As[kk][ty * 4 + i];
#pragma unroll
            for (int j = 0; j < 4; ++j) b[j] = Bs[kk][tx * 4 + j];
#pragma unroll
            for (int i = 0; i < 4; ++i)
#pragma unroll
                for (int j = 0; j < 4; ++j)
                    acc[i][j] = fmaf(a[i], b[j], acc[i][j]);
        }
        __syncthreads();
    }

    float* Cs = Cpart + (size_t)blockIdx.z * M * ldc;
#pragma unroll
    for (int i = 0; i < 4; ++i) {
        int m = m0 + ty * 4 + i;
        if (m >= M) continue;
#pragma unroll
        for (int j = 0; j < 4; ++j) {
            int n = n0 + tx * 4 + j;
            if (n >= N) continue;
            Cs[(size_t)m * ldc + n] = acc[i][j];
        }
    }
}

__global__ __launch_bounds__(256) void splitk_reduce(
    const float* __restrict__ Ppart, float* __restrict__ out, int n)
{
    int i = blockIdx.x * 256 + threadIdx.x;
    if (i >= n) return;
    float s = 0.f;
#pragma unroll
    for (int z = 0; z < SPLITK; ++z) s += Ppart[(size_t)z * n + i];
    out[i] = s;
}

// ---------------- depthwise causal conv1d (width 4) + SiLU ----------------
__global__ __launch_bounds__(256) void conv_silu_kernel(
    const float* __restrict__ xz,
    const float* __restrict__ conv_w,
    const float* __restrict__ conv_b,
    float* __restrict__ u)
{
    int idx = blockIdx.x * blockDim.x + threadIdx.x;
    if (idx >= LSEQ * DINNER) return;
    int d = idx % DINNER;
    int t = idx / DINNER;
    float w[4];
#pragma unroll
    for (int j = 0; j < 4; ++j) w[j] = conv_w[d * 4 + j];
    float acc = conv_b[d];
#pragma unroll
    for (int j = 0; j < 4; ++j) {
        int s = t - 3 + j;
        if (s >= 0) acc = fmaf(xz[(size_t)s * (2 * DINNER) + d], w[j], acc);
    }
    float sig = 1.f / (1.f + __expf(-acc));
    u[idx] = acc * sig;
}

// ================= chunked faithful scan =================
__global__ __launch_bounds__(256) void scan_chunkprod(
    const float* __restrict__ dtm,
    const float* __restrict__ A_log,
    float* __restrict__ P)
{
    __shared__ float sdtT[16][LDST];
    const int tid = threadIdx.x;
    const int d0 = blockIdx.x * 16;
    const int t0 = blockIdx.y * CHUNK;
    const int r = tid >> 4, c = tid & 15;
#pragma unroll
    for (int i = 0; i < 4; ++i) {
        int t = r + i * 16;
        sdtT[c][t] = dtm[(size_t)(t0 + t) * DINNER + d0 + c];
    }
    __syncthreads();
    const int n = tid & 15, dl = tid >> 4;
    const float Acoef = -expf(A_log[(d0 + dl) * DSTATE + n]);
    float s = 0.f;
#pragma unroll
    for (int tb = 0; tb < 16; ++tb) {
        f32x4 q = *(const f32x4*)&sdtT[dl][tb * 4];
        s += q[0] + q[1] + q[2] + q[3];
    }
    P[(size_t)blockIdx.y * NDN + d0 * DSTATE + tid] = __expf(Acoef * s);
}

template<int PROD>
__global__ __launch_bounds__(256) void scan_exclusive(float* __restrict__ buf)
{
    const int dn = blockIdx.x * 256 + threadIdx.x;
    float run = PROD ? 1.f : 0.f;
#pragma unroll
    for (int cidx = 0; cidx < NCHUNK; ++cidx) {
        float v = buf[(size_t)cidx * NDN + dn];
        buf[(size_t)cidx * NDN + dn] = run;
        run = PROD ? run * v : run + v;
    }
}

__global__ __launch_bounds__(256) void scan_chunksum(
    const float* __restrict__ dtm,
    const float* __restrict__ u,
    const float* __restrict__ xdbl,
    const float* __restrict__ A_log,
    const float* __restrict__ Ppre,
    float* __restrict__ S)
{
    __shared__ float sdtT[16][LDST], suT[16][LDST], sBT[16][LDST];
    const int tid = threadIdx.x;
    const int d0 = blockIdx.x * 16;
    const int t0 = blockIdx.y * CHUNK;
    const int r = tid >> 4, c = tid & 15;
#pragma unroll
    for (int i = 0; i < 4; ++i) {
        int t = r + i * 16;
        size_t row = (size_t)(t0 + t);
        sdtT[c][t] = dtm[row * DINNER + d0 + c];
        suT[c][t]  = u[row * DINNER + d0 + c];
        sBT[c][t]  = xdbl[row * XDBL_W + DTRANK + c];
    }
    __syncthreads();
    const int n = tid & 15, dl = tid >> 4;
    const float Acoef = -expf(A_log[(d0 + dl) * DSTATE + n]);
    float p = Ppre[(size_t)blockIdx.y * NDN + d0 * DSTATE + tid];
    float s = 0.f;
#pragma unroll
    for (int tb = 0; tb < 16; ++tb) {
        f32x4 dq = *(const f32x4*)&sdtT[dl][tb * 4];
        f32x4 uq = *(const f32x4*)&suT[dl][tb * 4];
        f32x4 bq = *(const f32x4*)&sBT[n][tb * 4];
#pragma unroll
        for (int j = 0; j < 4; ++j) {
            float dtv = dq[j];
            p *= __expf(dtv * Acoef);
            s += __fdividef((dtv * bq[j]) * uq[j], fmaxf(p, FEPS));
        }
    }
    S[(size_t)blockIdx.y * NDN + d0 * DSTATE + tid] = s;
}

// Phase 3c: 4-n-per-lane layout — quad-DPP reduction, zero LDS-pipe cross-lane ops.
// block: 256 thr = 4 waves; wave w owns d in [d0+16w, d0+16w+16); lane: dl=lane>>2, nq=lane&3.
__global__ __launch_bounds__(256) void scan_final(
    const float* __restrict__ dtm,
    const float* __restrict__ u,
    const float* __restrict__ xdbl,
    const float* __restrict__ A_log,
    const float* __restrict__ Ppre,
    const float* __restrict__ Gpre,
    float* __restrict__ xz)           // part written to cols 0..1535
{
    __shared__ float sdtT[64][LDST], suT[64][LDST];
    __shared__ float sBT[16][LDST], sCT[16][LDST];
    const int tid = threadIdx.x;
    const int d0 = blockIdx.x * 64;
    const int t0 = blockIdx.y * CHUNK;

    // stage dt,u (64 d x 64 t), coalesced global reads
#pragma unroll
    for (int i = 0; i < 16; ++i) {
        int idx = i * 256 + tid;
        int dl = idx & 63, t = idx >> 6;
        size_t row = (size_t)(t0 + t);
        sdtT[dl][t] = dtm[row * DINNER + d0 + dl];
        suT[dl][t]  = u[row * DINNER + d0 + dl];
    }
    // stage B,C (16 n x 64 t)
#pragma unroll
    for (int i = 0; i < 4; ++i) {
        int idx = i * 256 + tid;
        int n = idx & 15, t = idx >> 4;
        size_t row = (size_t)(t0 + t);
        sBT[n][t] = xdbl[row * XDBL_W + DTRANK + n];
        sCT[n][t] = xdbl[row * XDBL_W + DTRANK + DSTATE + n];
    }
    __syncthreads();

    const int lane = tid & 63, wid = tid >> 6;
    const int dloc = wid * 16 + (lane >> 2);   // 0..63
    const int d = d0 + dloc;
    const int nq = lane & 3;                   // owns n = nq*4 .. nq*4+3

    f32x4 Ar = *(const f32x4*)&A_log[d * DSTATE + nq * 4];
    float Ac[4] = {-expf(Ar[0]), -expf(Ar[1]), -expf(Ar[2]), -expf(Ar[3])};
    size_t pgbase = (size_t)blockIdx.y * NDN + (size_t)d * DSTATE + nq * 4;
    f32x4 p = *(const f32x4*)&Ppre[pgbase];
    f32x4 g = *(const f32x4*)&Gpre[pgbase];

#pragma unroll
    for (int tb = 0; tb < 16; ++tb) {
        f32x4 dq = *(const f32x4*)&sdtT[dloc][tb * 4];
        f32x4 uq = *(const f32x4*)&suT[dloc][tb * 4];
        f32x4 b0 = *(const f32x4*)&sBT[nq * 4 + 0][tb * 4];
        f32x4 b1 = *(const f32x4*)&sBT[nq * 4 + 1][tb * 4];
        f32x4 b2 = *(const f32x4*)&sBT[nq * 4 + 2][tb * 4];
        f32x4 b3 = *(const f32x4*)&sBT[nq * 4 + 3][tb * 4];
        f32x4 c0 = *(const f32x4*)&sCT[nq * 4 + 0][tb * 4];
        f32x4 c1 = *(const f32x4*)&sCT[nq * 4 + 1][tb * 4];
        f32x4 c2 = *(const f32x4*)&sCT[nq * 4 + 2][tb * 4];
        f32x4 c3 = *(const f32x4*)&sCT[nq * 4 + 3][tb * 4];
#pragma unroll
        for (int j = 0; j < 4; ++j) {
            float dtv = dq[j], uv = uq[j];
            // 4 independent recurrences (ILP-4)
            p[0] *= __expf(dtv * Ac[0]);
            p[1] *= __expf(dtv * Ac[1]);
            p[2] *= __expf(dtv * Ac[2]);
            p[3] *= __expf(dtv * Ac[3]);
            g[0] += __fdividef((dtv * b0[j]) * uv, fmaxf(p[0], FEPS));
            g[1] += __fdividef((dtv * b1[j]) * uv, fmaxf(p[1], FEPS));
            g[2] += __fdividef((dtv * b2[j]) * uv, fmaxf(p[2], FEPS));
            g[3] += __fdividef((dtv * b3[j]) * uv, fmaxf(p[3], FEPS));
            float part = (g[0] * p[0]) * c0[j];
            part = fmaf(g[1] * p[1], c1[j], part);
            part = fmaf(g[2] * p[2], c2[j], part);
            part = fmaf(g[3] * p[3], c3[j], part);
            // quad reduction via DPP (VALU, no LDS)
            part += qperm<0xB1>(part);   // xor1
            part += qperm<0x4E>(part);   // xor2
            if (nq == 0)
                xz[(size_t)(t0 + tb * 4 + j) * (2 * DINNER) + d] = part;
        }
    }
}

// gate/output epilogue: y = (part + D*u) * silu(z) -> bf16 hi/lo planes
__global__ __launch_bounds__(256) void gate_kernel(
    const float* __restrict__ xz,
    const float* __restrict__ u,
    const float* __restrict__ Dvec,
    u16* __restrict__ yhi, u16* __restrict__ ylo)
{
    int i4 = (blockIdx.x * 256 + threadIdx.x) * 4;
    if (i4 >= LSEQ * DINNER) return;
    int t = i4 / DINNER;
    int d = i4 - t * DINNER;
    size_t base = (size_t)t * (2 * DINNER) + d;
    float4 part = *(const float4*)&xz[base];
    float4 zv   = *(const float4*)&xz[base + DINNER];
    float4 uv   = *(const float4*)&u[i4];
    float4 Dd   = *(const float4*)&Dvec[d];
    float pa[4] = {part.x, part.y, part.z, part.w};
    float za[4] = {zv.x, zv.y, zv.z, zv.w};
    float ua[4] = {uv.x, uv.y, uv.z, uv.w};
    float Da[4] = {Dd.x, Dd.y, Dd.z, Dd.w};
    u16 ha[4], la[4];
#pragma unroll
    for (int j = 0; j < 4; ++j) {
        float sig = 1.f / (1.f + __expf(-za[j]));
        float yv = (pa[j] + Da[j] * ua[j]) * (za[j] * sig);
        ha[j] = f2bf_rn(yv);
        la[j] = f2bf_rn(yv - bf2f(ha[j]));
    }
    *(ushort4*)&yhi[i4] = make_ushort4(ha[0], ha[1], ha[2], ha[3]);
    *(ushort4*)&ylo[i4] = make_ushort4(la[0], la[1], la[2], la[3]);
}

// ---------------- launch ----------------
extern "C" void kernel_launch(void* const* d_in, const int* in_sizes, int n_in,
                              void* d_out, int out_size, void* d_ws, size_t ws_size,
                              hipStream_t stream) {
    const float* x          = (const float*)d_in[0];
    const float* in_proj_w  = (const float*)d_in[1];
    const float* conv_w     = (const float*)d_in[2];
    const float* conv_b     = (const float*)d_in[3];
    const float* x_proj_w   = (const float*)d_in[4];
    const float* dt_proj_w  = (const float*)d_in[5];
    const float* dt_proj_b  = (const float*)d_in[6];
    const float* A_log      = (const float*)d_in[7];
    const float* Dvec       = (const float*)d_in[8];
    const float* out_proj_w = (const float*)d_in[9];
    float* out = (float*)d_out;

    char* w = (char*)d_ws;
    auto alloc = [&](size_t bytes) { char* p = w; w += (bytes + 255) & ~(size_t)255; return p; };

    float* xz    = (float*)alloc((size_t)LSEQ * 2 * DINNER * 4);
    float* u     = (float*)alloc((size_t)LSEQ * DINNER * 4);
    float* xdbl  = (float*)alloc((size_t)LSEQ * XDBL_W * 4);
    float* dtb   = (float*)alloc((size_t)LSEQ * DINNER * 4);
    float* P     = (float*)alloc((size_t)NCHUNK * NDN * 4);
    float* S     = (float*)alloc((size_t)NCHUNK * NDN * 4);
    float* Ppart = (float*)alloc((size_t)SPLITK * LSEQ * XDBL_W * 4);
    u16* xhi  = (u16*)alloc((size_t)LSEQ * DMODEL * 2);
    u16* xlo  = (u16*)alloc((size_t)LSEQ * DMODEL * 2);
    u16* wihi = (u16*)alloc((size_t)2 * DINNER * DMODEL * 2);
    u16* wilo = (u16*)alloc((size_t)2 * DINNER * DMODEL * 2);
    u16* owhi = (u16*)alloc((size_t)DMODEL * DINNER * 2);
    u16* owlo = (u16*)alloc((size_t)DMODEL * DINNER * 2);
    u16* yhi  = (u16*)alloc((size_t)LSEQ * DINNER * 2);
    u16* ylo  = (u16*)alloc((size_t)LSEQ * DINNER * 2);
    float* opart = u;   // out_proj partials alias u..S (dead after gate_kernel)

    dim3 blk(256);

    // 0. conversions to bf16 hi/lo
    cvt_split<<<(LSEQ * DMODEL) / 1024, blk, 0, stream>>>(x, xhi, xlo, LSEQ * DMODEL);
    cvt_split<<<(2 * DINNER * DMODEL) / 1024, blk, 0, stream>>>(in_proj_w, wihi, wilo, 2 * DINNER * DMODEL);
    cvt_split<<<(DMODEL * DINNER) / 1024, blk, 0, stream>>>(out_proj_w, owhi, owlo, DMODEL * DINNER);

    // 1. xz = x @ in_proj_w.T   (M=2048, N=3072, K=768), dbuf MFMA
    mfma_gemm_tn<<<dim3(LSEQ / 128, (2 * DINNER) / 128, 1), blk, 0, stream>>>(
        xhi, xlo, wihi, wilo, xz, 2 * DINNER, DMODEL, DMODEL);

    // 2. u = silu(depthwise_conv(xh) + b)
    conv_silu_kernel<<<(LSEQ * DINNER + 255) / 256, blk, 0, stream>>>(xz, conv_w, conv_b, u);

    // 3. x_dbl = u @ x_proj_w.T (split-K fp32, deterministic reduce)
    gemm_tn_splitk<<<dim3(LSEQ / 64, (XDBL_W + 63) / 64, SPLITK), blk, 0, stream>>>(
        u, DINNER, x_proj_w, DINNER, Ppart, XDBL_W, LSEQ, XDBL_W, DINNER / SPLITK);
    splitk_reduce<<<(LSEQ * XDBL_W + 255) / 256, blk, 0, stream>>>(Ppart, xdbl, LSEQ * XDBL_W);

    // 4. dt = softplus(x_dbl[:, :48] @ dt_proj_w.T + dt_proj_b)
    gemm_tn<1><<<dim3(LSEQ / 64, DINNER / 64), blk, 0, stream>>>(
        xdbl, XDBL_W, dt_proj_w, DTRANK, dtb, DINNER, LSEQ, DINNER, DTRANK, dt_proj_b);

    // 5. chunked faithful selective scan; part -> xz cols 0..1535
    scan_chunkprod<<<dim3(DINNER / 16, NCHUNK), blk, 0, stream>>>(dtb, A_log, P);
    scan_exclusive<1><<<NDN / 256, blk, 0, stream>>>(P);
    scan_chunksum<<<dim3(DINNER / 16, NCHUNK), blk, 0, stream>>>(dtb, u, xdbl, A_log, P, S);
    scan_exclusive<0><<<NDN / 256, blk, 0, stream>>>(S);
    scan_final<<<dim3(DINNER / 64, NCHUNK), blk, 0, stream>>>(
        dtb, u, xdbl, A_log, P, S, xz);

    // 5b. gate epilogue
    gate_kernel<<<(LSEQ * DINNER) / 1024, blk, 0, stream>>>(xz, u, Dvec, yhi, ylo);

    // 6. out = y @ out_proj_w.T (split-K=4 + reduce)
    mfma_gemm_tn<<<dim3(LSEQ / 128, DMODEL / 128, OSPLIT), blk, 0, stream>>>(
        yhi, ylo, owhi, owlo, opart, DMODEL, DINNER, DINNER / OSPLIT);
    reduce4<<<(LSEQ * DMODEL) / 1024, blk, 0, stream>>>(opart, out, LSEQ * DMODEL);
}

// Round 10
// 236.062 us; speedup vs baseline: 9.5561x; 1.0089x over previous
//
#include <hip/hip_runtime.h>
#include <hip/hip_bf16.h>

// ---------------- sizes ----------------
#define LSEQ 2048
#define DMODEL 768
#define DINNER 1536
#define DSTATE 16
#define DTRANK 48
#define XDBL_W (DTRANK + 2*DSTATE)   // 80
#define CHUNK 64
#define NCHUNK (LSEQ / CHUNK)        // 32
#define NDN (DINNER * DSTATE)        // 24576
#define FEPS 1.1920928955078125e-07f
#define SPLITK 8
#define OSPLIT 4                     // split-K factor for out_proj
#define LDST 68                      // padded LDS row stride (floats)

typedef short bf16x8 __attribute__((ext_vector_type(8)));
typedef float f32x4 __attribute__((ext_vector_type(4)));
typedef unsigned short u16;

__device__ __forceinline__ u16 f2bf_rn(float f) {
    unsigned u = __float_as_uint(f);
    unsigned r = u + 0x7FFFu + ((u >> 16) & 1u);
    return (u16)(r >> 16);
}
__device__ __forceinline__ float bf2f(u16 h) {
    return __uint_as_float(((unsigned)h) << 16);
}

// quad_perm DPP lane exchange (full-rate VALU, no LDS pipe).
template<int CTRL>
__device__ __forceinline__ float qperm(float x) {
    return __int_as_float(__builtin_amdgcn_update_dpp(
        0, __float_as_int(x), CTRL, 0xF, 0xF, true));
}

// ---------------- fp32 -> bf16 hi/lo split conversion ----------------
__global__ __launch_bounds__(256) void cvt_split(
    const float* __restrict__ src, u16* __restrict__ hi, u16* __restrict__ lo, int n)
{
    int i = (blockIdx.x * 256 + threadIdx.x) * 4;
    if (i >= n) return;
    float4 v = *(const float4*)&src[i];
    u16 h0 = f2bf_rn(v.x), h1 = f2bf_rn(v.y), h2 = f2bf_rn(v.z), h3 = f2bf_rn(v.w);
    u16 l0 = f2bf_rn(v.x - bf2f(h0));
    u16 l1 = f2bf_rn(v.y - bf2f(h1));
    u16 l2 = f2bf_rn(v.z - bf2f(h2));
    u16 l3 = f2bf_rn(v.w - bf2f(h3));
    *(ushort4*)&hi[i] = make_ushort4(h0, h1, h2, h3);
    *(ushort4*)&lo[i] = make_ushort4(l0, l1, l2, l3);
}

// ---------------- split-bf16 MFMA GEMM, double-buffered ----------------
__global__ __launch_bounds__(256) void mfma_gemm_tn(
    const u16* __restrict__ Ahi, const u16* __restrict__ Alo,
    const u16* __restrict__ Bhi, const u16* __restrict__ Blo,
    float* __restrict__ C, int ldc, int ldk, int Klen)
{
    __shared__ u16 lds[2 * 4 * 4096];   // 2 buffers x 4 planes x 8KB = 64KB
    const int tid = threadIdx.x;
    const int wid = tid >> 6;
    const int lane = tid & 63;
    const int m0 = blockIdx.x * 128;
    const int n0 = blockIdx.y * 128;
    const int Koff = blockIdx.z * Klen;

    const int st_subrow = lane >> 2;
    const int st_cphys = lane & 3;
    const u16* myplane = (wid == 0) ? Ahi : (wid == 1) ? Alo : (wid == 2) ? Bhi : Blo;
    const int rowbase = (wid < 2) ? m0 : n0;

    f32x4 acc[4][4] = {};
    const int wm = (wid >> 1) * 64;
    const int wn = (wid & 1) * 64;
    const int fr = lane & 15;
    const int fc = lane >> 4;
    const int nsteps = Klen / 32;

    auto stage = [&](int buf, int k0) {
#pragma unroll
        for (int j = 0; j < 8; ++j) {
            int row = j * 16 + st_subrow;
            int clog = st_cphys ^ ((row >> 1) & 3);
            const u16* g = myplane + (size_t)(rowbase + row) * ldk + k0 + clog * 8;
            u16* l = &lds[buf * 16384 + wid * 4096 + j * 512];
            __builtin_amdgcn_global_load_lds(
                (const __attribute__((address_space(1))) unsigned int*)g,
                (__attribute__((address_space(3))) unsigned int*)l, 16, 0, 0);
        }
    };

    stage(0, Koff);
    int cur = 0;
    for (int t = 0; t < nsteps; ++t) {
        __syncthreads();
        if (t + 1 < nsteps) stage(cur ^ 1, Koff + (t + 1) * 32);

        bf16x8 ah[4], al[4], bh[4], bl[4];
        const bf16x8* L = (const bf16x8*)&lds[cur * 16384];
#pragma unroll
        for (int mi = 0; mi < 4; ++mi) {
            int r = wm + mi * 16 + fr;
            int idx = r * 4 + (fc ^ ((r >> 1) & 3));
            ah[mi] = L[idx];
            al[mi] = L[512 + idx];
        }
#pragma unroll
        for (int nj = 0; nj < 4; ++nj) {
            int r = wn + nj * 16 + fr;
            int idx = r * 4 + (fc ^ ((r >> 1) & 3));
            bh[nj] = L[1024 + idx];
            bl[nj] = L[1536 + idx];
        }
#pragma unroll
        for (int mi = 0; mi < 4; ++mi)
#pragma unroll
            for (int nj = 0; nj < 4; ++nj) {
                acc[mi][nj] = __builtin_amdgcn_mfma_f32_16x16x32_bf16(ah[mi], bh[nj], acc[mi][nj], 0, 0, 0);
                acc[mi][nj] = __builtin_amdgcn_mfma_f32_16x16x32_bf16(ah[mi], bl[nj], acc[mi][nj], 0, 0, 0);
                acc[mi][nj] = __builtin_amdgcn_mfma_f32_16x16x32_bf16(al[mi], bh[nj], acc[mi][nj], 0, 0, 0);
            }
        cur ^= 1;
    }

    float* Cz = C + (size_t)blockIdx.z * LSEQ * ldc;
#pragma unroll
    for (int mi = 0; mi < 4; ++mi) {
        int row_b = m0 + wm + mi * 16 + (lane >> 4) * 4;
#pragma unroll
        for (int nj = 0; nj < 4; ++nj) {
            int col = n0 + wn + nj * 16 + (lane & 15);
#pragma unroll
            for (int r = 0; r < 4; ++r)
                Cz[(size_t)(row_b + r) * ldc + col] = acc[mi][nj][r];
        }
    }
}

// deterministic 4-way partial reduce for out_proj
__global__ __launch_bounds__(256) void reduce4(
    const float* __restrict__ Ppart, float* __restrict__ out, int n)
{
    int i = (blockIdx.x * 256 + threadIdx.x) * 4;
    if (i >= n) return;
    float4 a0 = *(const float4*)&Ppart[i];
    float4 a1 = *(const float4*)&Ppart[(size_t)n + i];
    float4 a2 = *(const float4*)&Ppart[(size_t)2 * n + i];
    float4 a3 = *(const float4*)&Ppart[(size_t)3 * n + i];
    float4 r;
    r.x = ((a0.x + a1.x) + a2.x) + a3.x;
    r.y = ((a0.y + a1.y) + a2.y) + a3.y;
    r.z = ((a0.z + a1.z) + a2.z) + a3.z;
    r.w = ((a0.w + a1.w) + a2.w) + a3.w;
    *(float4*)&out[i] = r;
}

// ---------------- fp32 tiled GEMM (dt_proj) ----------------
template<int EPI>
__global__ __launch_bounds__(256) void gemm_tn(
    const float* __restrict__ A, int lda,
    const float* __restrict__ B, int ldb,
    float* __restrict__ C, int ldc,
    int M, int N, int K,
    const float* __restrict__ bias)
{
    __shared__ float As[16][64 + 4];
    __shared__ float Bs[16][64 + 4];
    const int tid = threadIdx.x;
    const int m0 = blockIdx.x * 64;
    const int n0 = blockIdx.y * 64;
    const int tx = tid & 15;
    const int ty = tid >> 4;
    const int lr = tid >> 4;
    const int lc = tid & 15;
    float acc[4][4] = {};

    for (int k0 = 0; k0 < K; k0 += 16) {
        const int k = k0 + lc;
#pragma unroll
        for (int i = 0; i < 4; ++i) {
            int m = m0 + lr + i * 16;
            As[lc][lr + i * 16] = (m < M) ? A[(size_t)m * lda + k] : 0.f;
        }
#pragma unroll
        for (int i = 0; i < 4; ++i) {
            int n = n0 + lr + i * 16;
            Bs[lc][lr + i * 16] = (n < N) ? B[(size_t)n * ldb + k] : 0.f;
        }
        __syncthreads();
#pragma unroll
        for (int kk = 0; kk < 16; ++kk) {
            float a[4], b[4];
#pragma unroll
            for (int i = 0; i < 4; ++i) a[i] = As[kk][ty * 4 + i];
#pragma unroll
            for (int j = 0; j < 4; ++j) b[j] = Bs[kk][tx * 4 + j];
#pragma unroll
            for (int i = 0; i < 4; ++i)
#pragma unroll
                for (int j = 0; j < 4; ++j)
                    acc[i][j] = fmaf(a[i], b[j], acc[i][j]);
        }
        __syncthreads();
    }

#pragma unroll
    for (int i = 0; i < 4; ++i) {
        int m = m0 + ty * 4 + i;
        if (m >= M) continue;
#pragma unroll
        for (int j = 0; j < 4; ++j) {
            int n = n0 + tx * 4 + j;
            if (n >= N) continue;
            float v = acc[i][j];
            if (EPI == 1) {
                v += bias[n];
                v = fmaxf(v, 0.f) + log1pf(expf(-fabsf(v)));
            }
            C[(size_t)m * ldc + n] = v;
        }
    }
}

// ---------------- fp32 split-K GEMM for x_proj ----------------
__global__ __launch_bounds__(256) void gemm_tn_splitk(
    const float* __restrict__ A, int lda,
    const float* __restrict__ B, int ldb,
    float* __restrict__ Cpart, int ldc,
    int M, int N, int Kchunk)
{
    __shared__ float As[16][64 + 4];
    __shared__ float Bs[16][64 + 4];
    const int tid = threadIdx.x;
    const int m0 = blockIdx.x * 64;
    const int n0 = blockIdx.y * 64;
    const int kb = blockIdx.z * Kchunk;
    const int tx = tid & 15;
    const int ty = tid >> 4;
    const int lr = tid >> 4;
    const int lc = tid & 15;
    float acc[4][4] = {};

    for (int k0 = kb; k0 < kb + Kchunk; k0 += 16) {
        const int k = k0 + lc;
#pragma unroll
        for (int i = 0; i < 4; ++i) {
            int m = m0 + lr + i * 16;
            As[lc][lr + i * 16] = (m < M) ? A[(size_t)m * lda + k] : 0.f;
        }
#pragma unroll
        for (int i = 0; i < 4; ++i) {
            int n = n0 + lr + i * 16;
            Bs[lc][lr + i * 16] = (n < N) ? B[(size_t)n * ldb + k] : 0.f;
        }
        __syncthreads();
#pragma unroll
        for (int kk = 0; kk < 16; ++kk) {
            float a[4], b[4];
#pragma unroll
            for (int i = 0; i < 4; ++i) a[i] = As[kk][ty * 4 + i];
#pragma unroll
            for (int j = 0; j < 4; ++j) b[j] = Bs[kk][tx * 4 + j];
#pragma unroll
            for (int i = 0; i < 4; ++i)
#pragma unroll
                for (int j = 0; j < 4; ++j)
                    acc[i][j] = fmaf(a[i], b[j], acc[i][j]);
        }
        __syncthreads();
    }

    float* Cs = Cpart + (size_t)blockIdx.z * M * ldc;
#pragma unroll
    for (int i = 0; i < 4; ++i) {
        int m = m0 + ty * 4 + i;
        if (m >= M) continue;
#pragma unroll
        for (int j = 0; j < 4; ++j) {
            int n = n0 + tx * 4 + j;
            if (n >= N) continue;
            Cs[(size_t)m * ldc + n] = acc[i][j];
        }
    }
}

__global__ __launch_bounds__(256) void splitk_reduce(
    const float* __restrict__ Ppart, float* __restrict__ out, int n)
{
    int i = blockIdx.x * 256 + threadIdx.x;
    if (i >= n) return;
    float s = 0.f;
#pragma unroll
    for (int z = 0; z < SPLITK; ++z) s += Ppart[(size_t)z * n + i];
    out[i] = s;
}

// ---------------- depthwise causal conv1d (width 4) + SiLU ----------------
__global__ __launch_bounds__(256) void conv_silu_kernel(
    const float* __restrict__ xz,
    const float* __restrict__ conv_w,
    const float* __restrict__ conv_b,
    float* __restrict__ u)
{
    int idx = blockIdx.x * blockDim.x + threadIdx.x;
    if (idx >= LSEQ * DINNER) return;
    int d = idx % DINNER;
    int t = idx / DINNER;
    float w[4];
#pragma unroll
    for (int j = 0; j < 4; ++j) w[j] = conv_w[d * 4 + j];
    float acc = conv_b[d];
#pragma unroll
    for (int j = 0; j < 4; ++j) {
        int s = t - 3 + j;
        if (s >= 0) acc = fmaf(xz[(size_t)s * (2 * DINNER) + d], w[j], acc);
    }
    float sig = 1.f / (1.f + __expf(-acc));
    u[idx] = acc * sig;
}

// ================= chunked faithful scan =================
__global__ __launch_bounds__(256) void scan_chunkprod(
    const float* __restrict__ dtm,
    const float* __restrict__ A_log,
    float* __restrict__ P)
{
    __shared__ float sdtT[16][LDST];
    const int tid = threadIdx.x;
    const int d0 = blockIdx.x * 16;
    const int t0 = blockIdx.y * CHUNK;
    const int r = tid >> 4, c = tid & 15;
#pragma unroll
    for (int i = 0; i < 4; ++i) {
        int t = r + i * 16;
        sdtT[c][t] = dtm[(size_t)(t0 + t) * DINNER + d0 + c];
    }
    __syncthreads();
    const int n = tid & 15, dl = tid >> 4;
    const float Acoef = -expf(A_log[(d0 + dl) * DSTATE + n]);
    float s = 0.f;
#pragma unroll
    for (int tb = 0; tb < 16; ++tb) {
        f32x4 q = *(const f32x4*)&sdtT[dl][tb * 4];
        s += q[0] + q[1] + q[2] + q[3];
    }
    P[(size_t)blockIdx.y * NDN + d0 * DSTATE + tid] = __expf(Acoef * s);
}

template<int PROD>
__global__ __launch_bounds__(256) void scan_exclusive(float* __restrict__ buf)
{
    const int dn = blockIdx.x * 256 + threadIdx.x;
    float run = PROD ? 1.f : 0.f;
#pragma unroll
    for (int cidx = 0; cidx < NCHUNK; ++cidx) {
        float v = buf[(size_t)cidx * NDN + dn];
        buf[(size_t)cidx * NDN + dn] = run;
        run = PROD ? run * v : run + v;
    }
}

// Phase 3a: prefix-sum-exp form — serial chain is two float adds; exp/rcp independent.
__global__ __launch_bounds__(256) void scan_chunksum(
    const float* __restrict__ dtm,
    const float* __restrict__ u,
    const float* __restrict__ xdbl,
    const float* __restrict__ A_log,
    const float* __restrict__ Ppre,
    float* __restrict__ S)
{
    __shared__ float sdtT[16][LDST], sduT[16][LDST], sBT[16][LDST];
    const int tid = threadIdx.x;
    const int d0 = blockIdx.x * 16;
    const int t0 = blockIdx.y * CHUNK;
    const int r = tid >> 4, c = tid & 15;
#pragma unroll
    for (int i = 0; i < 4; ++i) {
        int t = r + i * 16;
        size_t row = (size_t)(t0 + t);
        float dtv = dtm[row * DINNER + d0 + c];
        sdtT[c][t] = dtv;
        sduT[c][t] = dtv * u[row * DINNER + d0 + c];
        sBT[c][t]  = xdbl[row * XDBL_W + DTRANK + c];
    }
    __syncthreads();
    const int n = tid & 15, dl = tid >> 4;
    const float Acoef = -expf(A_log[(d0 + dl) * DSTATE + n]);
    const float Pp = Ppre[(size_t)blockIdx.y * NDN + d0 * DSTATE + tid];
    float s = 0.f, acc = 0.f;
#pragma unroll
    for (int tb = 0; tb < 16; ++tb) {
        f32x4 dq  = *(const f32x4*)&sdtT[dl][tb * 4];
        f32x4 duq = *(const f32x4*)&sduT[dl][tb * 4];
        f32x4 bq  = *(const f32x4*)&sBT[n][tb * 4];
#pragma unroll
        for (int j = 0; j < 4; ++j) {
            s += dq[j];                                   // only loop-carried chain (+acc)
            float p = Pp * __expf(Acoef * s);
            acc += __fdividef(duq[j] * bq[j], fmaxf(p, FEPS));
        }
    }
    S[(size_t)blockIdx.y * NDN + d0 * DSTATE + tid] = acc;
}

// Phase 3c: 4-n-per-lane + prefix-sum-exp; quad-DPP reduction.
__global__ __launch_bounds__(256) void scan_final(
    const float* __restrict__ dtm,
    const float* __restrict__ u,
    const float* __restrict__ xdbl,
    const float* __restrict__ A_log,
    const float* __restrict__ Ppre,
    const float* __restrict__ Gpre,
    float* __restrict__ xz)           // part written to cols 0..1535
{
    __shared__ float sdtT[64][LDST], sduT[64][LDST];
    __shared__ float sBT[16][LDST], sCT[16][LDST];
    const int tid = threadIdx.x;
    const int d0 = blockIdx.x * 64;
    const int t0 = blockIdx.y * CHUNK;

    // stage dt, du=dt*u (64 d x 64 t), coalesced global reads
#pragma unroll
    for (int i = 0; i < 16; ++i) {
        int idx = i * 256 + tid;
        int dl = idx & 63, t = idx >> 6;
        size_t row = (size_t)(t0 + t);
        float dtv = dtm[row * DINNER + d0 + dl];
        sdtT[dl][t] = dtv;
        sduT[dl][t] = dtv * u[row * DINNER + d0 + dl];
    }
    // stage B,C (16 n x 64 t)
#pragma unroll
    for (int i = 0; i < 4; ++i) {
        int idx = i * 256 + tid;
        int n = idx & 15, t = idx >> 4;
        size_t row = (size_t)(t0 + t);
        sBT[n][t] = xdbl[row * XDBL_W + DTRANK + n];
        sCT[n][t] = xdbl[row * XDBL_W + DTRANK + DSTATE + n];
    }
    __syncthreads();

    const int lane = tid & 63, wid = tid >> 6;
    const int dloc = wid * 16 + (lane >> 2);   // 0..63
    const int d = d0 + dloc;
    const int nq = lane & 3;                   // owns n = nq*4 .. nq*4+3

    f32x4 Ar = *(const f32x4*)&A_log[d * DSTATE + nq * 4];
    float Ac[4] = {-expf(Ar[0]), -expf(Ar[1]), -expf(Ar[2]), -expf(Ar[3])};
    size_t pgbase = (size_t)blockIdx.y * NDN + (size_t)d * DSTATE + nq * 4;
    f32x4 Pp = *(const f32x4*)&Ppre[pgbase];
    f32x4 g = *(const f32x4*)&Gpre[pgbase];
    float s = 0.f;

#pragma unroll
    for (int tb = 0; tb < 16; ++tb) {
        f32x4 dq  = *(const f32x4*)&sdtT[dloc][tb * 4];
        f32x4 duq = *(const f32x4*)&sduT[dloc][tb * 4];
        f32x4 b0 = *(const f32x4*)&sBT[nq * 4 + 0][tb * 4];
        f32x4 b1 = *(const f32x4*)&sBT[nq * 4 + 1][tb * 4];
        f32x4 b2 = *(const f32x4*)&sBT[nq * 4 + 2][tb * 4];
        f32x4 b3 = *(const f32x4*)&sBT[nq * 4 + 3][tb * 4];
        f32x4 c0 = *(const f32x4*)&sCT[nq * 4 + 0][tb * 4];
        f32x4 c1 = *(const f32x4*)&sCT[nq * 4 + 1][tb * 4];
        f32x4 c2 = *(const f32x4*)&sCT[nq * 4 + 2][tb * 4];
        f32x4 c3 = *(const f32x4*)&sCT[nq * 4 + 3][tb * 4];
#pragma unroll
        for (int j = 0; j < 4; ++j) {
            float duv = duq[j];
            s += dq[j];                      // loop-carried chain (add only)
            // independent exps: p_n = Ppre_n * exp(Ac_n * s)
            float p0 = Pp[0] * __expf(Ac[0] * s);
            float p1 = Pp[1] * __expf(Ac[1] * s);
            float p2 = Pp[2] * __expf(Ac[2] * s);
            float p3 = Pp[3] * __expf(Ac[3] * s);
            g[0] += __fdividef(duv * b0[j], fmaxf(p0, FEPS));
            g[1] += __fdividef(duv * b1[j], fmaxf(p1, FEPS));
            g[2] += __fdividef(duv * b2[j], fmaxf(p2, FEPS));
            g[3] += __fdividef(duv * b3[j], fmaxf(p3, FEPS));
            float part = (g[0] * p0) * c0[j];
            part = fmaf(g[1] * p1, c1[j], part);
            part = fmaf(g[2] * p2, c2[j], part);
            part = fmaf(g[3] * p3, c3[j], part);
            part += qperm<0xB1>(part);   // xor1 within quad
            part += qperm<0x4E>(part);   // xor2 within quad
            if (nq == 0)
                xz[(size_t)(t0 + tb * 4 + j) * (2 * DINNER) + d] = part;
        }
    }
}

// gate/output epilogue: y = (part + D*u) * silu(z) -> bf16 hi/lo planes
__global__ __launch_bounds__(256) void gate_kernel(
    const float* __restrict__ xz,
    const float* __restrict__ u,
    const float* __restrict__ Dvec,
    u16* __restrict__ yhi, u16* __restrict__ ylo)
{
    int i4 = (blockIdx.x * 256 + threadIdx.x) * 4;
    if (i4 >= LSEQ * DINNER) return;
    int t = i4 / DINNER;
    int d = i4 - t * DINNER;
    size_t base = (size_t)t * (2 * DINNER) + d;
    float4 part = *(const float4*)&xz[base];
    float4 zv   = *(const float4*)&xz[base + DINNER];
    float4 uv   = *(const float4*)&u[i4];
    float4 Dd   = *(const float4*)&Dvec[d];
    float pa[4] = {part.x, part.y, part.z, part.w};
    float za[4] = {zv.x, zv.y, zv.z, zv.w};
    float ua[4] = {uv.x, uv.y, uv.z, uv.w};
    float Da[4] = {Dd.x, Dd.y, Dd.z, Dd.w};
    u16 ha[4], la[4];
#pragma unroll
    for (int j = 0; j < 4; ++j) {
        float sig = 1.f / (1.f + __expf(-za[j]));
        float yv = (pa[j] + Da[j] * ua[j]) * (za[j] * sig);
        ha[j] = f2bf_rn(yv);
        la[j] = f2bf_rn(yv - bf2f(ha[j]));
    }
    *(ushort4*)&yhi[i4] = make_ushort4(ha[0], ha[1], ha[2], ha[3]);
    *(ushort4*)&ylo[i4] = make_ushort4(la[0], la[1], la[2], la[3]);
}

// ---------------- launch ----------------
extern "C" void kernel_launch(void* const* d_in, const int* in_sizes, int n_in,
                              void* d_out, int out_size, void* d_ws, size_t ws_size,
                              hipStream_t stream) {
    const float* x          = (const float*)d_in[0];
    const float* in_proj_w  = (const float*)d_in[1];
    const float* conv_w     = (const float*)d_in[2];
    const float* conv_b     = (const float*)d_in[3];
    const float* x_proj_w   = (const float*)d_in[4];
    const float* dt_proj_w  = (const float*)d_in[5];
    const float* dt_proj_b  = (const float*)d_in[6];
    const float* A_log      = (const float*)d_in[7];
    const float* Dvec       = (const float*)d_in[8];
    const float* out_proj_w = (const float*)d_in[9];
    float* out = (float*)d_out;

    char* w = (char*)d_ws;
    auto alloc = [&](size_t bytes) { char* p = w; w += (bytes + 255) & ~(size_t)255; return p; };

    float* xz    = (float*)alloc((size_t)LSEQ * 2 * DINNER * 4);
    float* u     = (float*)alloc((size_t)LSEQ * DINNER * 4);
    float* xdbl  = (float*)alloc((size_t)LSEQ * XDBL_W * 4);
    float* dtb   = (float*)alloc((size_t)LSEQ * DINNER * 4);
    float* P     = (float*)alloc((size_t)NCHUNK * NDN * 4);
    float* S     = (float*)alloc((size_t)NCHUNK * NDN * 4);
    float* Ppart = (float*)alloc((size_t)SPLITK * LSEQ * XDBL_W * 4);
    u16* xhi  = (u16*)alloc((size_t)LSEQ * DMODEL * 2);
    u16* xlo  = (u16*)alloc((size_t)LSEQ * DMODEL * 2);
    u16* wihi = (u16*)alloc((size_t)2 * DINNER * DMODEL * 2);
    u16* wilo = (u16*)alloc((size_t)2 * DINNER * DMODEL * 2);
    u16* owhi = (u16*)alloc((size_t)DMODEL * DINNER * 2);
    u16* owlo = (u16*)alloc((size_t)DMODEL * DINNER * 2);
    u16* yhi  = (u16*)alloc((size_t)LSEQ * DINNER * 2);
    u16* ylo  = (u16*)alloc((size_t)LSEQ * DINNER * 2);
    float* opart = u;   // out_proj partials alias u..S (dead after gate_kernel)

    dim3 blk(256);

    // 0. conversions to bf16 hi/lo
    cvt_split<<<(LSEQ * DMODEL) / 1024, blk, 0, stream>>>(x, xhi, xlo, LSEQ * DMODEL);
    cvt_split<<<(2 * DINNER * DMODEL) / 1024, blk, 0, stream>>>(in_proj_w, wihi, wilo, 2 * DINNER * DMODEL);
    cvt_split<<<(DMODEL * DINNER) / 1024, blk, 0, stream>>>(out_proj_w, owhi, owlo, DMODEL * DINNER);

    // 1. xz = x @ in_proj_w.T   (M=2048, N=3072, K=768), dbuf MFMA
    mfma_gemm_tn<<<dim3(LSEQ / 128, (2 * DINNER) / 128, 1), blk, 0, stream>>>(
        xhi, xlo, wihi, wilo, xz, 2 * DINNER, DMODEL, DMODEL);

    // 2. u = silu(depthwise_conv(xh) + b)
    conv_silu_kernel<<<(LSEQ * DINNER + 255) / 256, blk, 0, stream>>>(xz, conv_w, conv_b, u);

    // 3. x_dbl = u @ x_proj_w.T (split-K fp32, deterministic reduce)
    gemm_tn_splitk<<<dim3(LSEQ / 64, (XDBL_W + 63) / 64, SPLITK), blk, 0, stream>>>(
        u, DINNER, x_proj_w, DINNER, Ppart, XDBL_W, LSEQ, XDBL_W, DINNER / SPLITK);
    splitk_reduce<<<(LSEQ * XDBL_W + 255) / 256, blk, 0, stream>>>(Ppart, xdbl, LSEQ * XDBL_W);

    // 4. dt = softplus(x_dbl[:, :48] @ dt_proj_w.T + dt_proj_b)
    gemm_tn<1><<<dim3(LSEQ / 64, DINNER / 64), blk, 0, stream>>>(
        xdbl, XDBL_W, dt_proj_w, DTRANK, dtb, DINNER, LSEQ, DINNER, DTRANK, dt_proj_b);

    // 5. chunked faithful selective scan; part -> xz cols 0..1535
    scan_chunkprod<<<dim3(DINNER / 16, NCHUNK), blk, 0, stream>>>(dtb, A_log, P);
    scan_exclusive<1><<<NDN / 256, blk, 0, stream>>>(P);
    scan_chunksum<<<dim3(DINNER / 16, NCHUNK), blk, 0, stream>>>(dtb, u, xdbl, A_log, P, S);
    scan_exclusive<0><<<NDN / 256, blk, 0, stream>>>(S);
    scan_final<<<dim3(DINNER / 64, NCHUNK), blk, 0, stream>>>(
        dtb, u, xdbl, A_log, P, S, xz);

    // 5b. gate epilogue
    gate_kernel<<<(LSEQ * DINNER) / 1024, blk, 0, stream>>>(xz, u, Dvec, yhi, ylo);

    // 6. out = y @ out_proj_w.T (split-K=4 + reduce)
    mfma_gemm_tn<<<dim3(LSEQ / 128, DMODEL / 128, OSPLIT), blk, 0, stream>>>(
        yhi, ylo, owhi, owlo, opart, DMODEL, DINNER, DINNER / OSPLIT);
    reduce4<<<(LSEQ * DMODEL) / 1024, blk, 0, stream>>>(opart, out, LSEQ * DMODEL);
}

// Round 11
// 234.118 us; speedup vs baseline: 9.6354x; 1.0083x over previous
//
#include <hip/hip_runtime.h>
#include <hip/hip_bf16.h>

// ---------------- sizes ----------------
#define LSEQ 2048
#define DMODEL 768
#define DINNER 1536
#define DSTATE 16
#define DTRANK 48
#define XDBL_W (DTRANK + 2*DSTATE)   // 80
#define CHUNK 64
#define NCHUNK (LSEQ / CHUNK)        // 32
#define NDN (DINNER * DSTATE)        // 24576
#define FEPS 1.1920928955078125e-07f
#define SPLITK 8
#define OSPLIT 4                     // split-K factor for out_proj
#define LDST 68                      // padded LDS row stride (floats), 64-t kernels
#define LDST2 36                     // padded LDS row stride (floats), 32-t halves

typedef short bf16x8 __attribute__((ext_vector_type(8)));
typedef float f32x4 __attribute__((ext_vector_type(4)));
typedef unsigned short u16;

__device__ __forceinline__ u16 f2bf_rn(float f) {
    unsigned u = __float_as_uint(f);
    unsigned r = u + 0x7FFFu + ((u >> 16) & 1u);
    return (u16)(r >> 16);
}
__device__ __forceinline__ float bf2f(u16 h) {
    return __uint_as_float(((unsigned)h) << 16);
}

// quad_perm DPP lane exchange (full-rate VALU, no LDS pipe).
template<int CTRL>
__device__ __forceinline__ float qperm(float x) {
    return __int_as_float(__builtin_amdgcn_update_dpp(
        0, __float_as_int(x), CTRL, 0xF, 0xF, true));
}

// ---------------- fp32 -> bf16 hi/lo split conversion ----------------
__global__ __launch_bounds__(256) void cvt_split(
    const float* __restrict__ src, u16* __restrict__ hi, u16* __restrict__ lo, int n)
{
    int i = (blockIdx.x * 256 + threadIdx.x) * 4;
    if (i >= n) return;
    float4 v = *(const float4*)&src[i];
    u16 h0 = f2bf_rn(v.x), h1 = f2bf_rn(v.y), h2 = f2bf_rn(v.z), h3 = f2bf_rn(v.w);
    u16 l0 = f2bf_rn(v.x - bf2f(h0));
    u16 l1 = f2bf_rn(v.y - bf2f(h1));
    u16 l2 = f2bf_rn(v.z - bf2f(h2));
    u16 l3 = f2bf_rn(v.w - bf2f(h3));
    *(ushort4*)&hi[i] = make_ushort4(h0, h1, h2, h3);
    *(ushort4*)&lo[i] = make_ushort4(l0, l1, l2, l3);
}

// ---------------- split-bf16 MFMA GEMM, double-buffered ----------------
__global__ __launch_bounds__(256) void mfma_gemm_tn(
    const u16* __restrict__ Ahi, const u16* __restrict__ Alo,
    const u16* __restrict__ Bhi, const u16* __restrict__ Blo,
    float* __restrict__ C, int ldc, int ldk, int Klen)
{
    __shared__ u16 lds[2 * 4 * 4096];   // 2 buffers x 4 planes x 8KB = 64KB
    const int tid = threadIdx.x;
    const int wid = tid >> 6;
    const int lane = tid & 63;
    const int m0 = blockIdx.x * 128;
    const int n0 = blockIdx.y * 128;
    const int Koff = blockIdx.z * Klen;

    const int st_subrow = lane >> 2;
    const int st_cphys = lane & 3;
    const u16* myplane = (wid == 0) ? Ahi : (wid == 1) ? Alo : (wid == 2) ? Bhi : Blo;
    const int rowbase = (wid < 2) ? m0 : n0;

    f32x4 acc[4][4] = {};
    const int wm = (wid >> 1) * 64;
    const int wn = (wid & 1) * 64;
    const int fr = lane & 15;
    const int fc = lane >> 4;
    const int nsteps = Klen / 32;

    auto stage = [&](int buf, int k0) {
#pragma unroll
        for (int j = 0; j < 8; ++j) {
            int row = j * 16 + st_subrow;
            int clog = st_cphys ^ ((row >> 1) & 3);
            const u16* g = myplane + (size_t)(rowbase + row) * ldk + k0 + clog * 8;
            u16* l = &lds[buf * 16384 + wid * 4096 + j * 512];
            __builtin_amdgcn_global_load_lds(
                (const __attribute__((address_space(1))) unsigned int*)g,
                (__attribute__((address_space(3))) unsigned int*)l, 16, 0, 0);
        }
    };

    stage(0, Koff);
    int cur = 0;
    for (int t = 0; t < nsteps; ++t) {
        __syncthreads();
        if (t + 1 < nsteps) stage(cur ^ 1, Koff + (t + 1) * 32);

        bf16x8 ah[4], al[4], bh[4], bl[4];
        const bf16x8* L = (const bf16x8*)&lds[cur * 16384];
#pragma unroll
        for (int mi = 0; mi < 4; ++mi) {
            int r = wm + mi * 16 + fr;
            int idx = r * 4 + (fc ^ ((r >> 1) & 3));
            ah[mi] = L[idx];
            al[mi] = L[512 + idx];
        }
#pragma unroll
        for (int nj = 0; nj < 4; ++nj) {
            int r = wn + nj * 16 + fr;
            int idx = r * 4 + (fc ^ ((r >> 1) & 3));
            bh[nj] = L[1024 + idx];
            bl[nj] = L[1536 + idx];
        }
#pragma unroll
        for (int mi = 0; mi < 4; ++mi)
#pragma unroll
            for (int nj = 0; nj < 4; ++nj) {
                acc[mi][nj] = __builtin_amdgcn_mfma_f32_16x16x32_bf16(ah[mi], bh[nj], acc[mi][nj], 0, 0, 0);
                acc[mi][nj] = __builtin_amdgcn_mfma_f32_16x16x32_bf16(ah[mi], bl[nj], acc[mi][nj], 0, 0, 0);
                acc[mi][nj] = __builtin_amdgcn_mfma_f32_16x16x32_bf16(al[mi], bh[nj], acc[mi][nj], 0, 0, 0);
            }
        cur ^= 1;
    }

    float* Cz = C + (size_t)blockIdx.z * LSEQ * ldc;
#pragma unroll
    for (int mi = 0; mi < 4; ++mi) {
        int row_b = m0 + wm + mi * 16 + (lane >> 4) * 4;
#pragma unroll
        for (int nj = 0; nj < 4; ++nj) {
            int col = n0 + wn + nj * 16 + (lane & 15);
#pragma unroll
            for (int r = 0; r < 4; ++r)
                Cz[(size_t)(row_b + r) * ldc + col] = acc[mi][nj][r];
        }
    }
}

// deterministic 4-way partial reduce for out_proj
__global__ __launch_bounds__(256) void reduce4(
    const float* __restrict__ Ppart, float* __restrict__ out, int n)
{
    int i = (blockIdx.x * 256 + threadIdx.x) * 4;
    if (i >= n) return;
    float4 a0 = *(const float4*)&Ppart[i];
    float4 a1 = *(const float4*)&Ppart[(size_t)n + i];
    float4 a2 = *(const float4*)&Ppart[(size_t)2 * n + i];
    float4 a3 = *(const float4*)&Ppart[(size_t)3 * n + i];
    float4 r;
    r.x = ((a0.x + a1.x) + a2.x) + a3.x;
    r.y = ((a0.y + a1.y) + a2.y) + a3.y;
    r.z = ((a0.z + a1.z) + a2.z) + a3.z;
    r.w = ((a0.w + a1.w) + a2.w) + a3.w;
    *(float4*)&out[i] = r;
}

// ---------------- fp32 tiled GEMM (dt_proj) ----------------
template<int EPI>
__global__ __launch_bounds__(256) void gemm_tn(
    const float* __restrict__ A, int lda,
    const float* __restrict__ B, int ldb,
    float* __restrict__ C, int ldc,
    int M, int N, int K,
    const float* __restrict__ bias)
{
    __shared__ float As[16][64 + 4];
    __shared__ float Bs[16][64 + 4];
    const int tid = threadIdx.x;
    const int m0 = blockIdx.x * 64;
    const int n0 = blockIdx.y * 64;
    const int tx = tid & 15;
    const int ty = tid >> 4;
    const int lr = tid >> 4;
    const int lc = tid & 15;
    float acc[4][4] = {};

    for (int k0 = 0; k0 < K; k0 += 16) {
        const int k = k0 + lc;
#pragma unroll
        for (int i = 0; i < 4; ++i) {
            int m = m0 + lr + i * 16;
            As[lc][lr + i * 16] = (m < M) ? A[(size_t)m * lda + k] : 0.f;
        }
#pragma unroll
        for (int i = 0; i < 4; ++i) {
            int n = n0 + lr + i * 16;
            Bs[lc][lr + i * 16] = (n < N) ? B[(size_t)n * ldb + k] : 0.f;
        }
        __syncthreads();
#pragma unroll
        for (int kk = 0; kk < 16; ++kk) {
            float a[4], b[4];
#pragma unroll
            for (int i = 0; i < 4; ++i) a[i] = As[kk][ty * 4 + i];
#pragma unroll
            for (int j = 0; j < 4; ++j) b[j] = Bs[kk][tx * 4 + j];
#pragma unroll
            for (int i = 0; i < 4; ++i)
#pragma unroll
                for (int j = 0; j < 4; ++j)
                    acc[i][j] = fmaf(a[i], b[j], acc[i][j]);
        }
        __syncthreads();
    }

#pragma unroll
    for (int i = 0; i < 4; ++i) {
        int m = m0 + ty * 4 + i;
        if (m >= M) continue;
#pragma unroll
        for (int j = 0; j < 4; ++j) {
            int n = n0 + tx * 4 + j;
            if (n >= N) continue;
            float v = acc[i][j];
            if (EPI == 1) {
                v += bias[n];
                v = fmaxf(v, 0.f) + log1pf(expf(-fabsf(v)));
            }
            C[(size_t)m * ldc + n] = v;
        }
    }
}

// ---------------- fp32 split-K GEMM for x_proj ----------------
__global__ __launch_bounds__(256) void gemm_tn_splitk(
    const float* __restrict__ A, int lda,
    const float* __restrict__ B, int ldb,
    float* __restrict__ Cpart, int ldc,
    int M, int N, int Kchunk)
{
    __shared__ float As[16][64 + 4];
    __shared__ float Bs[16][64 + 4];
    const int tid = threadIdx.x;
    const int m0 = blockIdx.x * 64;
    const int n0 = blockIdx.y * 64;
    const int kb = blockIdx.z * Kchunk;
    const int tx = tid & 15;
    const int ty = tid >> 4;
    const int lr = tid >> 4;
    const int lc = tid & 15;
    float acc[4][4] = {};

    for (int k0 = kb; k0 < kb + Kchunk; k0 += 16) {
        const int k = k0 + lc;
#pragma unroll
        for (int i = 0; i < 4; ++i) {
            int m = m0 + lr + i * 16;
            As[lc][lr + i * 16] = (m < M) ? A[(size_t)m * lda + k] : 0.f;
        }
#pragma unroll
        for (int i = 0; i < 4; ++i) {
            int n = n0 + lr + i * 16;
            Bs[lc][lr + i * 16] = (n < N) ? B[(size_t)n * ldb + k] : 0.f;
        }
        __syncthreads();
#pragma unroll
        for (int kk = 0; kk < 16; ++kk) {
            float a[4], b[4];
#pragma unroll
            for (int i = 0; i < 4; ++i) a[i] = As[kk][ty * 4 + i];
#pragma unroll
            for (int j = 0; j < 4; ++j) b[j] = Bs[kk][tx * 4 + j];
#pragma unroll
            for (int i = 0; i < 4; ++i)
#pragma unroll
                for (int j = 0; j < 4; ++j)
                    acc[i][j] = fmaf(a[i], b[j], acc[i][j]);
        }
        __syncthreads();
    }

    float* Cs = Cpart + (size_t)blockIdx.z * M * ldc;
#pragma unroll
    for (int i = 0; i < 4; ++i) {
        int m = m0 + ty * 4 + i;
        if (m >= M) continue;
#pragma unroll
        for (int j = 0; j < 4; ++j) {
            int n = n0 + tx * 4 + j;
            if (n >= N) continue;
            Cs[(size_t)m * ldc + n] = acc[i][j];
        }
    }
}

__global__ __launch_bounds__(256) void splitk_reduce(
    const float* __restrict__ Ppart, float* __restrict__ out, int n)
{
    int i = blockIdx.x * 256 + threadIdx.x;
    if (i >= n) return;
    float s = 0.f;
#pragma unroll
    for (int z = 0; z < SPLITK; ++z) s += Ppart[(size_t)z * n + i];
    out[i] = s;
}

// ---------------- depthwise causal conv1d (width 4) + SiLU ----------------
__global__ __launch_bounds__(256) void conv_silu_kernel(
    const float* __restrict__ xz,
    const float* __restrict__ conv_w,
    const float* __restrict__ conv_b,
    float* __restrict__ u)
{
    int idx = blockIdx.x * blockDim.x + threadIdx.x;
    if (idx >= LSEQ * DINNER) return;
    int d = idx % DINNER;
    int t = idx / DINNER;
    float w[4];
#pragma unroll
    for (int j = 0; j < 4; ++j) w[j] = conv_w[d * 4 + j];
    float acc = conv_b[d];
#pragma unroll
    for (int j = 0; j < 4; ++j) {
        int s = t - 3 + j;
        if (s >= 0) acc = fmaf(xz[(size_t)s * (2 * DINNER) + d], w[j], acc);
    }
    float sig = 1.f / (1.f + __expf(-acc));
    u[idx] = acc * sig;
}

// ================= chunked faithful scan =================
__global__ __launch_bounds__(256) void scan_chunkprod(
    const float* __restrict__ dtm,
    const float* __restrict__ A_log,
    float* __restrict__ P)
{
    __shared__ float sdtT[16][LDST];
    const int tid = threadIdx.x;
    const int d0 = blockIdx.x * 16;
    const int t0 = blockIdx.y * CHUNK;
    const int r = tid >> 4, c = tid & 15;
#pragma unroll
    for (int i = 0; i < 4; ++i) {
        int t = r + i * 16;
        sdtT[c][t] = dtm[(size_t)(t0 + t) * DINNER + d0 + c];
    }
    __syncthreads();
    const int n = tid & 15, dl = tid >> 4;
    const float Acoef = -expf(A_log[(d0 + dl) * DSTATE + n]);
    float s = 0.f;
#pragma unroll
    for (int tb = 0; tb < 16; ++tb) {
        f32x4 q = *(const f32x4*)&sdtT[dl][tb * 4];
        s += q[0] + q[1] + q[2] + q[3];
    }
    P[(size_t)blockIdx.y * NDN + d0 * DSTATE + tid] = __expf(Acoef * s);
}

template<int PROD>
__global__ __launch_bounds__(256) void scan_exclusive(float* __restrict__ buf)
{
    const int dn = blockIdx.x * 256 + threadIdx.x;
    float run = PROD ? 1.f : 0.f;
#pragma unroll
    for (int cidx = 0; cidx < NCHUNK; ++cidx) {
        float v = buf[(size_t)cidx * NDN + dn];
        buf[(size_t)cidx * NDN + dn] = run;
        run = PROD ? run * v : run + v;
    }
}

// Phase 3a: prefix-sum-exp form — serial chain is two float adds; exp/rcp independent.
__global__ __launch_bounds__(256) void scan_chunksum(
    const float* __restrict__ dtm,
    const float* __restrict__ u,
    const float* __restrict__ xdbl,
    const float* __restrict__ A_log,
    const float* __restrict__ Ppre,
    float* __restrict__ S)
{
    __shared__ float sdtT[16][LDST], sduT[16][LDST], sBT[16][LDST];
    const int tid = threadIdx.x;
    const int d0 = blockIdx.x * 16;
    const int t0 = blockIdx.y * CHUNK;
    const int r = tid >> 4, c = tid & 15;
#pragma unroll
    for (int i = 0; i < 4; ++i) {
        int t = r + i * 16;
        size_t row = (size_t)(t0 + t);
        float dtv = dtm[row * DINNER + d0 + c];
        sdtT[c][t] = dtv;
        sduT[c][t] = dtv * u[row * DINNER + d0 + c];
        sBT[c][t]  = xdbl[row * XDBL_W + DTRANK + c];
    }
    __syncthreads();
    const int n = tid & 15, dl = tid >> 4;
    const float Acoef = -expf(A_log[(d0 + dl) * DSTATE + n]);
    const float Pp = Ppre[(size_t)blockIdx.y * NDN + d0 * DSTATE + tid];
    float s = 0.f, acc = 0.f;
#pragma unroll
    for (int tb = 0; tb < 16; ++tb) {
        f32x4 dq  = *(const f32x4*)&sdtT[dl][tb * 4];
        f32x4 duq = *(const f32x4*)&sduT[dl][tb * 4];
        f32x4 bq  = *(const f32x4*)&sBT[n][tb * 4];
#pragma unroll
        for (int j = 0; j < 4; ++j) {
            s += dq[j];                                   // only loop-carried chain (+acc)
            float p = Pp * __expf(Acoef * s);
            acc += __fdividef(duq[j] * bq[j], fmaxf(p, FEPS));
        }
    }
    S[(size_t)blockIdx.y * NDN + d0 * DSTATE + tid] = acc;
}

// Phase 3c: 4-n-per-lane + prefix-sum-exp + quad-DPP reduction.
// Two-half t-staging (32 cols each) halves LDS: 23040 B -> 7 blocks/CU.
__global__ __launch_bounds__(256) void scan_final(
    const float* __restrict__ dtm,
    const float* __restrict__ u,
    const float* __restrict__ xdbl,
    const float* __restrict__ A_log,
    const float* __restrict__ Ppre,
    const float* __restrict__ Gpre,
    float* __restrict__ xz)           // part written to cols 0..1535
{
    __shared__ float sdtT[64][LDST2], sduT[64][LDST2];
    __shared__ float sBT[16][LDST2], sCT[16][LDST2];
    const int tid = threadIdx.x;
    const int d0 = blockIdx.x * 64;
    const int t0 = blockIdx.y * CHUNK;

    const int lane = tid & 63, wid = tid >> 6;
    const int dloc = wid * 16 + (lane >> 2);   // 0..63
    const int d = d0 + dloc;
    const int nq = lane & 3;                   // owns n = nq*4 .. nq*4+3

    f32x4 Ar = *(const f32x4*)&A_log[d * DSTATE + nq * 4];
    float Ac[4] = {-expf(Ar[0]), -expf(Ar[1]), -expf(Ar[2]), -expf(Ar[3])};
    size_t pgbase = (size_t)blockIdx.y * NDN + (size_t)d * DSTATE + nq * 4;
    f32x4 Pp = *(const f32x4*)&Ppre[pgbase];
    f32x4 g = *(const f32x4*)&Gpre[pgbase];
    float s = 0.f;

    for (int half = 0; half < 2; ++half) {
        // stage dt, du=dt*u (64 d x 32 t), coalesced
#pragma unroll
        for (int i = 0; i < 8; ++i) {
            int idx = i * 256 + tid;
            int dl = idx & 63, tl = idx >> 6;          // tl 0..31
            size_t row = (size_t)(t0 + half * 32 + tl);
            float dtv = dtm[row * DINNER + d0 + dl];
            sdtT[dl][tl] = dtv;
            sduT[dl][tl] = dtv * u[row * DINNER + d0 + dl];
        }
        // stage B,C (16 n x 32 t)
#pragma unroll
        for (int i = 0; i < 2; ++i) {
            int idx = i * 256 + tid;
            int n = idx & 15, tl = idx >> 4;
            size_t row = (size_t)(t0 + half * 32 + tl);
            sBT[n][tl] = xdbl[row * XDBL_W + DTRANK + n];
            sCT[n][tl] = xdbl[row * XDBL_W + DTRANK + DSTATE + n];
        }
        __syncthreads();

#pragma unroll
        for (int tb = 0; tb < 8; ++tb) {
            f32x4 dq  = *(const f32x4*)&sdtT[dloc][tb * 4];
            f32x4 duq = *(const f32x4*)&sduT[dloc][tb * 4];
            f32x4 b0 = *(const f32x4*)&sBT[nq * 4 + 0][tb * 4];
            f32x4 b1 = *(const f32x4*)&sBT[nq * 4 + 1][tb * 4];
            f32x4 b2 = *(const f32x4*)&sBT[nq * 4 + 2][tb * 4];
            f32x4 b3 = *(const f32x4*)&sBT[nq * 4 + 3][tb * 4];
            f32x4 c0 = *(const f32x4*)&sCT[nq * 4 + 0][tb * 4];
            f32x4 c1 = *(const f32x4*)&sCT[nq * 4 + 1][tb * 4];
            f32x4 c2 = *(const f32x4*)&sCT[nq * 4 + 2][tb * 4];
            f32x4 c3 = *(const f32x4*)&sCT[nq * 4 + 3][tb * 4];
#pragma unroll
            for (int j = 0; j < 4; ++j) {
                float duv = duq[j];
                s += dq[j];                      // loop-carried chain (add only)
                float p0 = Pp[0] * __expf(Ac[0] * s);
                float p1 = Pp[1] * __expf(Ac[1] * s);
                float p2 = Pp[2] * __expf(Ac[2] * s);
                float p3 = Pp[3] * __expf(Ac[3] * s);
                g[0] += __fdividef(duv * b0[j], fmaxf(p0, FEPS));
                g[1] += __fdividef(duv * b1[j], fmaxf(p1, FEPS));
                g[2] += __fdividef(duv * b2[j], fmaxf(p2, FEPS));
                g[3] += __fdividef(duv * b3[j], fmaxf(p3, FEPS));
                float part = (g[0] * p0) * c0[j];
                part = fmaf(g[1] * p1, c1[j], part);
                part = fmaf(g[2] * p2, c2[j], part);
                part = fmaf(g[3] * p3, c3[j], part);
                part += qperm<0xB1>(part);   // xor1 within quad
                part += qperm<0x4E>(part);   // xor2 within quad
                if (nq == 0)
                    xz[(size_t)(t0 + half * 32 + tb * 4 + j) * (2 * DINNER) + d] = part;
            }
        }
        __syncthreads();   // before next half overwrites the buffer
    }
}

// gate/output epilogue: y = (part + D*u) * silu(z) -> bf16 hi/lo planes
__global__ __launch_bounds__(256) void gate_kernel(
    const float* __restrict__ xz,
    const float* __restrict__ u,
    const float* __restrict__ Dvec,
    u16* __restrict__ yhi, u16* __restrict__ ylo)
{
    int i4 = (blockIdx.x * 256 + threadIdx.x) * 4;
    if (i4 >= LSEQ * DINNER) return;
    int t = i4 / DINNER;
    int d = i4 - t * DINNER;
    size_t base = (size_t)t * (2 * DINNER) + d;
    float4 part = *(const float4*)&xz[base];
    float4 zv   = *(const float4*)&xz[base + DINNER];
    float4 uv   = *(const float4*)&u[i4];
    float4 Dd   = *(const float4*)&Dvec[d];
    float pa[4] = {part.x, part.y, part.z, part.w};
    float za[4] = {zv.x, zv.y, zv.z, zv.w};
    float ua[4] = {uv.x, uv.y, uv.z, uv.w};
    float Da[4] = {Dd.x, Dd.y, Dd.z, Dd.w};
    u16 ha[4], la[4];
#pragma unroll
    for (int j = 0; j < 4; ++j) {
        float sig = 1.f / (1.f + __expf(-za[j]));
        float yv = (pa[j] + Da[j] * ua[j]) * (za[j] * sig);
        ha[j] = f2bf_rn(yv);
        la[j] = f2bf_rn(yv - bf2f(ha[j]));
    }
    *(ushort4*)&yhi[i4] = make_ushort4(ha[0], ha[1], ha[2], ha[3]);
    *(ushort4*)&ylo[i4] = make_ushort4(la[0], la[1], la[2], la[3]);
}

// ---------------- launch ----------------
extern "C" void kernel_launch(void* const* d_in, const int* in_sizes, int n_in,
                              void* d_out, int out_size, void* d_ws, size_t ws_size,
                              hipStream_t stream) {
    const float* x          = (const float*)d_in[0];
    const float* in_proj_w  = (const float*)d_in[1];
    const float* conv_w     = (const float*)d_in[2];
    const float* conv_b     = (const float*)d_in[3];
    const float* x_proj_w   = (const float*)d_in[4];
    const float* dt_proj_w  = (const float*)d_in[5];
    const float* dt_proj_b  = (const float*)d_in[6];
    const float* A_log      = (const float*)d_in[7];
    const float* Dvec       = (const float*)d_in[8];
    const float* out_proj_w = (const float*)d_in[9];
    float* out = (float*)d_out;

    char* w = (char*)d_ws;
    auto alloc = [&](size_t bytes) { char* p = w; w += (bytes + 255) & ~(size_t)255; return p; };

    float* xz    = (float*)alloc((size_t)LSEQ * 2 * DINNER * 4);
    float* u     = (float*)alloc((size_t)LSEQ * DINNER * 4);
    float* xdbl  = (float*)alloc((size_t)LSEQ * XDBL_W * 4);
    float* dtb   = (float*)alloc((size_t)LSEQ * DINNER * 4);
    float* P     = (float*)alloc((size_t)NCHUNK * NDN * 4);
    float* S     = (float*)alloc((size_t)NCHUNK * NDN * 4);
    float* Ppart = (float*)alloc((size_t)SPLITK * LSEQ * XDBL_W * 4);
    u16* xhi  = (u16*)alloc((size_t)LSEQ * DMODEL * 2);
    u16* xlo  = (u16*)alloc((size_t)LSEQ * DMODEL * 2);
    u16* wihi = (u16*)alloc((size_t)2 * DINNER * DMODEL * 2);
    u16* wilo = (u16*)alloc((size_t)2 * DINNER * DMODEL * 2);
    u16* owhi = (u16*)alloc((size_t)DMODEL * DINNER * 2);
    u16* owlo = (u16*)alloc((size_t)DMODEL * DINNER * 2);
    u16* yhi  = (u16*)alloc((size_t)LSEQ * DINNER * 2);
    u16* ylo  = (u16*)alloc((size_t)LSEQ * DINNER * 2);
    float* opart = u;   // out_proj partials alias u..S (dead after gate_kernel)

    dim3 blk(256);

    // 0. conversions to bf16 hi/lo
    cvt_split<<<(LSEQ * DMODEL) / 1024, blk, 0, stream>>>(x, xhi, xlo, LSEQ * DMODEL);
    cvt_split<<<(2 * DINNER * DMODEL) / 1024, blk, 0, stream>>>(in_proj_w, wihi, wilo, 2 * DINNER * DMODEL);
    cvt_split<<<(DMODEL * DINNER) / 1024, blk, 0, stream>>>(out_proj_w, owhi, owlo, DMODEL * DINNER);

    // 1. xz = x @ in_proj_w.T   (M=2048, N=3072, K=768), dbuf MFMA
    mfma_gemm_tn<<<dim3(LSEQ / 128, (2 * DINNER) / 128, 1), blk, 0, stream>>>(
        xhi, xlo, wihi, wilo, xz, 2 * DINNER, DMODEL, DMODEL);

    // 2. u = silu(depthwise_conv(xh) + b)
    conv_silu_kernel<<<(LSEQ * DINNER + 255) / 256, blk, 0, stream>>>(xz, conv_w, conv_b, u);

    // 3. x_dbl = u @ x_proj_w.T (split-K fp32, deterministic reduce)
    gemm_tn_splitk<<<dim3(LSEQ / 64, (XDBL_W + 63) / 64, SPLITK), blk, 0, stream>>>(
        u, DINNER, x_proj_w, DINNER, Ppart, XDBL_W, LSEQ, XDBL_W, DINNER / SPLITK);
    splitk_reduce<<<(LSEQ * XDBL_W + 255) / 256, blk, 0, stream>>>(Ppart, xdbl, LSEQ * XDBL_W);

    // 4. dt = softplus(x_dbl[:, :48] @ dt_proj_w.T + dt_proj_b)
    gemm_tn<1><<<dim3(LSEQ / 64, DINNER / 64), blk, 0, stream>>>(
        xdbl, XDBL_W, dt_proj_w, DTRANK, dtb, DINNER, LSEQ, DINNER, DTRANK, dt_proj_b);

    // 5. chunked faithful selective scan; part -> xz cols 0..1535
    scan_chunkprod<<<dim3(DINNER / 16, NCHUNK), blk, 0, stream>>>(dtb, A_log, P);
    scan_exclusive<1><<<NDN / 256, blk, 0, stream>>>(P);
    scan_chunksum<<<dim3(DINNER / 16, NCHUNK), blk, 0, stream>>>(dtb, u, xdbl, A_log, P, S);
    scan_exclusive<0><<<NDN / 256, blk, 0, stream>>>(S);
    scan_final<<<dim3(DINNER / 64, NCHUNK), blk, 0, stream>>>(
        dtb, u, xdbl, A_log, P, S, xz);

    // 5b. gate epilogue
    gate_kernel<<<(LSEQ * DINNER) / 1024, blk, 0, stream>>>(xz, u, Dvec, yhi, ylo);

    // 6. out = y @ out_proj_w.T (split-K=4 + reduce)
    mfma_gemm_tn<<<dim3(LSEQ / 128, DMODEL / 128, OSPLIT), blk, 0, stream>>>(
        yhi, ylo, owhi, owlo, opart, DMODEL, DINNER, DINNER / OSPLIT);
    reduce4<<<(LSEQ * DMODEL) / 1024, blk, 0, stream>>>(opart, out, LSEQ * DMODEL);
}